// Round 10
// baseline (69633.374 us; speedup 1.0000x reference)
//
#include <hip/hip_runtime.h>
#include <hip/hip_bf16.h>

typedef __hip_bfloat16 bf16;
typedef __attribute__((ext_vector_type(8))) short bfrag;            // 8 bf16 = 4 VGPRs
typedef __attribute__((ext_vector_type(8))) unsigned short u16x8;   // 16B copy unit
typedef __attribute__((ext_vector_type(4))) float f32x4;

#define SB 2
#define SS 2048
#define SD 512
#define SH 8
#define SWIN 128
#define SCH 64
#define SNCH 32
#define SFF 2048
#define KPROWS 2176              // WIN + S
#define KPBATCH 1114112L         // KPROWS*SD
#define BSD 1048576L             // SS*SD
#define DD 262144L               // SD*SD
#define ERRN 98304L              // 192*SD
#define NBLK 512                 // persistent scan grid

__device__ __forceinline__ void stf(float* p, float v){ *p = v; }
__device__ __forceinline__ void stf(bf16* p, float v){ *p = __float2bfloat16(v); }

// f32 -> bf16 bits, round-to-nearest-even (finite inputs)
__device__ __forceinline__ unsigned short f2bs(float f){
  union { float f; unsigned int u; } v; v.f = f;
  unsigned int r = v.u + 0x7FFFu + ((v.u >> 16) & 1u);
  return (unsigned short)(r >> 16);
}
__device__ __forceinline__ float bs2f(unsigned short h){
  union { unsigned int u; float f; } v; v.u = ((unsigned int)h) << 16;
  return v.f;
}

__device__ __forceinline__ float block_sum256(float v, float* sbuf){
  #pragma unroll
  for (int o = 32; o > 0; o >>= 1) v += __shfl_xor(v, o);
  int wid = threadIdx.x >> 6;
  if ((threadIdx.x & 63) == 0) sbuf[wid] = v;
  __syncthreads();
  float r = sbuf[0] + sbuf[1] + sbuf[2] + sbuf[3];
  __syncthreads();
  return r;
}

enum { EPI_NONE=0, EPI_SILU=1, EPI_SUB=2, EPI_LINCOMB=3, EPI_MUL=4, EPI_ADD=5, EPI_SILU_MUL=6 };

// ===== distributed-flag grid barrier: no RMW contention =====
// Each block stores its generation to its OWN flag (parallel). Block 0 polls all
// flags with plain agent-scope loads, then publishes gen; others spin on gen.
__device__ __forceinline__ void gsync(unsigned* __restrict__ flags,
                                      unsigned* __restrict__ gen, unsigned& my){
  my++;
  __threadfence();                              // release prior writes
  __syncthreads();
  const int bid = blockIdx.x, tid = threadIdx.x;
  if (bid == 0){
    int f1 = tid*2, f2 = tid*2 + 1;             // covers flags[0..511]; flag 0 unused
    if (f1 > 0)
      while (__hip_atomic_load(&flags[f1], __ATOMIC_RELAXED, __HIP_MEMORY_SCOPE_AGENT) < my)
        __builtin_amdgcn_s_sleep(1);
    while (__hip_atomic_load(&flags[f2], __ATOMIC_RELAXED, __HIP_MEMORY_SCOPE_AGENT) < my)
      __builtin_amdgcn_s_sleep(1);
    __syncthreads();
    if (tid == 0)
      __hip_atomic_store(gen, my, __ATOMIC_RELEASE, __HIP_MEMORY_SCOPE_AGENT);
  } else {
    if (tid == 0){
      __hip_atomic_store(&flags[bid], my, __ATOMIC_RELEASE, __HIP_MEMORY_SCOPE_AGENT);
      while (__hip_atomic_load(gen, __ATOMIC_ACQUIRE, __HIP_MEMORY_SCOPE_AGENT) < my)
        __builtin_amdgcn_s_sleep(16);
    }
    __syncthreads();
  }
  __threadfence();                              // acquire side
}

// ===== one 32x32 output tile of a split-pair 3-term Dekker GEMM =====
// A,B pre-split bf16 hi/lo planes (plane offsets pA/pB). f32 accum.
// TRA: A given [K,M]. TRB: B given [N,K]. K%32==0.
// MUPD: instead of storing C, do Mio = Mio*alRow[col] - v*etRow[col] (split pair).
template<bool TRA, bool TRB, int EPI, bool EPAIR, bool OSPLIT, bool OF32, bool FROB, bool MUPD=false>
__device__ __forceinline__ void gtile(
    const unsigned short* __restrict__ A, long pA, int lda,
    const unsigned short* __restrict__ B, long pB, int ldb,
    float* __restrict__ Cf, unsigned short* __restrict__ Chl, long pC, int ldc,
    const float* __restrict__ Ef, const unsigned short* __restrict__ Ehl, long pE, int lde,
    float* __restrict__ frobSlot,
    unsigned short* __restrict__ Mio, long pM,
    const float* __restrict__ alRow, const float* __restrict__ etRow,
    float a0, float a1,
    int K, int bm, int bn,
    unsigned short (*As)[2][32][40], unsigned short (*Bs)[2][32][40],
    float* fbuf)
{
  const int tid = threadIdx.x;
  const int lane = tid & 63, wid = tid >> 6;
  const int wr = (wid >> 1) * 16, wc = (wid & 1) * 16;
  const int fm = lane & 15, fk = (lane >> 4) * 8;

  int aR=0, aC=0, aPl=0, tK=0, tM0=0, tPl=0;
  if (!TRA) { aR = tid >> 3; int s = tid & 7; aPl = s >> 2; aC = (s & 3) << 3; }
  else      { tK = tid & 31; int q = tid >> 5; tPl = q >> 2; tM0 = (q & 3) << 3; }
  int bR=0, bC=0, bPl=0, uK=0, uN0=0, uPl=0;
  if (TRB)  { bR = tid >> 3; int s = tid & 7; bPl = s >> 2; bC = (s & 3) << 3; }
  else      { uK = tid & 31; int q = tid >> 5; uPl = q >> 2; uN0 = (q & 3) << 3; }

  u16x8 ra, rb;
  auto LA = [&](int k0){
    if (!TRA) ra = *reinterpret_cast<const u16x8*>(A + (long)(bm+aR)*lda + k0 + aC + (aPl ? pA : 0));
    else      ra = *reinterpret_cast<const u16x8*>(A + (long)(k0+tK)*lda + bm + tM0 + (tPl ? pA : 0));
  };
  auto SA = [&](int buf){
    if (!TRA) *reinterpret_cast<u16x8*>(&(*As)[0][0][0] + ((long)buf*2 + aPl)*32*40 + aR*40 + aC) = ra;
    else {
      #pragma unroll
      for (int j=0;j<8;j++) As[buf][tPl][tM0+j][tK] = ra[j];
    }
  };
  auto LB = [&](int k0){
    if (TRB)  rb = *reinterpret_cast<const u16x8*>(B + (long)(bn+bR)*ldb + k0 + bC + (bPl ? pB : 0));
    else      rb = *reinterpret_cast<const u16x8*>(B + (long)(k0+uK)*ldb + bn + uN0 + (uPl ? pB : 0));
  };
  auto SBst = [&](int buf){
    if (TRB)  *reinterpret_cast<u16x8*>(&(*Bs)[0][0][0] + ((long)buf*2 + bPl)*32*40 + bR*40 + bC) = rb;
    else {
      #pragma unroll
      for (int j=0;j<8;j++) Bs[buf][uPl][uN0+j][uK] = rb[j];
    }
  };

  f32x4 acc = {0.f,0.f,0.f,0.f};
  const int nk = K >> 5;
  LA(0); LB(0);
  int buf = 0;
  for (int i = 0; i < nk; i++) {
    SA(buf); SBst(buf);
    __syncthreads();
    if (i+1 < nk) { LA((i+1)<<5); LB((i+1)<<5); }
    bfrag ah = *reinterpret_cast<const bfrag*>(&As[buf][0][wr+fm][fk]);
    bfrag al = *reinterpret_cast<const bfrag*>(&As[buf][1][wr+fm][fk]);
    bfrag bh = *reinterpret_cast<const bfrag*>(&Bs[buf][0][wc+fm][fk]);
    bfrag bl = *reinterpret_cast<const bfrag*>(&Bs[buf][1][wc+fm][fk]);
    acc = __builtin_amdgcn_mfma_f32_16x16x32_bf16(ah, bh, acc, 0,0,0);
    acc = __builtin_amdgcn_mfma_f32_16x16x32_bf16(ah, bl, acc, 0,0,0);
    acc = __builtin_amdgcn_mfma_f32_16x16x32_bf16(al, bh, acc, 0,0,0);
    buf ^= 1;
  }

  float fs = 0.f;
  #pragma unroll
  for (int r=0;r<4;r++){
    int row = bm + wr + (lane>>4)*4 + r;
    int col = bn + wc + fm;
    float v = acc[r];
    if (EPI == EPI_SUB || EPI == EPI_LINCOMB) {
      float e;
      if (EPAIR){ long ei = (long)row*lde + col; e = bs2f(Ehl[ei]) + bs2f(Ehl[ei + pE]); }
      else      { e = Ef[(long)row*lde + col]; }
      v = (EPI == EPI_SUB) ? (v - e) : (a0*e + a1*v);
    }
    if (FROB) fs += v*v;
    if (OF32) Cf[(long)row*ldc + col] = v;
    if (OSPLIT){
      long ci = (long)row*ldc + col;
      unsigned short h = f2bs(v);
      Chl[ci] = h; Chl[ci + pC] = f2bs(v - bs2f(h));
    }
    if (MUPD){
      long mi = (long)row*ldc + col;
      float mo = bs2f(Mio[mi]) + bs2f(Mio[mi + pM]);
      float nv = mo*alRow[col] - v*etRow[col];
      unsigned short h = f2bs(nv);
      Mio[mi] = h; Mio[mi + pM] = f2bs(nv - bs2f(h));
    }
  }
  if (FROB){
    #pragma unroll
    for (int o = 32; o > 0; o >>= 1) fs += __shfl_xor(fs, o);
    if (lane == 0) fbuf[wid] = fs;
    __syncthreads();
    if (tid == 0) *frobSlot = fbuf[0]+fbuf[1]+fbuf[2]+fbuf[3];
  }
}

// ===== persistent scan kernel: 32 chunks, 577 grid syncs, 1 launch =====
__global__ __launch_bounds__(256, 2)
void scan_persist_k(const unsigned short* __restrict__ khl,
                    const unsigned short* __restrict__ qhl,
                    unsigned short* __restrict__ Mhl,
                    unsigned short* __restrict__ Xhl, unsigned short* __restrict__ Yhl,
                    unsigned short* __restrict__ Ahl, unsigned short* __restrict__ Thl,
                    unsigned short* __restrict__ errhl,
                    const float* __restrict__ vp, float* __restrict__ X0,
                    float* __restrict__ aout,
                    const float* __restrict__ etaM, const float* __restrict__ alphaM,
                    float* __restrict__ partials,
                    unsigned* __restrict__ flags, unsigned* __restrict__ gen)
{
  __shared__ __align__(16) unsigned short As[2][2][32][40];
  __shared__ __align__(16) unsigned short Bs[2][2][32][40];
  __shared__ float fbuf[4];
  const int bid = blockIdx.x;
  const int tid = threadIdx.x;
  unsigned my = 0;

  auto err_tile = [&](int t, int ti){
    int b = ti / 96, r = ti % 96, mt = r >> 4, nt = r & 15;
    long off = (long)t*SCH*SD;
    gtile<false,false,EPI_SUB,false,true,false,false>(
      khl + (long)b*2*KPBATCH + off, KPBATCH, SD,
      Mhl + (long)b*2*DD, DD, SD,
      nullptr, errhl + (long)b*2*ERRN, ERRN, SD,
      vp + (long)b*KPBATCH + off, nullptr, 0, SD,
      nullptr, nullptr, 0, nullptr, nullptr,
      0.f, 0.f, SD, mt*32, nt*32, As, Bs, fbuf);
  };

  // err for chunk 0
  if (bid < 192) err_tile(0, bid);
  gsync(flags, gen, my);

  for (int t = 0; t < SNCH; ++t){
    // grad = ck^T @ err (+ frob partial) -> X0
    {
      int b = bid >> 8, r = bid & 255, mt = r >> 4, nt = r & 15;
      long off = (long)t*SCH*SD;
      gtile<true,false,EPI_NONE,false,false,true,true>(
        khl + (long)b*2*KPBATCH + off, KPBATCH, SD,
        errhl + (long)b*2*ERRN, ERRN, SD,
        X0 + (long)b*DD, nullptr, 0, SD,
        nullptr, nullptr, 0, 0,
        &partials[bid], nullptr, 0, nullptr, nullptr,
        0.f, 0.f, 192, mt*32, nt*32, As, Bs, fbuf);
    }
    gsync(flags, gen, my);
    // scale by 1/(||G||_F + 1e-7), split -> Xhl
    {
      int b = bid >> 8, seg = bid & 255;
      float pv = partials[b*256 + tid];
      float s = block_sum256(pv, fbuf);
      float sc = 1.f / (sqrtf(s) + 1e-7f);
      long base = (long)b*DD + (long)seg*1024;
      long ob   = (long)b*2*DD + (long)seg*1024;
      for (int i = tid; i < 1024; i += 256){
        float f = X0[base + i] * sc;
        unsigned short h = f2bs(f);
        Xhl[ob + i] = h; Xhl[ob + DD + i] = f2bs(f - bs2f(h));
      }
    }
    gsync(flags, gen, my);
    unsigned short* Xc = Xhl;
    unsigned short* Xn = Yhl;
    // NS iterations 1..4 (full), 5th fused with M-update
    for (int it = 0; it < 4; ++it){
      { // A = X @ X^T
        int b = bid >> 8, r = bid & 255, mt = r >> 4, nt = r & 15;
        gtile<false,true,EPI_NONE,false,true,false,false>(
          Xc + (long)b*2*DD, DD, SD, Xc + (long)b*2*DD, DD, SD,
          nullptr, Ahl + (long)b*2*DD, DD, SD,
          nullptr, nullptr, 0, 0,
          nullptr, nullptr, 0, nullptr, nullptr,
          0.f, 0.f, SD, mt*32, nt*32, As, Bs, fbuf);
      }
      gsync(flags, gen, my);
      { // T = b*A + c*A@A
        int b = bid >> 8, r = bid & 255, mt = r >> 4, nt = r & 15;
        gtile<false,true,EPI_LINCOMB,true,true,false,false>(
          Ahl + (long)b*2*DD, DD, SD, Ahl + (long)b*2*DD, DD, SD,
          nullptr, Thl + (long)b*2*DD, DD, SD,
          nullptr, Ahl + (long)b*2*DD, DD, SD,
          nullptr, nullptr, 0, nullptr, nullptr,
          -4.7750f, 2.0315f, SD, mt*32, nt*32, As, Bs, fbuf);
      }
      gsync(flags, gen, my);
      { // Xn = a*X + T@X
        int b = bid >> 8, r = bid & 255, mt = r >> 4, nt = r & 15;
        gtile<false,false,EPI_LINCOMB,true,true,false,false>(
          Thl + (long)b*2*DD, DD, SD, Xc + (long)b*2*DD, DD, SD,
          nullptr, Xn + (long)b*2*DD, DD, SD,
          nullptr, Xc + (long)b*2*DD, DD, SD,
          nullptr, nullptr, 0, nullptr, nullptr,
          3.4445f, 1.0f, SD, mt*32, nt*32, As, Bs, fbuf);
      }
      gsync(flags, gen, my);
      unsigned short* tmp = Xc; Xc = Xn; Xn = tmp;
    }
    // iter 5: A, T, then fused X5 + M-update (X5 never materialized)
    {
      int b = bid >> 8, r = bid & 255, mt = r >> 4, nt = r & 15;
      gtile<false,true,EPI_NONE,false,true,false,false>(
        Xc + (long)b*2*DD, DD, SD, Xc + (long)b*2*DD, DD, SD,
        nullptr, Ahl + (long)b*2*DD, DD, SD,
        nullptr, nullptr, 0, 0,
        nullptr, nullptr, 0, nullptr, nullptr,
        0.f, 0.f, SD, mt*32, nt*32, As, Bs, fbuf);
    }
    gsync(flags, gen, my);
    {
      int b = bid >> 8, r = bid & 255, mt = r >> 4, nt = r & 15;
      gtile<false,true,EPI_LINCOMB,true,true,false,false>(
        Ahl + (long)b*2*DD, DD, SD, Ahl + (long)b*2*DD, DD, SD,
        nullptr, Thl + (long)b*2*DD, DD, SD,
        nullptr, Ahl + (long)b*2*DD, DD, SD,
        nullptr, nullptr, 0, nullptr, nullptr,
        -4.7750f, 2.0315f, SD, mt*32, nt*32, As, Bs, fbuf);
    }
    gsync(flags, gen, my);
    { // v = a*X4 + T@X4 ; M = M*alpha - v*eta  (split pair, in place)
      int b = bid >> 8, r = bid & 255, mt = r >> 4, nt = r & 15;
      gtile<false,false,EPI_LINCOMB,true,false,false,false,true>(
        Thl + (long)b*2*DD, DD, SD, Xc + (long)b*2*DD, DD, SD,
        nullptr, nullptr, 0, SD,
        nullptr, Xc + (long)b*2*DD, DD, SD,
        nullptr,
        Mhl + (long)b*2*DD, DD,
        alphaM + ((long)(b*32 + t) << 9), etaM + ((long)(b*32 + t) << 9),
        3.4445f, 1.0f, SD, mt*32, nt*32, As, Bs, fbuf);
    }
    gsync(flags, gen, my);
    // out(t) = cq @ M  ||  err(t+1)
    if (bid < 64){
      int b = bid >> 5, r = bid & 31, mt = r >> 4, nt = r & 15;
      long off = (long)t*SCH*SD;
      gtile<false,false,EPI_NONE,false,false,true,false>(
        qhl + (long)b*2*BSD + off, BSD, SD,
        Mhl + (long)b*2*DD, DD, SD,
        aout + (long)b*BSD + off, nullptr, 0, SD,
        nullptr, nullptr, 0, 0,
        nullptr, nullptr, 0, nullptr, nullptr,
        0.f, 0.f, SD, mt*32, nt*32, As, Bs, fbuf);
    } else if (bid < 256 && t+1 < SNCH){
      err_tile(t+1, bid - 64);
    }
    gsync(flags, gen, my);
  }
}

// ===================== f32-input MFMA GEMM (phase A/C) =====================
template<bool TRA, bool TRB, int EPI, typename TO>
__global__ __launch_bounds__(256)
void mgemm_k(const float* __restrict__ Ag, const float* __restrict__ Bg, TO* __restrict__ Cg,
             const float* __restrict__ Eg, float a0, float a1,
             int M, int N, int K,
             long sA, long sB, long sC, long sE,
             int lda, int ldb, int ldc, int lde)
{
  __shared__ __align__(16) unsigned short As[2][64][40];
  __shared__ __align__(16) unsigned short Bs[2][64][40];
  const int bz = blockIdx.z;
  const float* A = Ag + (long)bz*sA;
  const float* Bp = Bg + (long)bz*sB;
  TO* C = Cg + (long)bz*sC;
  const float* E = Eg ? (Eg + (long)bz*sE) : nullptr;
  const int bm = blockIdx.x*64, bn = blockIdx.y*64;
  const int tid = threadIdx.x;
  const int lane = tid & 63, wid = tid >> 6;
  const int wr = (wid >> 1)*32, wc = (wid & 1)*32;
  const int fm = lane & 15, fk = (lane >> 4)*8;

  f32x4 acc[2][2];
  #pragma unroll
  for (int i=0;i<2;i++)
    #pragma unroll
    for (int j=0;j<2;j++) acc[i][j] = (f32x4){0.f,0.f,0.f,0.f};

  for (int k0 = 0; k0 < K; k0 += 32) {
    if (!TRA) {
      int k = tid & 31, m0 = tid >> 5;
      #pragma unroll
      for (int u = 0; u < 8; u++) {
        int m = m0 + u*8;
        float f = A[(long)(bm+m)*lda + k0 + k];
        unsigned short h = f2bs(f);
        As[0][m][k] = h;
        As[1][m][k] = f2bs(f - bs2f(h));
      }
    } else {
      int m = tid & 63, kk0 = tid >> 6;
      #pragma unroll
      for (int u = 0; u < 8; u++) {
        int k = kk0 + u*4;
        float f = A[(long)(k0+k)*lda + bm + m];
        unsigned short h = f2bs(f);
        As[0][m][k] = h;
        As[1][m][k] = f2bs(f - bs2f(h));
      }
    }
    if (TRB) {
      int k = tid & 31, n0 = tid >> 5;
      #pragma unroll
      for (int u = 0; u < 8; u++) {
        int n = n0 + u*8;
        float f = Bp[(long)(bn+n)*ldb + k0 + k];
        unsigned short h = f2bs(f);
        Bs[0][n][k] = h;
        Bs[1][n][k] = f2bs(f - bs2f(h));
      }
    } else {
      int n = tid & 63, kk0 = tid >> 6;
      #pragma unroll
      for (int u = 0; u < 8; u++) {
        int k = kk0 + u*4;
        float f = Bp[(long)(k0+k)*ldb + bn + n];
        unsigned short h = f2bs(f);
        Bs[0][n][k] = h;
        Bs[1][n][k] = f2bs(f - bs2f(h));
      }
    }
    __syncthreads();
    bfrag ah0 = *reinterpret_cast<const bfrag*>(&As[0][wr + fm][fk]);
    bfrag ah1 = *reinterpret_cast<const bfrag*>(&As[0][wr + 16 + fm][fk]);
    bfrag bh0 = *reinterpret_cast<const bfrag*>(&Bs[0][wc + fm][fk]);
    bfrag bh1 = *reinterpret_cast<const bfrag*>(&Bs[0][wc + 16 + fm][fk]);
    bfrag al0 = *reinterpret_cast<const bfrag*>(&As[1][wr + fm][fk]);
    bfrag al1 = *reinterpret_cast<const bfrag*>(&As[1][wr + 16 + fm][fk]);
    bfrag bl0 = *reinterpret_cast<const bfrag*>(&Bs[1][wc + fm][fk]);
    bfrag bl1 = *reinterpret_cast<const bfrag*>(&Bs[1][wc + 16 + fm][fk]);
    acc[0][0] = __builtin_amdgcn_mfma_f32_16x16x32_bf16(ah0, bh0, acc[0][0], 0,0,0);
    acc[0][1] = __builtin_amdgcn_mfma_f32_16x16x32_bf16(ah0, bh1, acc[0][1], 0,0,0);
    acc[1][0] = __builtin_amdgcn_mfma_f32_16x16x32_bf16(ah1, bh0, acc[1][0], 0,0,0);
    acc[1][1] = __builtin_amdgcn_mfma_f32_16x16x32_bf16(ah1, bh1, acc[1][1], 0,0,0);
    acc[0][0] = __builtin_amdgcn_mfma_f32_16x16x32_bf16(ah0, bl0, acc[0][0], 0,0,0);
    acc[0][1] = __builtin_amdgcn_mfma_f32_16x16x32_bf16(ah0, bl1, acc[0][1], 0,0,0);
    acc[1][0] = __builtin_amdgcn_mfma_f32_16x16x32_bf16(ah1, bl0, acc[1][0], 0,0,0);
    acc[1][1] = __builtin_amdgcn_mfma_f32_16x16x32_bf16(ah1, bl1, acc[1][1], 0,0,0);
    acc[0][0] = __builtin_amdgcn_mfma_f32_16x16x32_bf16(al0, bh0, acc[0][0], 0,0,0);
    acc[0][1] = __builtin_amdgcn_mfma_f32_16x16x32_bf16(al0, bh1, acc[0][1], 0,0,0);
    acc[1][0] = __builtin_amdgcn_mfma_f32_16x16x32_bf16(al1, bh0, acc[1][0], 0,0,0);
    acc[1][1] = __builtin_amdgcn_mfma_f32_16x16x32_bf16(al1, bh1, acc[1][1], 0,0,0);
    __syncthreads();
  }

  #pragma unroll
  for (int i=0;i<2;i++) {
    #pragma unroll
    for (int j=0;j<2;j++) {
      #pragma unroll
      for (int r=0;r<4;r++) {
        int row = bm + wr + i*16 + (lane>>4)*4 + r;
        int col = bn + wc + j*16 + fm;
        float v = acc[i][j][r];
        if (EPI == EPI_SILU)          v = v / (1.f + __expf(-v));
        else if (EPI == EPI_SUB)      v = v - E[(long)row*lde + col];
        else if (EPI == EPI_LINCOMB)  v = a0*E[(long)row*lde + col] + a1*v;
        else if (EPI == EPI_MUL)      v = v * E[(long)row*lde + col];
        else if (EPI == EPI_ADD)      v = v + E[(long)row*lde + col];
        else if (EPI == EPI_SILU_MUL) v = (v / (1.f + __expf(-v))) * E[(long)row*lde + col];
        stf(&C[(long)row*ldc + col], v);
      }
    }
  }
}

// xn = x * nw * rsqrt(mean(x^2)+eps); one block per row
__global__ __launch_bounds__(256) void rmsnorm_in_k(const float* __restrict__ x,
    const float* __restrict__ w, float* __restrict__ xn)
{
  __shared__ float sbuf[4];
  long row = blockIdx.x;
  const float* xr = x + row*SD;
  int c0 = threadIdx.x, c1 = threadIdx.x + 256;
  float v0 = xr[c0], v1 = xr[c1];
  float ss = block_sum256(v0*v0 + v1*v1, sbuf);
  float r = rsqrtf(ss*(1.f/SD) + 1e-6f);
  xn[row*SD + c0] = v0*r*w[c0];
  xn[row*SD + c1] = v1*r*w[c1];
}

// dst_row = rms(silu(dwconv3(raw_row))) * nw ;  one block per (t, b)
__global__ __launch_bounds__(256) void conv_silu_rms_k(const float* __restrict__ raw,
    const float* __restrict__ cw, const float* __restrict__ cb, const float* __restrict__ nw,
    float* __restrict__ dst, long dstBatchStride, int dstRowOff)
{
  __shared__ float sbuf[4];
  int t = blockIdx.x, b = blockIdx.y;
  const float* base = raw + ((long)b*SS + t)*SD;
  float vals[2];
  #pragma unroll
  for (int u = 0; u < 2; u++) {
    int c = threadIdx.x + u*256;
    float w0 = cw[c*3+0], w1 = cw[c*3+1], w2 = cw[c*3+2];
    float acc = cb[c];
    if (t > 0)     acc += base[c - SD]*w0;
    acc += base[c]*w1;
    if (t < SS-1)  acc += base[c + SD]*w2;
    vals[u] = acc / (1.f + __expf(-acc));
  }
  float ss = block_sum256(vals[0]*vals[0] + vals[1]*vals[1], sbuf);
  float r = rsqrtf(ss*(1.f/SD) + 1e-6f);
  float* out = dst + (long)b*dstBatchStride + (long)(dstRowOff + t)*SD;
  out[threadIdx.x]       = vals[0]*r*nw[threadIdx.x];
  out[threadIdx.x + 256] = vals[1]*r*nw[threadIdx.x + 256];
}

// per-(b,chunk) column means of a [B*S, 512] buffer -> [B*NCH, 512]
__global__ __launch_bounds__(256) void chunk_means1_k(const float* __restrict__ src,
    float* __restrict__ dst)
{
  int cb = blockIdx.x;
  long rowbase = (long)cb*SCH*SD;
  #pragma unroll
  for (int u = 0; u < 2; u++) {
    int col = threadIdx.x + u*256;
    float s = 0.f;
    for (int r = 0; r < SCH; r++) s += src[rowbase + (long)r*SD + col];
    dst[(long)cb*SD + col] = s * (1.f/SCH);
  }
}

// atlas epilogue (in place): t = rms(a)*nw_out*gb; a = rms(t)*n1_w
__global__ __launch_bounds__(256) void atlas_final_norm_k(float* __restrict__ a,
    const float* __restrict__ gb, const float* __restrict__ nwout,
    const float* __restrict__ n1w)
{
  __shared__ float sbuf[4];
  long row = blockIdx.x;
  float* xr = a + row*SD;
  int c0 = threadIdx.x, c1 = threadIdx.x + 256;
  float v0 = xr[c0], v1 = xr[c1];
  float ss = block_sum256(v0*v0 + v1*v1, sbuf);
  float r = rsqrtf(ss*(1.f/SD) + 1e-6f);
  float t0 = v0*r*nwout[c0] * gb[row*SD+c0];
  float t1 = v1*r*nwout[c1] * gb[row*SD+c1];
  float ss2 = block_sum256(t0*t0 + t1*t1, sbuf);
  float r2 = rsqrtf(ss2*(1.f/SD) + 1e-6f);
  xr[c0] = t0*r2*n1w[c0];
  xr[c1] = t1*r2*n1w[c1];
}

// dst = rms(o)*w + dst  (in place on dst)
__global__ __launch_bounds__(256) void rms_add_k(const float* __restrict__ o,
    const float* __restrict__ w, float* __restrict__ dst)
{
  __shared__ float sbuf[4];
  long row = blockIdx.x;
  const float* xr = o + row*SD;
  int c0 = threadIdx.x, c1 = threadIdx.x + 256;
  float v0 = xr[c0], v1 = xr[c1];
  float ss = block_sum256(v0*v0 + v1*v1, sbuf);
  float r = rsqrtf(ss*(1.f/SD) + 1e-6f);
  dst[row*SD+c0] += v0*r*w[c0];
  dst[row*SD+c1] += v1*r*w[c1];
}

// sliding-window attention, one wave per (b, h, query); 4 waves/block
__global__ __launch_bounds__(256) void attn_swa_k(const float* __restrict__ Q,
    const float* __restrict__ K, const float* __restrict__ V, float* __restrict__ O)
{
  __shared__ float sc[4][SWIN];
  int wid = threadIdx.x >> 6, lane = threadIdx.x & 63;
  int w = blockIdx.x*4 + wid;
  int b = w >> 14;
  int rem = w & 16383;
  int h = rem >> 11;
  int i = rem & (SS-1);
  const float* qp = Q + ((long)b*SS + i)*SD + h*64;
  float qv = qp[lane];
  int j0 = i - (SWIN-1); if (j0 < 0) j0 = 0;
  int cnt = i - j0 + 1;
  const float* Kb = K + (long)b*SS*SD + h*64;
  const float* Vb = V + (long)b*SS*SD + h*64;
  float mx = -1e30f;
  for (int jj = 0; jj < cnt; jj++) {
    float p = qv * Kb[(long)(j0+jj)*SD + lane];
    #pragma unroll
    for (int o2 = 32; o2 > 0; o2 >>= 1) p += __shfl_xor(p, o2);
    p *= 0.125f;
    if (lane == 0) sc[wid][jj] = p;
    mx = fmaxf(mx, p);
  }
  __syncthreads();
  float sum = 0.f, oa = 0.f;
  for (int jj = 0; jj < cnt; jj++) {
    float p = __expf(sc[wid][jj] - mx);
    sum += p;
    oa += p * Vb[(long)(j0+jj)*SD + lane];
  }
  O[((long)b*SS + i)*SD + h*64 + lane] = oa / sum;
}

__global__ __launch_bounds__(256) void copy_f_k(float* __restrict__ dst, long dstride,
    const float* __restrict__ src, long sstride, long nper, int nb)
{
  long total = nper * nb;
  for (long i = (long)blockIdx.x*256 + threadIdx.x; i < total; i += (long)gridDim.x*256) {
    long b = i / nper, r = i - b*nper;
    dst[b*dstride + r] = src[b*sstride + r];
  }
}

// f32 -> hi/lo bf16 planes
__global__ __launch_bounds__(256) void split_k(unsigned short* __restrict__ dst,
    long dBatch, long dPlane, const float* __restrict__ src, long sBatch,
    long nper, int nb)
{
  long total = nper * nb;
  for (long i = (long)blockIdx.x*256 + threadIdx.x; i < total; i += (long)gridDim.x*256) {
    long b = i / nper, r = i - b*nper;
    float f = src[b*sBatch + r];
    unsigned short h = f2bs(f);
    dst[b*dBatch + r]          = h;
    dst[b*dBatch + dPlane + r] = f2bs(f - bs2f(h));
  }
}

// hi/lo planes -> f32
__global__ __launch_bounds__(256) void merge_k(float* __restrict__ dst, long dBatch,
    const unsigned short* __restrict__ src, long sBatch, long sPlane, long nper, int nb)
{
  long total = nper * nb;
  for (long i = (long)blockIdx.x*256 + threadIdx.x; i < total; i += (long)gridDim.x*256) {
    long b = i / nper, r = i - b*nper;
    dst[b*dBatch + r] = bs2f(src[b*sBatch + r]) + bs2f(src[b*sBatch + sPlane + r]);
  }
}

extern "C" void kernel_launch(void* const* d_in, const int* in_sizes, int n_in,
                              void* d_out, int out_size, void* d_ws, size_t ws_size,
                              hipStream_t stream)
{
  (void)in_sizes; (void)n_in; (void)out_size; (void)ws_size;
  const float* x      = (const float*)d_in[0];
  const float* mem0   = (const float*)d_in[1];
  const float* buf_k  = (const float*)d_in[2];
  const float* buf_v  = (const float*)d_in[3];
  const float* nw_in  = (const float*)d_in[4];
  const float* nw_kq  = (const float*)d_in[5];
  const float* nw_out = (const float*)d_in[6];
  const float* wk_a   = (const float*)d_in[7];
  const float* wq_a   = (const float*)d_in[8];
  const float* wv_a   = (const float*)d_in[9];
  const float* wg     = (const float*)d_in[10];
  const float* wb     = (const float*)d_in[11];
  const float* ck_w   = (const float*)d_in[12];
  const float* ck_b   = (const float*)d_in[13];
  const float* cq_w   = (const float*)d_in[14];
  const float* cq_b   = (const float*)d_in[15];
  const float* s1_wq  = (const float*)d_in[16];
  const float* s1_wk  = (const float*)d_in[17];
  const float* s1_wv  = (const float*)d_in[18];
  const float* s1_wo  = (const float*)d_in[19];
  const float* s2_wq  = (const float*)d_in[20];
  const float* s2_wk  = (const float*)d_in[21];
  const float* s2_wv  = (const float*)d_in[22];
  const float* s2_wo  = (const float*)d_in[23];
  const float* n1_w   = (const float*)d_in[24];
  const float* n2_w   = (const float*)d_in[25];
  const float* m_w1   = (const float*)d_in[26];
  const float* m_w2   = (const float*)d_in[27];
  const float* m_w3   = (const float*)d_in[28];
  float* ob = (float*)d_out;

  // ---- workspace carve: f32 section (~56MB) + u16 split arena (~29MB) ----
  float* p = (float*)d_ws;
  float* kp   = p; p += SB*KPBATCH;   // padded k f32; C: attn out; MLP: h1 head
  float* vp   = p; p += SB*KPBATCH;   // padded v f32; C: oproj1 out
  float* qbuf = p; p += SB*BSD;       // atlas q f32; C: v1/v2
  float* gb   = p; p += SB*BSD;       // gamma*bypass; C: k1/k2; MLP: h1 tail
  float* sc1  = p; p += SB*BSD;       // xn; C: q1/q2, y
  float* sc2  = p; p += SB*BSD;       // kraw/qraw; B: aout; C: memn->fused
  float* Mb   = p; p += SB*DD;        // mem0 f32 (split source)
  float* X0   = p; p += SB*DD;        // grad f32 (frob input)
  float* etaM = p; p += (long)SB*SNCH*SD;
  float* alphaM = p; p += (long)SB*SNCH*SD;
  float* partials = p; p += 512;
  unsigned* barArea = (unsigned*)p; p += 544;  // flags[512] + gen + pad
  unsigned short* us = (unsigned short*)p;
  unsigned short* khl = us; us += SB*2*KPBATCH;
  unsigned short* qhl = us; us += SB*2*BSD;
  unsigned short* Mhl = us; us += SB*2*DD;
  unsigned short* Xhl = us; us += SB*2*DD;
  unsigned short* Yhl = us; us += SB*2*DD;
  unsigned short* Ahl = us; us += SB*2*DD;
  unsigned short* Thl = us; us += SB*2*DD;
  unsigned short* errhl = us; us += SB*2*ERRN;
  float* nsbuf = (float*)khl;         // phase-A scratch (before splits)
  float* aout = sc2;
  float* hbuf = kp;                   // MLP h1/h2: kp..gb span

  dim3 blk(256);

  hipMemsetAsync(barArea, 0, 544*4, stream);   // flags + gen = 0 each call

  // ================= Phase A =================
  rmsnorm_in_k<<<SB*SS, blk, 0, stream>>>(x, nw_in, sc1);

  mgemm_k<false,true,EPI_SILU,float><<<dim3(32,8,2),blk,0,stream>>>(
      sc1, wv_a, vp + (long)SWIN*SD, nullptr, 0.f,0.f, SS, SD, SD,
      BSD, 0, KPBATCH, 0, SD, SD, SD, 0);

  mgemm_k<false,true,EPI_NONE,float><<<dim3(64,8,1),blk,0,stream>>>(
      sc1, wk_a, sc2, nullptr, 0.f,0.f, SB*SS, SD, SD, 0,0,0,0, SD,SD,SD,0);
  conv_silu_rms_k<<<dim3(SS,SB),blk,0,stream>>>(sc2, ck_w, ck_b, nw_kq, kp, KPBATCH, SWIN);

  mgemm_k<false,true,EPI_NONE,float><<<dim3(64,8,1),blk,0,stream>>>(
      sc1, wq_a, sc2, nullptr, 0.f,0.f, SB*SS, SD, SD, 0,0,0,0, SD,SD,SD,0);
  conv_silu_rms_k<<<dim3(SS,SB),blk,0,stream>>>(sc2, cq_w, cq_b, nw_kq, qbuf, BSD, 0);

  mgemm_k<false,true,EPI_SILU,float><<<dim3(64,8,1),blk,0,stream>>>(
      sc1, wg, gb, nullptr, 0.f,0.f, SB*SS, SD, SD, 0,0,0,0, SD,SD,SD,0);
  mgemm_k<false,true,EPI_SILU_MUL,float><<<dim3(64,8,1),blk,0,stream>>>(
      sc1, wb, gb, gb, 0.f,0.f, SB*SS, SD, SD, 0,0,0,0, SD,SD,SD,SD);

  mgemm_k<false,true,EPI_SILU,float><<<dim3(64,8,1),blk,0,stream>>>(
      sc1, wg + (long)SD*SD, nsbuf, nullptr, 0.f,0.f, SB*SS, SD, SD, 0,0,0,0, SD,SD,SD,0);
  chunk_means1_k<<<SB*SNCH, blk, 0, stream>>>(nsbuf, etaM);
  mgemm_k<false,true,EPI_SILU,float><<<dim3(64,8,1),blk,0,stream>>>(
      sc1, wg + 2L*SD*SD, nsbuf, nullptr, 0.f,0.f, SB*SS, SD, SD, 0,0,0,0, SD,SD,SD,0);
  chunk_means1_k<<<SB*SNCH, blk, 0, stream>>>(nsbuf, alphaM);

  copy_f_k<<<256,blk,0,stream>>>(kp, KPBATCH, buf_k, (long)SWIN*SD, (long)SWIN*SD, SB);
  copy_f_k<<<256,blk,0,stream>>>(vp, KPBATCH, buf_v, (long)SWIN*SD, (long)SWIN*SD, SB);
  copy_f_k<<<256,blk,0,stream>>>(Mb, DD, mem0, DD, DD, SB);

  // split once for the scan (AFTER nsbuf is dead)
  split_k<<<512,blk,0,stream>>>(khl, 2*KPBATCH, KPBATCH, kp, KPBATCH, KPBATCH, SB);
  split_k<<<512,blk,0,stream>>>(qhl, 2*BSD, BSD, qbuf, BSD, BSD, SB);
  split_k<<<256,blk,0,stream>>>(Mhl, 2*DD, DD, Mb, DD, DD, SB);

  // ================= Phase B: one persistent kernel =================
  scan_persist_k<<<NBLK, blk, 0, stream>>>(
      khl, qhl, Mhl, Xhl, Yhl, Ahl, Thl, errhl,
      vp, X0, aout, etaM, alphaM, partials,
      &barArea[0], &barArea[512]);

  // ================= Phase C =================
  atlas_final_norm_k<<<SB*SS,blk,0,stream>>>(sc2, gb, nw_out, n1_w);

  // side outputs (before kp/vp reuse)
  merge_k<<<256,blk,0,stream>>>(ob + (long)SB*SS*SD, DD, Mhl, 2*DD, DD, DD, SB);
  copy_f_k<<<256,blk,0,stream>>>(ob + (long)SB*SS*SD + SB*DD, (long)SWIN*SD,
      kp + (long)SS*SD, KPBATCH, (long)SWIN*SD, SB);
  copy_f_k<<<256,blk,0,stream>>>(ob + (long)SB*SS*SD + SB*DD + (long)SB*SWIN*SD, (long)SWIN*SD,
      vp + (long)SS*SD, KPBATCH, (long)SWIN*SD, SB);

  // SWA 1 on x
  mgemm_k<false,true,EPI_NONE,float><<<dim3(64,8,1),blk,0,stream>>>(
      x, s1_wq, sc1, nullptr,0.f,0.f, SB*SS, SD, SD, 0,0,0,0, SD,SD,SD,0);
  mgemm_k<false,true,EPI_NONE,float><<<dim3(64,8,1),blk,0,stream>>>(
      x, s1_wk, gb, nullptr,0.f,0.f, SB*SS, SD, SD, 0,0,0,0, SD,SD,SD,0);
  mgemm_k<false,true,EPI_NONE,float><<<dim3(64,8,1),blk,0,stream>>>(
      x, s1_wv, qbuf, nullptr,0.f,0.f, SB*SS, SD, SD, 0,0,0,0, SD,SD,SD,0);
  attn_swa_k<<<SB*SH*SS/4, blk, 0, stream>>>(sc1, gb, qbuf, kp);
  mgemm_k<false,true,EPI_NONE,float><<<dim3(64,8,1),blk,0,stream>>>(
      kp, s1_wo, vp, nullptr,0.f,0.f, SB*SS, SD, SD, 0,0,0,0, SD,SD,SD,0);
  rms_add_k<<<SB*SS,blk,0,stream>>>(vp, n2_w, sc2);   // sc2 = fused

  // SWA 2 on fused
  mgemm_k<false,true,EPI_NONE,float><<<dim3(64,8,1),blk,0,stream>>>(
      sc2, s2_wq, sc1, nullptr,0.f,0.f, SB*SS, SD, SD, 0,0,0,0, SD,SD,SD,0);
  mgemm_k<false,true,EPI_NONE,float><<<dim3(64,8,1),blk,0,stream>>>(
      sc2, s2_wk, gb, nullptr,0.f,0.f, SB*SS, SD, SD, 0,0,0,0, SD,SD,SD,0);
  mgemm_k<false,true,EPI_NONE,float><<<dim3(64,8,1),blk,0,stream>>>(
      sc2, s2_wv, qbuf, nullptr,0.f,0.f, SB*SS, SD, SD, 0,0,0,0, SD,SD,SD,0);
  attn_swa_k<<<SB*SH*SS/4, blk, 0, stream>>>(sc1, gb, qbuf, kp);
  mgemm_k<false,true,EPI_NONE,float><<<dim3(64,8,1),blk,0,stream>>>(
      kp, s2_wo, sc1, nullptr,0.f,0.f, SB*SS, SD, SD, 0,0,0,0, SD,SD,SD,0); // y=sc1

  // MLP
  mgemm_k<false,true,EPI_SILU,float><<<dim3(64,32,1),blk,0,stream>>>(
      sc1, m_w1, hbuf, nullptr,0.f,0.f, SB*SS, SFF, SD, 0,0,0,0, SD,SD,SFF,0);
  mgemm_k<false,true,EPI_MUL,float><<<dim3(64,32,1),blk,0,stream>>>(
      sc1, m_w2, hbuf, hbuf, 0.f,0.f, SB*SS, SFF, SD, 0,0,0,0, SD,SD,SFF,SFF);
  mgemm_k<false,true,EPI_ADD,float><<<dim3(64,8,1),blk,0,stream>>>(
      hbuf, m_w3, ob, sc2, 0.f,0.f, SB*SS, SD, SFF, 0,0,0,0, SFF,SFF,SD,SD);
}

// Round 11
// 51410.071 us; speedup vs baseline: 1.3545x; 1.3545x over previous
//
#include <hip/hip_runtime.h>
#include <hip/hip_bf16.h>

typedef __hip_bfloat16 bf16;
typedef __attribute__((ext_vector_type(8))) short bfrag;            // 8 bf16 = 4 VGPRs
typedef __attribute__((ext_vector_type(8))) unsigned short u16x8;   // 16B copy unit
typedef __attribute__((ext_vector_type(4))) float f32x4;

#define SB 2
#define SS 2048
#define SD 512
#define SH 8
#define SWIN 128
#define SCH 64
#define SNCH 32
#define SFF 2048
#define KPROWS 2176              // WIN + S
#define KPBATCH 1114112L         // KPROWS*SD
#define BSD 1048576L             // SS*SD
#define DD 262144L               // SD*SD
#define ERRN 98304L              // 192*SD
#define NBLK 512                 // persistent scan grid

__device__ __forceinline__ void stf(float* p, float v){ *p = v; }
__device__ __forceinline__ void stf(bf16* p, float v){ *p = __float2bfloat16(v); }

// f32 -> bf16 bits, round-to-nearest-even (finite inputs)
__device__ __forceinline__ unsigned short f2bs(float f){
  union { float f; unsigned int u; } v; v.f = f;
  unsigned int r = v.u + 0x7FFFu + ((v.u >> 16) & 1u);
  return (unsigned short)(r >> 16);
}
__device__ __forceinline__ float bs2f(unsigned short h){
  union { unsigned int u; float f; } v; v.u = ((unsigned int)h) << 16;
  return v.f;
}

__device__ __forceinline__ float block_sum256(float v, float* sbuf){
  #pragma unroll
  for (int o = 32; o > 0; o >>= 1) v += __shfl_xor(v, o);
  int wid = threadIdx.x >> 6;
  if ((threadIdx.x & 63) == 0) sbuf[wid] = v;
  __syncthreads();
  float r = sbuf[0] + sbuf[1] + sbuf[2] + sbuf[3];
  __syncthreads();
  return r;
}

enum { EPI_NONE=0, EPI_SILU=1, EPI_SUB=2, EPI_LINCOMB=3, EPI_MUL=4, EPI_ADD=5, EPI_SILU_MUL=6 };

// ===== distributed-flag grid barrier =====
// ALL polls are RELAXED (an acquire in the spin loop emits buffer_inv per
// iteration -> continuous full-L2 invalidation across all XCDs; that was the
// round-9/10 pathology). Ordering comes from the single explicit
// __threadfence() release before arrival and acquire after exit.
__device__ __forceinline__ void gsync(unsigned* __restrict__ flags,
                                      unsigned* __restrict__ gen, unsigned& my){
  my++;
  __threadfence();                              // release: one wb per sync
  __syncthreads();
  const int bid = blockIdx.x, tid = threadIdx.x;
  if (bid == 0){
    int f1 = tid*2, f2 = tid*2 + 1;             // covers flags[0..511]; flag 0 unused
    if (f1 > 0)
      while (__hip_atomic_load(&flags[f1], __ATOMIC_RELAXED, __HIP_MEMORY_SCOPE_AGENT) < my)
        __builtin_amdgcn_s_sleep(1);
    while (__hip_atomic_load(&flags[f2], __ATOMIC_RELAXED, __HIP_MEMORY_SCOPE_AGENT) < my)
      __builtin_amdgcn_s_sleep(1);
    __syncthreads();
    if (tid == 0)
      __hip_atomic_store(gen, my, __ATOMIC_RELAXED, __HIP_MEMORY_SCOPE_AGENT);
  } else {
    if (tid == 0){
      __hip_atomic_store(&flags[bid], my, __ATOMIC_RELAXED, __HIP_MEMORY_SCOPE_AGENT);
      while (__hip_atomic_load(gen, __ATOMIC_RELAXED, __HIP_MEMORY_SCOPE_AGENT) < my)
        __builtin_amdgcn_s_sleep(8);
    }
    __syncthreads();
  }
  __threadfence();                              // acquire: one inv per sync
}

// ===== one 32x32 output tile of a split-pair 3-term Dekker GEMM =====
// A,B pre-split bf16 hi/lo planes (plane offsets pA/pB). f32 accum.
// TRA: A given [K,M]. TRB: B given [N,K]. K%32==0.
// MUPD: instead of storing C, do Mio = Mio*alRow[col] - v*etRow[col] (split pair).
template<bool TRA, bool TRB, int EPI, bool EPAIR, bool OSPLIT, bool OF32, bool FROB, bool MUPD=false>
__device__ __forceinline__ void gtile(
    const unsigned short* __restrict__ A, long pA, int lda,
    const unsigned short* __restrict__ B, long pB, int ldb,
    float* __restrict__ Cf, unsigned short* __restrict__ Chl, long pC, int ldc,
    const float* __restrict__ Ef, const unsigned short* __restrict__ Ehl, long pE, int lde,
    float* __restrict__ frobSlot,
    unsigned short* __restrict__ Mio, long pM,
    const float* __restrict__ alRow, const float* __restrict__ etRow,
    float a0, float a1,
    int K, int bm, int bn,
    unsigned short (*As)[2][32][40], unsigned short (*Bs)[2][32][40],
    float* fbuf)
{
  const int tid = threadIdx.x;
  const int lane = tid & 63, wid = tid >> 6;
  const int wr = (wid >> 1) * 16, wc = (wid & 1) * 16;
  const int fm = lane & 15, fk = (lane >> 4) * 8;

  int aR=0, aC=0, aPl=0, tK=0, tM0=0, tPl=0;
  if (!TRA) { aR = tid >> 3; int s = tid & 7; aPl = s >> 2; aC = (s & 3) << 3; }
  else      { tK = tid & 31; int q = tid >> 5; tPl = q >> 2; tM0 = (q & 3) << 3; }
  int bR=0, bC=0, bPl=0, uK=0, uN0=0, uPl=0;
  if (TRB)  { bR = tid >> 3; int s = tid & 7; bPl = s >> 2; bC = (s & 3) << 3; }
  else      { uK = tid & 31; int q = tid >> 5; uPl = q >> 2; uN0 = (q & 3) << 3; }

  u16x8 ra, rb;
  auto LA = [&](int k0){
    if (!TRA) ra = *reinterpret_cast<const u16x8*>(A + (long)(bm+aR)*lda + k0 + aC + (aPl ? pA : 0));
    else      ra = *reinterpret_cast<const u16x8*>(A + (long)(k0+tK)*lda + bm + tM0 + (tPl ? pA : 0));
  };
  auto SA = [&](int buf){
    if (!TRA) *reinterpret_cast<u16x8*>(&(*As)[0][0][0] + ((long)buf*2 + aPl)*32*40 + aR*40 + aC) = ra;
    else {
      #pragma unroll
      for (int j=0;j<8;j++) As[buf][tPl][tM0+j][tK] = ra[j];
    }
  };
  auto LB = [&](int k0){
    if (TRB)  rb = *reinterpret_cast<const u16x8*>(B + (long)(bn+bR)*ldb + k0 + bC + (bPl ? pB : 0));
    else      rb = *reinterpret_cast<const u16x8*>(B + (long)(k0+uK)*ldb + bn + uN0 + (uPl ? pB : 0));
  };
  auto SBst = [&](int buf){
    if (TRB)  *reinterpret_cast<u16x8*>(&(*Bs)[0][0][0] + ((long)buf*2 + bPl)*32*40 + bR*40 + bC) = rb;
    else {
      #pragma unroll
      for (int j=0;j<8;j++) Bs[buf][uPl][uN0+j][uK] = rb[j];
    }
  };

  f32x4 acc = {0.f,0.f,0.f,0.f};
  const int nk = K >> 5;
  LA(0); LB(0);
  int buf = 0;
  for (int i = 0; i < nk; i++) {
    SA(buf); SBst(buf);
    __syncthreads();
    if (i+1 < nk) { LA((i+1)<<5); LB((i+1)<<5); }
    bfrag ah = *reinterpret_cast<const bfrag*>(&As[buf][0][wr+fm][fk]);
    bfrag al = *reinterpret_cast<const bfrag*>(&As[buf][1][wr+fm][fk]);
    bfrag bh = *reinterpret_cast<const bfrag*>(&Bs[buf][0][wc+fm][fk]);
    bfrag bl = *reinterpret_cast<const bfrag*>(&Bs[buf][1][wc+fm][fk]);
    acc = __builtin_amdgcn_mfma_f32_16x16x32_bf16(ah, bh, acc, 0,0,0);
    acc = __builtin_amdgcn_mfma_f32_16x16x32_bf16(ah, bl, acc, 0,0,0);
    acc = __builtin_amdgcn_mfma_f32_16x16x32_bf16(al, bh, acc, 0,0,0);
    buf ^= 1;
  }

  float fs = 0.f;
  #pragma unroll
  for (int r=0;r<4;r++){
    int row = bm + wr + (lane>>4)*4 + r;
    int col = bn + wc + fm;
    float v = acc[r];
    if (EPI == EPI_SUB || EPI == EPI_LINCOMB) {
      float e;
      if (EPAIR){ long ei = (long)row*lde + col; e = bs2f(Ehl[ei]) + bs2f(Ehl[ei + pE]); }
      else      { e = Ef[(long)row*lde + col]; }
      v = (EPI == EPI_SUB) ? (v - e) : (a0*e + a1*v);
    }
    if (FROB) fs += v*v;
    if (OF32) Cf[(long)row*ldc + col] = v;
    if (OSPLIT){
      long ci = (long)row*ldc + col;
      unsigned short h = f2bs(v);
      Chl[ci] = h; Chl[ci + pC] = f2bs(v - bs2f(h));
    }
    if (MUPD){
      long mi = (long)row*ldc + col;
      float mo = bs2f(Mio[mi]) + bs2f(Mio[mi + pM]);
      float nv = mo*alRow[col] - v*etRow[col];
      unsigned short h = f2bs(nv);
      Mio[mi] = h; Mio[mi + pM] = f2bs(nv - bs2f(h));
    }
  }
  if (FROB){
    #pragma unroll
    for (int o = 32; o > 0; o >>= 1) fs += __shfl_xor(fs, o);
    if (lane == 0) fbuf[wid] = fs;
    __syncthreads();
    if (tid == 0) *frobSlot = fbuf[0]+fbuf[1]+fbuf[2]+fbuf[3];
  }
}

// ===== persistent scan kernel: 32 chunks, 577 grid syncs, 1 launch =====
__global__ __launch_bounds__(256, 2)
void scan_persist_k(const unsigned short* __restrict__ khl,
                    const unsigned short* __restrict__ qhl,
                    unsigned short* __restrict__ Mhl,
                    unsigned short* __restrict__ Xhl, unsigned short* __restrict__ Yhl,
                    unsigned short* __restrict__ Ahl, unsigned short* __restrict__ Thl,
                    unsigned short* __restrict__ errhl,
                    const float* __restrict__ vp, float* __restrict__ X0,
                    float* __restrict__ aout,
                    const float* __restrict__ etaM, const float* __restrict__ alphaM,
                    float* __restrict__ partials,
                    unsigned* __restrict__ flags, unsigned* __restrict__ gen)
{
  __shared__ __align__(16) unsigned short As[2][2][32][40];
  __shared__ __align__(16) unsigned short Bs[2][2][32][40];
  __shared__ float fbuf[4];
  const int bid = blockIdx.x;
  const int tid = threadIdx.x;
  unsigned my = 0;

  auto err_tile = [&](int t, int ti){
    int b = ti / 96, r = ti % 96, mt = r >> 4, nt = r & 15;
    long off = (long)t*SCH*SD;
    gtile<false,false,EPI_SUB,false,true,false,false>(
      khl + (long)b*2*KPBATCH + off, KPBATCH, SD,
      Mhl + (long)b*2*DD, DD, SD,
      nullptr, errhl + (long)b*2*ERRN, ERRN, SD,
      vp + (long)b*KPBATCH + off, nullptr, 0, SD,
      nullptr, nullptr, 0, nullptr, nullptr,
      0.f, 0.f, SD, mt*32, nt*32, As, Bs, fbuf);
  };

  // err for chunk 0
  if (bid < 192) err_tile(0, bid);
  gsync(flags, gen, my);

  for (int t = 0; t < SNCH; ++t){
    // grad = ck^T @ err (+ frob partial) -> X0
    {
      int b = bid >> 8, r = bid & 255, mt = r >> 4, nt = r & 15;
      long off = (long)t*SCH*SD;
      gtile<true,false,EPI_NONE,false,false,true,true>(
        khl + (long)b*2*KPBATCH + off, KPBATCH, SD,
        errhl + (long)b*2*ERRN, ERRN, SD,
        X0 + (long)b*DD, nullptr, 0, SD,
        nullptr, nullptr, 0, 0,
        &partials[bid], nullptr, 0, nullptr, nullptr,
        0.f, 0.f, 192, mt*32, nt*32, As, Bs, fbuf);
    }
    gsync(flags, gen, my);
    // scale by 1/(||G||_F + 1e-7), split -> Xhl
    {
      int b = bid >> 8, seg = bid & 255;
      float pv = partials[b*256 + tid];
      float s = block_sum256(pv, fbuf);
      float sc = 1.f / (sqrtf(s) + 1e-7f);
      long base = (long)b*DD + (long)seg*1024;
      long ob   = (long)b*2*DD + (long)seg*1024;
      for (int i = tid; i < 1024; i += 256){
        float f = X0[base + i] * sc;
        unsigned short h = f2bs(f);
        Xhl[ob + i] = h; Xhl[ob + DD + i] = f2bs(f - bs2f(h));
      }
    }
    gsync(flags, gen, my);
    unsigned short* Xc = Xhl;
    unsigned short* Xn = Yhl;
    // NS iterations 1..4 (full), 5th fused with M-update
    for (int it = 0; it < 4; ++it){
      { // A = X @ X^T
        int b = bid >> 8, r = bid & 255, mt = r >> 4, nt = r & 15;
        gtile<false,true,EPI_NONE,false,true,false,false>(
          Xc + (long)b*2*DD, DD, SD, Xc + (long)b*2*DD, DD, SD,
          nullptr, Ahl + (long)b*2*DD, DD, SD,
          nullptr, nullptr, 0, 0,
          nullptr, nullptr, 0, nullptr, nullptr,
          0.f, 0.f, SD, mt*32, nt*32, As, Bs, fbuf);
      }
      gsync(flags, gen, my);
      { // T = b*A + c*A@A
        int b = bid >> 8, r = bid & 255, mt = r >> 4, nt = r & 15;
        gtile<false,true,EPI_LINCOMB,true,true,false,false>(
          Ahl + (long)b*2*DD, DD, SD, Ahl + (long)b*2*DD, DD, SD,
          nullptr, Thl + (long)b*2*DD, DD, SD,
          nullptr, Ahl + (long)b*2*DD, DD, SD,
          nullptr, nullptr, 0, nullptr, nullptr,
          -4.7750f, 2.0315f, SD, mt*32, nt*32, As, Bs, fbuf);
      }
      gsync(flags, gen, my);
      { // Xn = a*X + T@X
        int b = bid >> 8, r = bid & 255, mt = r >> 4, nt = r & 15;
        gtile<false,false,EPI_LINCOMB,true,true,false,false>(
          Thl + (long)b*2*DD, DD, SD, Xc + (long)b*2*DD, DD, SD,
          nullptr, Xn + (long)b*2*DD, DD, SD,
          nullptr, Xc + (long)b*2*DD, DD, SD,
          nullptr, nullptr, 0, nullptr, nullptr,
          3.4445f, 1.0f, SD, mt*32, nt*32, As, Bs, fbuf);
      }
      gsync(flags, gen, my);
      unsigned short* tmp = Xc; Xc = Xn; Xn = tmp;
    }
    // iter 5: A, T, then fused X5 + M-update (X5 never materialized)
    {
      int b = bid >> 8, r = bid & 255, mt = r >> 4, nt = r & 15;
      gtile<false,true,EPI_NONE,false,true,false,false>(
        Xc + (long)b*2*DD, DD, SD, Xc + (long)b*2*DD, DD, SD,
        nullptr, Ahl + (long)b*2*DD, DD, SD,
        nullptr, nullptr, 0, 0,
        nullptr, nullptr, 0, nullptr, nullptr,
        0.f, 0.f, SD, mt*32, nt*32, As, Bs, fbuf);
    }
    gsync(flags, gen, my);
    {
      int b = bid >> 8, r = bid & 255, mt = r >> 4, nt = r & 15;
      gtile<false,true,EPI_LINCOMB,true,true,false,false>(
        Ahl + (long)b*2*DD, DD, SD, Ahl + (long)b*2*DD, DD, SD,
        nullptr, Thl + (long)b*2*DD, DD, SD,
        nullptr, Ahl + (long)b*2*DD, DD, SD,
        nullptr, nullptr, 0, nullptr, nullptr,
        -4.7750f, 2.0315f, SD, mt*32, nt*32, As, Bs, fbuf);
    }
    gsync(flags, gen, my);
    { // v = a*X4 + T@X4 ; M = M*alpha - v*eta  (split pair, in place)
      int b = bid >> 8, r = bid & 255, mt = r >> 4, nt = r & 15;
      gtile<false,false,EPI_LINCOMB,true,false,false,false,true>(
        Thl + (long)b*2*DD, DD, SD, Xc + (long)b*2*DD, DD, SD,
        nullptr, nullptr, 0, SD,
        nullptr, Xc + (long)b*2*DD, DD, SD,
        nullptr,
        Mhl + (long)b*2*DD, DD,
        alphaM + ((long)(b*32 + t) << 9), etaM + ((long)(b*32 + t) << 9),
        3.4445f, 1.0f, SD, mt*32, nt*32, As, Bs, fbuf);
    }
    gsync(flags, gen, my);
    // out(t) = cq @ M  ||  err(t+1)
    if (bid < 64){
      int b = bid >> 5, r = bid & 31, mt = r >> 4, nt = r & 15;
      long off = (long)t*SCH*SD;
      gtile<false,false,EPI_NONE,false,false,true,false>(
        qhl + (long)b*2*BSD + off, BSD, SD,
        Mhl + (long)b*2*DD, DD, SD,
        aout + (long)b*BSD + off, nullptr, 0, SD,
        nullptr, nullptr, 0, 0,
        nullptr, nullptr, 0, nullptr, nullptr,
        0.f, 0.f, SD, mt*32, nt*32, As, Bs, fbuf);
    } else if (bid < 256 && t+1 < SNCH){
      err_tile(t+1, bid - 64);
    }
    gsync(flags, gen, my);
  }
}

// ===================== f32-input MFMA GEMM (phase A/C) =====================
template<bool TRA, bool TRB, int EPI, typename TO>
__global__ __launch_bounds__(256)
void mgemm_k(const float* __restrict__ Ag, const float* __restrict__ Bg, TO* __restrict__ Cg,
             const float* __restrict__ Eg, float a0, float a1,
             int M, int N, int K,
             long sA, long sB, long sC, long sE,
             int lda, int ldb, int ldc, int lde)
{
  __shared__ __align__(16) unsigned short As[2][64][40];
  __shared__ __align__(16) unsigned short Bs[2][64][40];
  const int bz = blockIdx.z;
  const float* A = Ag + (long)bz*sA;
  const float* Bp = Bg + (long)bz*sB;
  TO* C = Cg + (long)bz*sC;
  const float* E = Eg ? (Eg + (long)bz*sE) : nullptr;
  const int bm = blockIdx.x*64, bn = blockIdx.y*64;
  const int tid = threadIdx.x;
  const int lane = tid & 63, wid = tid >> 6;
  const int wr = (wid >> 1)*32, wc = (wid & 1)*32;
  const int fm = lane & 15, fk = (lane >> 4)*8;

  f32x4 acc[2][2];
  #pragma unroll
  for (int i=0;i<2;i++)
    #pragma unroll
    for (int j=0;j<2;j++) acc[i][j] = (f32x4){0.f,0.f,0.f,0.f};

  for (int k0 = 0; k0 < K; k0 += 32) {
    if (!TRA) {
      int k = tid & 31, m0 = tid >> 5;
      #pragma unroll
      for (int u = 0; u < 8; u++) {
        int m = m0 + u*8;
        float f = A[(long)(bm+m)*lda + k0 + k];
        unsigned short h = f2bs(f);
        As[0][m][k] = h;
        As[1][m][k] = f2bs(f - bs2f(h));
      }
    } else {
      int m = tid & 63, kk0 = tid >> 6;
      #pragma unroll
      for (int u = 0; u < 8; u++) {
        int k = kk0 + u*4;
        float f = A[(long)(k0+k)*lda + bm + m];
        unsigned short h = f2bs(f);
        As[0][m][k] = h;
        As[1][m][k] = f2bs(f - bs2f(h));
      }
    }
    if (TRB) {
      int k = tid & 31, n0 = tid >> 5;
      #pragma unroll
      for (int u = 0; u < 8; u++) {
        int n = n0 + u*8;
        float f = Bp[(long)(bn+n)*ldb + k0 + k];
        unsigned short h = f2bs(f);
        Bs[0][n][k] = h;
        Bs[1][n][k] = f2bs(f - bs2f(h));
      }
    } else {
      int n = tid & 63, kk0 = tid >> 6;
      #pragma unroll
      for (int u = 0; u < 8; u++) {
        int k = kk0 + u*4;
        float f = Bp[(long)(k0+k)*ldb + bn + n];
        unsigned short h = f2bs(f);
        Bs[0][n][k] = h;
        Bs[1][n][k] = f2bs(f - bs2f(h));
      }
    }
    __syncthreads();
    bfrag ah0 = *reinterpret_cast<const bfrag*>(&As[0][wr + fm][fk]);
    bfrag ah1 = *reinterpret_cast<const bfrag*>(&As[0][wr + 16 + fm][fk]);
    bfrag bh0 = *reinterpret_cast<const bfrag*>(&Bs[0][wc + fm][fk]);
    bfrag bh1 = *reinterpret_cast<const bfrag*>(&Bs[0][wc + 16 + fm][fk]);
    bfrag al0 = *reinterpret_cast<const bfrag*>(&As[1][wr + fm][fk]);
    bfrag al1 = *reinterpret_cast<const bfrag*>(&As[1][wr + 16 + fm][fk]);
    bfrag bl0 = *reinterpret_cast<const bfrag*>(&Bs[1][wc + fm][fk]);
    bfrag bl1 = *reinterpret_cast<const bfrag*>(&Bs[1][wc + 16 + fm][fk]);
    acc[0][0] = __builtin_amdgcn_mfma_f32_16x16x32_bf16(ah0, bh0, acc[0][0], 0,0,0);
    acc[0][1] = __builtin_amdgcn_mfma_f32_16x16x32_bf16(ah0, bh1, acc[0][1], 0,0,0);
    acc[1][0] = __builtin_amdgcn_mfma_f32_16x16x32_bf16(ah1, bh0, acc[1][0], 0,0,0);
    acc[1][1] = __builtin_amdgcn_mfma_f32_16x16x32_bf16(ah1, bh1, acc[1][1], 0,0,0);
    acc[0][0] = __builtin_amdgcn_mfma_f32_16x16x32_bf16(ah0, bl0, acc[0][0], 0,0,0);
    acc[0][1] = __builtin_amdgcn_mfma_f32_16x16x32_bf16(ah0, bl1, acc[0][1], 0,0,0);
    acc[1][0] = __builtin_amdgcn_mfma_f32_16x16x32_bf16(ah1, bl0, acc[1][0], 0,0,0);
    acc[1][1] = __builtin_amdgcn_mfma_f32_16x16x32_bf16(ah1, bl1, acc[1][1], 0,0,0);
    acc[0][0] = __builtin_amdgcn_mfma_f32_16x16x32_bf16(al0, bh0, acc[0][0], 0,0,0);
    acc[0][1] = __builtin_amdgcn_mfma_f32_16x16x32_bf16(al0, bh1, acc[0][1], 0,0,0);
    acc[1][0] = __builtin_amdgcn_mfma_f32_16x16x32_bf16(al1, bh0, acc[1][0], 0,0,0);
    acc[1][1] = __builtin_amdgcn_mfma_f32_16x16x32_bf16(al1, bh1, acc[1][1], 0,0,0);
    __syncthreads();
  }

  #pragma unroll
  for (int i=0;i<2;i++) {
    #pragma unroll
    for (int j=0;j<2;j++) {
      #pragma unroll
      for (int r=0;r<4;r++) {
        int row = bm + wr + i*16 + (lane>>4)*4 + r;
        int col = bn + wc + j*16 + fm;
        float v = acc[i][j][r];
        if (EPI == EPI_SILU)          v = v / (1.f + __expf(-v));
        else if (EPI == EPI_SUB)      v = v - E[(long)row*lde + col];
        else if (EPI == EPI_LINCOMB)  v = a0*E[(long)row*lde + col] + a1*v;
        else if (EPI == EPI_MUL)      v = v * E[(long)row*lde + col];
        else if (EPI == EPI_ADD)      v = v + E[(long)row*lde + col];
        else if (EPI == EPI_SILU_MUL) v = (v / (1.f + __expf(-v))) * E[(long)row*lde + col];
        stf(&C[(long)row*ldc + col], v);
      }
    }
  }
}

// xn = x * nw * rsqrt(mean(x^2)+eps); one block per row
__global__ __launch_bounds__(256) void rmsnorm_in_k(const float* __restrict__ x,
    const float* __restrict__ w, float* __restrict__ xn)
{
  __shared__ float sbuf[4];
  long row = blockIdx.x;
  const float* xr = x + row*SD;
  int c0 = threadIdx.x, c1 = threadIdx.x + 256;
  float v0 = xr[c0], v1 = xr[c1];
  float ss = block_sum256(v0*v0 + v1*v1, sbuf);
  float r = rsqrtf(ss*(1.f/SD) + 1e-6f);
  xn[row*SD + c0] = v0*r*w[c0];
  xn[row*SD + c1] = v1*r*w[c1];
}

// dst_row = rms(silu(dwconv3(raw_row))) * nw ;  one block per (t, b)
__global__ __launch_bounds__(256) void conv_silu_rms_k(const float* __restrict__ raw,
    const float* __restrict__ cw, const float* __restrict__ cb, const float* __restrict__ nw,
    float* __restrict__ dst, long dstBatchStride, int dstRowOff)
{
  __shared__ float sbuf[4];
  int t = blockIdx.x, b = blockIdx.y;
  const float* base = raw + ((long)b*SS + t)*SD;
  float vals[2];
  #pragma unroll
  for (int u = 0; u < 2; u++) {
    int c = threadIdx.x + u*256;
    float w0 = cw[c*3+0], w1 = cw[c*3+1], w2 = cw[c*3+2];
    float acc = cb[c];
    if (t > 0)     acc += base[c - SD]*w0;
    acc += base[c]*w1;
    if (t < SS-1)  acc += base[c + SD]*w2;
    vals[u] = acc / (1.f + __expf(-acc));
  }
  float ss = block_sum256(vals[0]*vals[0] + vals[1]*vals[1], sbuf);
  float r = rsqrtf(ss*(1.f/SD) + 1e-6f);
  float* out = dst + (long)b*dstBatchStride + (long)(dstRowOff + t)*SD;
  out[threadIdx.x]       = vals[0]*r*nw[threadIdx.x];
  out[threadIdx.x + 256] = vals[1]*r*nw[threadIdx.x + 256];
}

// per-(b,chunk) column means of a [B*S, 512] buffer -> [B*NCH, 512]
__global__ __launch_bounds__(256) void chunk_means1_k(const float* __restrict__ src,
    float* __restrict__ dst)
{
  int cb = blockIdx.x;
  long rowbase = (long)cb*SCH*SD;
  #pragma unroll
  for (int u = 0; u < 2; u++) {
    int col = threadIdx.x + u*256;
    float s = 0.f;
    for (int r = 0; r < SCH; r++) s += src[rowbase + (long)r*SD + col];
    dst[(long)cb*SD + col] = s * (1.f/SCH);
  }
}

// atlas epilogue (in place): t = rms(a)*nw_out*gb; a = rms(t)*n1_w
__global__ __launch_bounds__(256) void atlas_final_norm_k(float* __restrict__ a,
    const float* __restrict__ gb, const float* __restrict__ nwout,
    const float* __restrict__ n1w)
{
  __shared__ float sbuf[4];
  long row = blockIdx.x;
  float* xr = a + row*SD;
  int c0 = threadIdx.x, c1 = threadIdx.x + 256;
  float v0 = xr[c0], v1 = xr[c1];
  float ss = block_sum256(v0*v0 + v1*v1, sbuf);
  float r = rsqrtf(ss*(1.f/SD) + 1e-6f);
  float t0 = v0*r*nwout[c0] * gb[row*SD+c0];
  float t1 = v1*r*nwout[c1] * gb[row*SD+c1];
  float ss2 = block_sum256(t0*t0 + t1*t1, sbuf);
  float r2 = rsqrtf(ss2*(1.f/SD) + 1e-6f);
  xr[c0] = t0*r2*n1w[c0];
  xr[c1] = t1*r2*n1w[c1];
}

// dst = rms(o)*w + dst  (in place on dst)
__global__ __launch_bounds__(256) void rms_add_k(const float* __restrict__ o,
    const float* __restrict__ w, float* __restrict__ dst)
{
  __shared__ float sbuf[4];
  long row = blockIdx.x;
  const float* xr = o + row*SD;
  int c0 = threadIdx.x, c1 = threadIdx.x + 256;
  float v0 = xr[c0], v1 = xr[c1];
  float ss = block_sum256(v0*v0 + v1*v1, sbuf);
  float r = rsqrtf(ss*(1.f/SD) + 1e-6f);
  dst[row*SD+c0] += v0*r*w[c0];
  dst[row*SD+c1] += v1*r*w[c1];
}

// sliding-window attention, one wave per (b, h, query); 4 waves/block
__global__ __launch_bounds__(256) void attn_swa_k(const float* __restrict__ Q,
    const float* __restrict__ K, const float* __restrict__ V, float* __restrict__ O)
{
  __shared__ float sc[4][SWIN];
  int wid = threadIdx.x >> 6, lane = threadIdx.x & 63;
  int w = blockIdx.x*4 + wid;
  int b = w >> 14;
  int rem = w & 16383;
  int h = rem >> 11;
  int i = rem & (SS-1);
  const float* qp = Q + ((long)b*SS + i)*SD + h*64;
  float qv = qp[lane];
  int j0 = i - (SWIN-1); if (j0 < 0) j0 = 0;
  int cnt = i - j0 + 1;
  const float* Kb = K + (long)b*SS*SD + h*64;
  const float* Vb = V + (long)b*SS*SD + h*64;
  float mx = -1e30f;
  for (int jj = 0; jj < cnt; jj++) {
    float p = qv * Kb[(long)(j0+jj)*SD + lane];
    #pragma unroll
    for (int o2 = 32; o2 > 0; o2 >>= 1) p += __shfl_xor(p, o2);
    p *= 0.125f;
    if (lane == 0) sc[wid][jj] = p;
    mx = fmaxf(mx, p);
  }
  __syncthreads();
  float sum = 0.f, oa = 0.f;
  for (int jj = 0; jj < cnt; jj++) {
    float p = __expf(sc[wid][jj] - mx);
    sum += p;
    oa += p * Vb[(long)(j0+jj)*SD + lane];
  }
  O[((long)b*SS + i)*SD + h*64 + lane] = oa / sum;
}

__global__ __launch_bounds__(256) void copy_f_k(float* __restrict__ dst, long dstride,
    const float* __restrict__ src, long sstride, long nper, int nb)
{
  long total = nper * nb;
  for (long i = (long)blockIdx.x*256 + threadIdx.x; i < total; i += (long)gridDim.x*256) {
    long b = i / nper, r = i - b*nper;
    dst[b*dstride + r] = src[b*sstride + r];
  }
}

// f32 -> hi/lo bf16 planes
__global__ __launch_bounds__(256) void split_k(unsigned short* __restrict__ dst,
    long dBatch, long dPlane, const float* __restrict__ src, long sBatch,
    long nper, int nb)
{
  long total = nper * nb;
  for (long i = (long)blockIdx.x*256 + threadIdx.x; i < total; i += (long)gridDim.x*256) {
    long b = i / nper, r = i - b*nper;
    float f = src[b*sBatch + r];
    unsigned short h = f2bs(f);
    dst[b*dBatch + r]          = h;
    dst[b*dBatch + dPlane + r] = f2bs(f - bs2f(h));
  }
}

// hi/lo planes -> f32
__global__ __launch_bounds__(256) void merge_k(float* __restrict__ dst, long dBatch,
    const unsigned short* __restrict__ src, long sBatch, long sPlane, long nper, int nb)
{
  long total = nper * nb;
  for (long i = (long)blockIdx.x*256 + threadIdx.x; i < total; i += (long)gridDim.x*256) {
    long b = i / nper, r = i - b*nper;
    dst[b*dBatch + r] = bs2f(src[b*sBatch + r]) + bs2f(src[b*sBatch + sPlane + r]);
  }
}

extern "C" void kernel_launch(void* const* d_in, const int* in_sizes, int n_in,
                              void* d_out, int out_size, void* d_ws, size_t ws_size,
                              hipStream_t stream)
{
  (void)in_sizes; (void)n_in; (void)out_size; (void)ws_size;
  const float* x      = (const float*)d_in[0];
  const float* mem0   = (const float*)d_in[1];
  const float* buf_k  = (const float*)d_in[2];
  const float* buf_v  = (const float*)d_in[3];
  const float* nw_in  = (const float*)d_in[4];
  const float* nw_kq  = (const float*)d_in[5];
  const float* nw_out = (const float*)d_in[6];
  const float* wk_a   = (const float*)d_in[7];
  const float* wq_a   = (const float*)d_in[8];
  const float* wv_a   = (const float*)d_in[9];
  const float* wg     = (const float*)d_in[10];
  const float* wb     = (const float*)d_in[11];
  const float* ck_w   = (const float*)d_in[12];
  const float* ck_b   = (const float*)d_in[13];
  const float* cq_w   = (const float*)d_in[14];
  const float* cq_b   = (const float*)d_in[15];
  const float* s1_wq  = (const float*)d_in[16];
  const float* s1_wk  = (const float*)d_in[17];
  const float* s1_wv  = (const float*)d_in[18];
  const float* s1_wo  = (const float*)d_in[19];
  const float* s2_wq  = (const float*)d_in[20];
  const float* s2_wk  = (const float*)d_in[21];
  const float* s2_wv  = (const float*)d_in[22];
  const float* s2_wo  = (const float*)d_in[23];
  const float* n1_w   = (const float*)d_in[24];
  const float* n2_w   = (const float*)d_in[25];
  const float* m_w1   = (const float*)d_in[26];
  const float* m_w2   = (const float*)d_in[27];
  const float* m_w3   = (const float*)d_in[28];
  float* ob = (float*)d_out;

  // ---- workspace carve: f32 section (~56MB) + u16 split arena (~29MB) ----
  float* p = (float*)d_ws;
  float* kp   = p; p += SB*KPBATCH;   // padded k f32; C: attn out; MLP: h1 head
  float* vp   = p; p += SB*KPBATCH;   // padded v f32; C: oproj1 out
  float* qbuf = p; p += SB*BSD;       // atlas q f32; C: v1/v2
  float* gb   = p; p += SB*BSD;       // gamma*bypass; C: k1/k2; MLP: h1 tail
  float* sc1  = p; p += SB*BSD;       // xn; C: q1/q2, y
  float* sc2  = p; p += SB*BSD;       // kraw/qraw; B: aout; C: memn->fused
  float* Mb   = p; p += SB*DD;        // mem0 f32 (split source)
  float* X0   = p; p += SB*DD;        // grad f32 (frob input)
  float* etaM = p; p += (long)SB*SNCH*SD;
  float* alphaM = p; p += (long)SB*SNCH*SD;
  float* partials = p; p += 512;
  unsigned* barArea = (unsigned*)p; p += 640;  // flags[512] ... gen at [576] (own line)
  unsigned short* us = (unsigned short*)p;
  unsigned short* khl = us; us += SB*2*KPBATCH;
  unsigned short* qhl = us; us += SB*2*BSD;
  unsigned short* Mhl = us; us += SB*2*DD;
  unsigned short* Xhl = us; us += SB*2*DD;
  unsigned short* Yhl = us; us += SB*2*DD;
  unsigned short* Ahl = us; us += SB*2*DD;
  unsigned short* Thl = us; us += SB*2*DD;
  unsigned short* errhl = us; us += SB*2*ERRN;
  float* nsbuf = (float*)khl;         // phase-A scratch (before splits)
  float* aout = sc2;
  float* hbuf = kp;                   // MLP h1/h2: kp..gb span

  dim3 blk(256);

  hipMemsetAsync(barArea, 0, 640*4, stream);   // flags + gen = 0 each call

  // ================= Phase A =================
  rmsnorm_in_k<<<SB*SS, blk, 0, stream>>>(x, nw_in, sc1);

  mgemm_k<false,true,EPI_SILU,float><<<dim3(32,8,2),blk,0,stream>>>(
      sc1, wv_a, vp + (long)SWIN*SD, nullptr, 0.f,0.f, SS, SD, SD,
      BSD, 0, KPBATCH, 0, SD, SD, SD, 0);

  mgemm_k<false,true,EPI_NONE,float><<<dim3(64,8,1),blk,0,stream>>>(
      sc1, wk_a, sc2, nullptr, 0.f,0.f, SB*SS, SD, SD, 0,0,0,0, SD,SD,SD,0);
  conv_silu_rms_k<<<dim3(SS,SB),blk,0,stream>>>(sc2, ck_w, ck_b, nw_kq, kp, KPBATCH, SWIN);

  mgemm_k<false,true,EPI_NONE,float><<<dim3(64,8,1),blk,0,stream>>>(
      sc1, wq_a, sc2, nullptr, 0.f,0.f, SB*SS, SD, SD, 0,0,0,0, SD,SD,SD,0);
  conv_silu_rms_k<<<dim3(SS,SB),blk,0,stream>>>(sc2, cq_w, cq_b, nw_kq, qbuf, BSD, 0);

  mgemm_k<false,true,EPI_SILU,float><<<dim3(64,8,1),blk,0,stream>>>(
      sc1, wg, gb, nullptr, 0.f,0.f, SB*SS, SD, SD, 0,0,0,0, SD,SD,SD,0);
  mgemm_k<false,true,EPI_SILU_MUL,float><<<dim3(64,8,1),blk,0,stream>>>(
      sc1, wb, gb, gb, 0.f,0.f, SB*SS, SD, SD, 0,0,0,0, SD,SD,SD,SD);

  mgemm_k<false,true,EPI_SILU,float><<<dim3(64,8,1),blk,0,stream>>>(
      sc1, wg + (long)SD*SD, nsbuf, nullptr, 0.f,0.f, SB*SS, SD, SD, 0,0,0,0, SD,SD,SD,0);
  chunk_means1_k<<<SB*SNCH, blk, 0, stream>>>(nsbuf, etaM);
  mgemm_k<false,true,EPI_SILU,float><<<dim3(64,8,1),blk,0,stream>>>(
      sc1, wg + 2L*SD*SD, nsbuf, nullptr, 0.f,0.f, SB*SS, SD, SD, 0,0,0,0, SD,SD,SD,0);
  chunk_means1_k<<<SB*SNCH, blk, 0, stream>>>(nsbuf, alphaM);

  copy_f_k<<<256,blk,0,stream>>>(kp, KPBATCH, buf_k, (long)SWIN*SD, (long)SWIN*SD, SB);
  copy_f_k<<<256,blk,0,stream>>>(vp, KPBATCH, buf_v, (long)SWIN*SD, (long)SWIN*SD, SB);
  copy_f_k<<<256,blk,0,stream>>>(Mb, DD, mem0, DD, DD, SB);

  // split once for the scan (AFTER nsbuf is dead)
  split_k<<<512,blk,0,stream>>>(khl, 2*KPBATCH, KPBATCH, kp, KPBATCH, KPBATCH, SB);
  split_k<<<512,blk,0,stream>>>(qhl, 2*BSD, BSD, qbuf, BSD, BSD, SB);
  split_k<<<256,blk,0,stream>>>(Mhl, 2*DD, DD, Mb, DD, DD, SB);

  // ================= Phase B: one persistent kernel =================
  scan_persist_k<<<NBLK, blk, 0, stream>>>(
      khl, qhl, Mhl, Xhl, Yhl, Ahl, Thl, errhl,
      vp, X0, aout, etaM, alphaM, partials,
      &barArea[0], &barArea[576]);

  // ================= Phase C =================
  atlas_final_norm_k<<<SB*SS,blk,0,stream>>>(sc2, gb, nw_out, n1_w);

  // side outputs (before kp/vp reuse)
  merge_k<<<256,blk,0,stream>>>(ob + (long)SB*SS*SD, DD, Mhl, 2*DD, DD, DD, SB);
  copy_f_k<<<256,blk,0,stream>>>(ob + (long)SB*SS*SD + SB*DD, (long)SWIN*SD,
      kp + (long)SS*SD, KPBATCH, (long)SWIN*SD, SB);
  copy_f_k<<<256,blk,0,stream>>>(ob + (long)SB*SS*SD + SB*DD + (long)SB*SWIN*SD, (long)SWIN*SD,
      vp + (long)SS*SD, KPBATCH, (long)SWIN*SD, SB);

  // SWA 1 on x
  mgemm_k<false,true,EPI_NONE,float><<<dim3(64,8,1),blk,0,stream>>>(
      x, s1_wq, sc1, nullptr,0.f,0.f, SB*SS, SD, SD, 0,0,0,0, SD,SD,SD,0);
  mgemm_k<false,true,EPI_NONE,float><<<dim3(64,8,1),blk,0,stream>>>(
      x, s1_wk, gb, nullptr,0.f,0.f, SB*SS, SD, SD, 0,0,0,0, SD,SD,SD,0);
  mgemm_k<false,true,EPI_NONE,float><<<dim3(64,8,1),blk,0,stream>>>(
      x, s1_wv, qbuf, nullptr,0.f,0.f, SB*SS, SD, SD, 0,0,0,0, SD,SD,SD,0);
  attn_swa_k<<<SB*SH*SS/4, blk, 0, stream>>>(sc1, gb, qbuf, kp);
  mgemm_k<false,true,EPI_NONE,float><<<dim3(64,8,1),blk,0,stream>>>(
      kp, s1_wo, vp, nullptr,0.f,0.f, SB*SS, SD, SD, 0,0,0,0, SD,SD,SD,0);
  rms_add_k<<<SB*SS,blk,0,stream>>>(vp, n2_w, sc2);   // sc2 = fused

  // SWA 2 on fused
  mgemm_k<false,true,EPI_NONE,float><<<dim3(64,8,1),blk,0,stream>>>(
      sc2, s2_wq, sc1, nullptr,0.f,0.f, SB*SS, SD, SD, 0,0,0,0, SD,SD,SD,0);
  mgemm_k<false,true,EPI_NONE,float><<<dim3(64,8,1),blk,0,stream>>>(
      sc2, s2_wk, gb, nullptr,0.f,0.f, SB*SS, SD, SD, 0,0,0,0, SD,SD,SD,0);
  mgemm_k<false,true,EPI_NONE,float><<<dim3(64,8,1),blk,0,stream>>>(
      sc2, s2_wv, qbuf, nullptr,0.f,0.f, SB*SS, SD, SD, 0,0,0,0, SD,SD,SD,0);
  attn_swa_k<<<SB*SH*SS/4, blk, 0, stream>>>(sc1, gb, qbuf, kp);
  mgemm_k<false,true,EPI_NONE,float><<<dim3(64,8,1),blk,0,stream>>>(
      kp, s2_wo, sc1, nullptr,0.f,0.f, SB*SS, SD, SD, 0,0,0,0, SD,SD,SD,0); // y=sc1

  // MLP
  mgemm_k<false,true,EPI_SILU,float><<<dim3(64,32,1),blk,0,stream>>>(
      sc1, m_w1, hbuf, nullptr,0.f,0.f, SB*SS, SFF, SD, 0,0,0,0, SD,SD,SFF,0);
  mgemm_k<false,true,EPI_MUL,float><<<dim3(64,32,1),blk,0,stream>>>(
      sc1, m_w2, hbuf, hbuf, 0.f,0.f, SB*SS, SFF, SD, 0,0,0,0, SD,SD,SFF,SFF);
  mgemm_k<false,true,EPI_ADD,float><<<dim3(64,8,1),blk,0,stream>>>(
      hbuf, m_w3, ob, sc2, 0.f,0.f, SB*SS, SD, SFF, 0,0,0,0, SFF,SFF,SD,SD);
}

// Round 12
// 7357.307 us; speedup vs baseline: 9.4645x; 6.9876x over previous
//
#include <hip/hip_runtime.h>
#include <hip/hip_bf16.h>

typedef __hip_bfloat16 bf16;
typedef __attribute__((ext_vector_type(8))) short bfrag;            // 8 bf16 = 4 VGPRs
typedef __attribute__((ext_vector_type(8))) unsigned short u16x8;   // 16B copy unit
typedef __attribute__((ext_vector_type(4))) float f32x4;

#define SB 2
#define SS 2048
#define SD 512
#define SH 8
#define SWIN 128
#define SCH 64
#define SNCH 32
#define SFF 2048
#define KPROWS 2176              // WIN + S
#define KPBATCH 1114112L         // KPROWS*SD
#define BSD 1048576L             // SS*SD
#define DD 262144L               // SD*SD
#define ERRN 98304L              // 192*SD

__device__ __forceinline__ void stf(float* p, float v){ *p = v; }
__device__ __forceinline__ void stf(bf16* p, float v){ *p = __float2bfloat16(v); }

// f32 -> bf16 bits, round-to-nearest-even (finite inputs)
__device__ __forceinline__ unsigned short f2bs(float f){
  union { float f; unsigned int u; } v; v.f = f;
  unsigned int r = v.u + 0x7FFFu + ((v.u >> 16) & 1u);
  return (unsigned short)(r >> 16);
}
__device__ __forceinline__ float bs2f(unsigned short h){
  union { unsigned int u; float f; } v; v.u = ((unsigned int)h) << 16;
  return v.f;
}

__device__ __forceinline__ float block_sum256(float v, float* sbuf){
  #pragma unroll
  for (int o = 32; o > 0; o >>= 1) v += __shfl_xor(v, o);
  int wid = threadIdx.x >> 6;
  if ((threadIdx.x & 63) == 0) sbuf[wid] = v;
  __syncthreads();
  float r = sbuf[0] + sbuf[1] + sbuf[2] + sbuf[3];
  __syncthreads();
  return r;
}

enum { EPI_NONE=0, EPI_SILU=1, EPI_SUB=2, EPI_LINCOMB=3, EPI_MUL=4, EPI_ADD=5, EPI_SILU_MUL=6 };

// ===================== split-pair MFMA GEMM (scan) =====================
// Pre-split bf16 hi/lo planes; 3-term Dekker product, f32 accum.
// BM in {32,64}, BN=64. Double-buffered LDS, reg prefetch, 1 barrier/k-step.
// TRA: A given [K,M]. TRB: B given [N,K]. M%BM==N%64==K%32==0.
// MUPD: after epilogue value v, update Chl (as M in/out split pair):
//   M = M*alpha[col] - v*eta[col], per-batch row of alphaM/etaM selected by chunkIdx.
template<int BM, bool TRA, bool TRB, int EPI, bool EPAIR, bool OSPLIT, bool OF32, bool FROB, bool MUPD>
__global__ __launch_bounds__(256)
void sgemm_k(const unsigned short* __restrict__ Ahl, const unsigned short* __restrict__ Bhl,
             float* __restrict__ Cf, unsigned short* __restrict__ Chl,
             const float* __restrict__ Ef, const unsigned short* __restrict__ Ehl,
             float* __restrict__ frobOut,
             float a0, float a1, int M, int N, int K,
             long sA, long pA, long sB, long pB,
             long sCf, long sChl, long pC, long sE, long pE,
             int lda, int ldb, int ldc, int lde,
             const float* __restrict__ alphaM, const float* __restrict__ etaM, int chunkIdx)
{
  constexpr int MR = BM/32;                           // 1 (BM=32) or 2 (BM=64)
  __shared__ __align__(16) unsigned short As[2][2][BM][40];
  __shared__ __align__(16) unsigned short Bs[2][2][64][40];
  __shared__ float fb[4];
  const int bz = blockIdx.z;
  const unsigned short* A = Ahl + (long)bz*sA;
  const unsigned short* B = Bhl + (long)bz*sB;
  const int bm = blockIdx.x*BM, bn = blockIdx.y*64;
  const int tid = threadIdx.x;
  const int lane = tid & 63, wid = tid >> 6;
  const int wr = (wid >> 1)*16*MR, wc = (wid & 1)*32;
  const int fm = lane & 15, fk = (lane >> 4)*8;

  // staging address precompute
  int arow=0, acb=0, ak=0, am0=0, apl=0;
  if (!TRA) {
    if (BM==64){ arow=tid>>2; acb=(tid&3)<<3; }
    else { apl=tid>>7; int v=tid&127; arow=v>>2; acb=(v&3)<<3; }
  } else {
    if (BM==64){ ak=tid>>3; am0=(tid&7)<<3; }
    else { apl=tid>>7; int v=tid&127; ak=v>>2; am0=(v&3)<<3; }
  }
  int brow=0, bcb=0, bk=0, bn0=0;
  if (TRB){ brow=tid>>2; bcb=(tid&3)<<3; } else { bk=tid>>3; bn0=(tid&7)<<3; }

  u16x8 ra0, ra1, rb0, rb1;
  auto LOADA = [&](int k0){
    if (!TRA) {
      const unsigned short* a0 = A + (long)(bm+arow)*lda + k0 + acb;
      if (BM==64){ ra0 = *reinterpret_cast<const u16x8*>(a0);
                   ra1 = *reinterpret_cast<const u16x8*>(a0 + pA); }
      else       { ra0 = *reinterpret_cast<const u16x8*>(a0 + (apl ? pA : 0)); }
    } else {
      const unsigned short* a0 = A + (long)(k0+ak)*lda + bm + am0;
      if (BM==64){ ra0 = *reinterpret_cast<const u16x8*>(a0);
                   ra1 = *reinterpret_cast<const u16x8*>(a0 + pA); }
      else       { ra0 = *reinterpret_cast<const u16x8*>(a0 + (apl ? pA : 0)); }
    }
  };
  auto STOREA = [&](int buf){
    if (!TRA) {
      if (BM==64){ *reinterpret_cast<u16x8*>(&As[buf][0][arow][acb]) = ra0;
                   *reinterpret_cast<u16x8*>(&As[buf][1][arow][acb]) = ra1; }
      else       { *reinterpret_cast<u16x8*>(&As[buf][apl][arow][acb]) = ra0; }
    } else {
      if (BM==64){
        #pragma unroll
        for (int j=0;j<8;j++){ As[buf][0][am0+j][ak]=ra0[j]; As[buf][1][am0+j][ak]=ra1[j]; }
      } else {
        #pragma unroll
        for (int j=0;j<8;j++){ As[buf][apl][am0+j][ak]=ra0[j]; }
      }
    }
  };
  auto LOADB = [&](int k0){
    if (TRB) {
      const unsigned short* b0 = B + (long)(bn+brow)*ldb + k0 + bcb;
      rb0 = *reinterpret_cast<const u16x8*>(b0);
      rb1 = *reinterpret_cast<const u16x8*>(b0 + pB);
    } else {
      const unsigned short* b0 = B + (long)(k0+bk)*ldb + bn + bn0;
      rb0 = *reinterpret_cast<const u16x8*>(b0);
      rb1 = *reinterpret_cast<const u16x8*>(b0 + pB);
    }
  };
  auto STOREB = [&](int buf){
    if (TRB) {
      *reinterpret_cast<u16x8*>(&Bs[buf][0][brow][bcb]) = rb0;
      *reinterpret_cast<u16x8*>(&Bs[buf][1][brow][bcb]) = rb1;
    } else {
      #pragma unroll
      for (int j=0;j<8;j++){ Bs[buf][0][bn0+j][bk]=rb0[j]; Bs[buf][1][bn0+j][bk]=rb1[j]; }
    }
  };

  f32x4 acc[MR][2];
  #pragma unroll
  for (int i=0;i<MR;i++)
    #pragma unroll
    for (int j=0;j<2;j++) acc[i][j] = (f32x4){0.f,0.f,0.f,0.f};

  const int nk = K >> 5;
  LOADA(0); LOADB(0);
  int buf = 0;
  for (int i = 0; i < nk; i++) {
    STOREA(buf); STOREB(buf);
    __syncthreads();
    if (i+1 < nk) { LOADA((i+1)<<5); LOADB((i+1)<<5); }
    bfrag ah[MR], al[MR], bh[2], bl[2];
    #pragma unroll
    for (int m=0;m<MR;m++){
      ah[m] = *reinterpret_cast<const bfrag*>(&As[buf][0][wr + m*16 + fm][fk]);
      al[m] = *reinterpret_cast<const bfrag*>(&As[buf][1][wr + m*16 + fm][fk]);
    }
    #pragma unroll
    for (int j=0;j<2;j++){
      bh[j] = *reinterpret_cast<const bfrag*>(&Bs[buf][0][wc + j*16 + fm][fk]);
      bl[j] = *reinterpret_cast<const bfrag*>(&Bs[buf][1][wc + j*16 + fm][fk]);
    }
    #pragma unroll
    for (int m=0;m<MR;m++)
      #pragma unroll
      for (int j=0;j<2;j++)
        acc[m][j] = __builtin_amdgcn_mfma_f32_16x16x32_bf16(ah[m], bh[j], acc[m][j], 0,0,0);
    #pragma unroll
    for (int m=0;m<MR;m++)
      #pragma unroll
      for (int j=0;j<2;j++)
        acc[m][j] = __builtin_amdgcn_mfma_f32_16x16x32_bf16(ah[m], bl[j], acc[m][j], 0,0,0);
    #pragma unroll
    for (int m=0;m<MR;m++)
      #pragma unroll
      for (int j=0;j<2;j++)
        acc[m][j] = __builtin_amdgcn_mfma_f32_16x16x32_bf16(al[m], bh[j], acc[m][j], 0,0,0);
    buf ^= 1;
  }

  const float* alR = MUPD ? (alphaM + ((long)(bz*32 + chunkIdx) << 9)) : nullptr;
  const float* etR = MUPD ? (etaM  + ((long)(bz*32 + chunkIdx) << 9)) : nullptr;

  float fs = 0.f;
  #pragma unroll
  for (int i=0;i<MR;i++) {
    #pragma unroll
    for (int j=0;j<2;j++) {
      #pragma unroll
      for (int r=0;r<4;r++) {
        int row = bm + wr + i*16 + (lane>>4)*4 + r;
        int col = bn + wc + j*16 + fm;
        float v = acc[i][j][r];
        if (EPI == EPI_SUB || EPI == EPI_LINCOMB) {
          long eidx = (long)bz*sE + (long)row*lde + col;
          float e = EPAIR ? (bs2f(Ehl[eidx]) + bs2f(Ehl[eidx + pE])) : Ef[eidx];
          if (EPI == EPI_SUB) v = v - e;
          else                v = a0*e + a1*v;
        }
        if (FROB) fs += v*v;
        if (OF32) Cf[(long)bz*sCf + (long)row*ldc + col] = v;
        if (OSPLIT) {
          long cidx = (long)bz*sChl + (long)row*ldc + col;
          unsigned short h = f2bs(v);
          Chl[cidx]      = h;
          Chl[cidx + pC] = f2bs(v - bs2f(h));
        }
        if (MUPD) {
          long mi = (long)bz*sChl + (long)row*ldc + col;
          float mo = bs2f(Chl[mi]) + bs2f(Chl[mi + pC]);
          float nv = mo*alR[col] - v*etR[col];
          unsigned short h = f2bs(nv);
          Chl[mi]      = h;
          Chl[mi + pC] = f2bs(nv - bs2f(h));
        }
      }
    }
  }
  if (FROB) {
    #pragma unroll
    for (int o = 32; o > 0; o >>= 1) fs += __shfl_xor(fs, o);
    if (lane == 0) fb[wid] = fs;
    __syncthreads();
    if (tid == 0)
      frobOut[bz*(gridDim.x*gridDim.y) + blockIdx.x*gridDim.y + blockIdx.y] =
          fb[0]+fb[1]+fb[2]+fb[3];
  }
}

// ===== one 32x32 output tile of a split-pair 3-term Dekker GEMM (device fn) =====
template<bool TRA, bool TRB, int EPI, bool EPAIR, bool OSPLIT, bool OF32>
__device__ __forceinline__ void gtile(
    const unsigned short* __restrict__ A, long pA, int lda,
    const unsigned short* __restrict__ B, long pB, int ldb,
    float* __restrict__ Cf, unsigned short* __restrict__ Chl, long pC, int ldc,
    const float* __restrict__ Ef, const unsigned short* __restrict__ Ehl, long pE, int lde,
    float a0, float a1,
    int K, int bm, int bn,
    unsigned short (*As)[2][32][40], unsigned short (*Bs)[2][32][40])
{
  const int tid = threadIdx.x;
  const int lane = tid & 63, wid = tid >> 6;
  const int wr = (wid >> 1) * 16, wc = (wid & 1) * 16;
  const int fm = lane & 15, fk = (lane >> 4) * 8;

  int aR=0, aC=0, aPl=0, tK=0, tM0=0, tPl=0;
  if (!TRA) { aR = tid >> 3; int s = tid & 7; aPl = s >> 2; aC = (s & 3) << 3; }
  else      { tK = tid & 31; int q = tid >> 5; tPl = q >> 2; tM0 = (q & 3) << 3; }
  int bR=0, bC=0, bPl=0, uK=0, uN0=0, uPl=0;
  if (TRB)  { bR = tid >> 3; int s = tid & 7; bPl = s >> 2; bC = (s & 3) << 3; }
  else      { uK = tid & 31; int q = tid >> 5; uPl = q >> 2; uN0 = (q & 3) << 3; }

  u16x8 ra, rb;
  auto LA = [&](int k0){
    if (!TRA) ra = *reinterpret_cast<const u16x8*>(A + (long)(bm+aR)*lda + k0 + aC + (aPl ? pA : 0));
    else      ra = *reinterpret_cast<const u16x8*>(A + (long)(k0+tK)*lda + bm + tM0 + (tPl ? pA : 0));
  };
  auto SA = [&](int buf){
    if (!TRA) *reinterpret_cast<u16x8*>(&(*As)[0][0][0] + ((long)buf*2 + aPl)*32*40 + aR*40 + aC) = ra;
    else {
      #pragma unroll
      for (int j=0;j<8;j++) As[buf][tPl][tM0+j][tK] = ra[j];
    }
  };
  auto LB = [&](int k0){
    if (TRB)  rb = *reinterpret_cast<const u16x8*>(B + (long)(bn+bR)*ldb + k0 + bC + (bPl ? pB : 0));
    else      rb = *reinterpret_cast<const u16x8*>(B + (long)(k0+uK)*ldb + bn + uN0 + (uPl ? pB : 0));
  };
  auto SBst = [&](int buf){
    if (TRB)  *reinterpret_cast<u16x8*>(&(*Bs)[0][0][0] + ((long)buf*2 + bPl)*32*40 + bR*40 + bC) = rb;
    else {
      #pragma unroll
      for (int j=0;j<8;j++) Bs[buf][uPl][uN0+j][uK] = rb[j];
    }
  };

  f32x4 acc = {0.f,0.f,0.f,0.f};
  const int nk = K >> 5;
  LA(0); LB(0);
  int buf = 0;
  for (int i = 0; i < nk; i++) {
    SA(buf); SBst(buf);
    __syncthreads();
    if (i+1 < nk) { LA((i+1)<<5); LB((i+1)<<5); }
    bfrag ah = *reinterpret_cast<const bfrag*>(&As[buf][0][wr+fm][fk]);
    bfrag al = *reinterpret_cast<const bfrag*>(&As[buf][1][wr+fm][fk]);
    bfrag bh = *reinterpret_cast<const bfrag*>(&Bs[buf][0][wc+fm][fk]);
    bfrag bl = *reinterpret_cast<const bfrag*>(&Bs[buf][1][wc+fm][fk]);
    acc = __builtin_amdgcn_mfma_f32_16x16x32_bf16(ah, bh, acc, 0,0,0);
    acc = __builtin_amdgcn_mfma_f32_16x16x32_bf16(ah, bl, acc, 0,0,0);
    acc = __builtin_amdgcn_mfma_f32_16x16x32_bf16(al, bh, acc, 0,0,0);
    buf ^= 1;
  }

  #pragma unroll
  for (int r=0;r<4;r++){
    int row = bm + wr + (lane>>4)*4 + r;
    int col = bn + wc + fm;
    float v = acc[r];
    if (EPI == EPI_SUB || EPI == EPI_LINCOMB) {
      float e;
      if (EPAIR){ long ei = (long)row*lde + col; e = bs2f(Ehl[ei]) + bs2f(Ehl[ei + pE]); }
      else      { e = Ef[(long)row*lde + col]; }
      v = (EPI == EPI_SUB) ? (v - e) : (a0*e + a1*v);
    }
    if (OF32) Cf[(long)row*ldc + col] = v;
    if (OSPLIT){
      long ci = (long)row*ldc + col;
      unsigned short h = f2bs(v);
      Chl[ci] = h; Chl[ci + pC] = f2bs(v - bs2f(h));
    }
  }
}

// ===== combined out(tOut) + err(tErr) dispatch: 256 flat blocks =====
// blocks [0,64): out = cq@M ; blocks [64,256): err = ck@M - cv
__global__ __launch_bounds__(256)
void out_err_k(const unsigned short* __restrict__ khl,
               const unsigned short* __restrict__ qhl,
               unsigned short* __restrict__ Mhl,
               unsigned short* __restrict__ errhl,
               const float* __restrict__ vp, float* __restrict__ aout,
               int tOut, int tErr)
{
  __shared__ __align__(16) unsigned short As[2][2][32][40];
  __shared__ __align__(16) unsigned short Bs[2][2][32][40];
  int bid = blockIdx.x;
  if (bid < 64) {
    if (tOut < 0) return;
    int b = bid >> 5, r = bid & 31, mt = r >> 4, nt = r & 15;
    long off = (long)tOut*SCH*SD;
    gtile<false,false,EPI_NONE,false,false,true>(
      qhl + (long)b*2*BSD + off, BSD, SD,
      Mhl + (long)b*2*DD, DD, SD,
      aout + (long)b*BSD + off, nullptr, 0, SD,
      nullptr, nullptr, 0, 0,
      0.f,0.f, SD, mt*32, nt*32, As, Bs);
  } else {
    if (tErr >= SNCH) return;
    int ti = bid - 64;
    int b = ti / 96, r = ti % 96, mt = r >> 4, nt = r & 15;
    long off = (long)tErr*SCH*SD;
    gtile<false,false,EPI_SUB,false,true,false>(
      khl + (long)b*2*KPBATCH + off, KPBATCH, SD,
      Mhl + (long)b*2*DD, DD, SD,
      nullptr, errhl + (long)b*2*ERRN, ERRN, SD,
      vp + (long)b*KPBATCH + off, nullptr, 0, SD,
      0.f,0.f, SD, mt*32, nt*32, As, Bs);
  }
}

// ===================== f32-input MFMA GEMM (phase A/C) =====================
template<bool TRA, bool TRB, int EPI, typename TO>
__global__ __launch_bounds__(256)
void mgemm_k(const float* __restrict__ Ag, const float* __restrict__ Bg, TO* __restrict__ Cg,
             const float* __restrict__ Eg, float a0, float a1,
             int M, int N, int K,
             long sA, long sB, long sC, long sE,
             int lda, int ldb, int ldc, int lde)
{
  __shared__ __align__(16) unsigned short As[2][64][40];
  __shared__ __align__(16) unsigned short Bs[2][64][40];
  const int bz = blockIdx.z;
  const float* A = Ag + (long)bz*sA;
  const float* Bp = Bg + (long)bz*sB;
  TO* C = Cg + (long)bz*sC;
  const float* E = Eg ? (Eg + (long)bz*sE) : nullptr;
  const int bm = blockIdx.x*64, bn = blockIdx.y*64;
  const int tid = threadIdx.x;
  const int lane = tid & 63, wid = tid >> 6;
  const int wr = (wid >> 1)*32, wc = (wid & 1)*32;
  const int fm = lane & 15, fk = (lane >> 4)*8;

  f32x4 acc[2][2];
  #pragma unroll
  for (int i=0;i<2;i++)
    #pragma unroll
    for (int j=0;j<2;j++) acc[i][j] = (f32x4){0.f,0.f,0.f,0.f};

  for (int k0 = 0; k0 < K; k0 += 32) {
    if (!TRA) {
      int k = tid & 31, m0 = tid >> 5;
      #pragma unroll
      for (int u = 0; u < 8; u++) {
        int m = m0 + u*8;
        float f = A[(long)(bm+m)*lda + k0 + k];
        unsigned short h = f2bs(f);
        As[0][m][k] = h;
        As[1][m][k] = f2bs(f - bs2f(h));
      }
    } else {
      int m = tid & 63, kk0 = tid >> 6;
      #pragma unroll
      for (int u = 0; u < 8; u++) {
        int k = kk0 + u*4;
        float f = A[(long)(k0+k)*lda + bm + m];
        unsigned short h = f2bs(f);
        As[0][m][k] = h;
        As[1][m][k] = f2bs(f - bs2f(h));
      }
    }
    if (TRB) {
      int k = tid & 31, n0 = tid >> 5;
      #pragma unroll
      for (int u = 0; u < 8; u++) {
        int n = n0 + u*8;
        float f = Bp[(long)(bn+n)*ldb + k0 + k];
        unsigned short h = f2bs(f);
        Bs[0][n][k] = h;
        Bs[1][n][k] = f2bs(f - bs2f(h));
      }
    } else {
      int n = tid & 63, kk0 = tid >> 6;
      #pragma unroll
      for (int u = 0; u < 8; u++) {
        int k = kk0 + u*4;
        float f = Bp[(long)(k0+k)*ldb + bn + n];
        unsigned short h = f2bs(f);
        Bs[0][n][k] = h;
        Bs[1][n][k] = f2bs(f - bs2f(h));
      }
    }
    __syncthreads();
    bfrag ah0 = *reinterpret_cast<const bfrag*>(&As[0][wr + fm][fk]);
    bfrag ah1 = *reinterpret_cast<const bfrag*>(&As[0][wr + 16 + fm][fk]);
    bfrag bh0 = *reinterpret_cast<const bfrag*>(&Bs[0][wc + fm][fk]);
    bfrag bh1 = *reinterpret_cast<const bfrag*>(&Bs[0][wc + 16 + fm][fk]);
    bfrag al0 = *reinterpret_cast<const bfrag*>(&As[1][wr + fm][fk]);
    bfrag al1 = *reinterpret_cast<const bfrag*>(&As[1][wr + 16 + fm][fk]);
    bfrag bl0 = *reinterpret_cast<const bfrag*>(&Bs[1][wc + fm][fk]);
    bfrag bl1 = *reinterpret_cast<const bfrag*>(&Bs[1][wc + 16 + fm][fk]);
    acc[0][0] = __builtin_amdgcn_mfma_f32_16x16x32_bf16(ah0, bh0, acc[0][0], 0,0,0);
    acc[0][1] = __builtin_amdgcn_mfma_f32_16x16x32_bf16(ah0, bh1, acc[0][1], 0,0,0);
    acc[1][0] = __builtin_amdgcn_mfma_f32_16x16x32_bf16(ah1, bh0, acc[1][0], 0,0,0);
    acc[1][1] = __builtin_amdgcn_mfma_f32_16x16x32_bf16(ah1, bh1, acc[1][1], 0,0,0);
    acc[0][0] = __builtin_amdgcn_mfma_f32_16x16x32_bf16(ah0, bl0, acc[0][0], 0,0,0);
    acc[0][1] = __builtin_amdgcn_mfma_f32_16x16x32_bf16(ah0, bl1, acc[0][1], 0,0,0);
    acc[1][0] = __builtin_amdgcn_mfma_f32_16x16x32_bf16(ah1, bl0, acc[1][0], 0,0,0);
    acc[1][1] = __builtin_amdgcn_mfma_f32_16x16x32_bf16(ah1, bl1, acc[1][1], 0,0,0);
    acc[0][0] = __builtin_amdgcn_mfma_f32_16x16x32_bf16(al0, bh0, acc[0][0], 0,0,0);
    acc[0][1] = __builtin_amdgcn_mfma_f32_16x16x32_bf16(al0, bh1, acc[0][1], 0,0,0);
    acc[1][0] = __builtin_amdgcn_mfma_f32_16x16x32_bf16(al1, bh0, acc[1][0], 0,0,0);
    acc[1][1] = __builtin_amdgcn_mfma_f32_16x16x32_bf16(al1, bh1, acc[1][1], 0,0,0);
    __syncthreads();
  }

  #pragma unroll
  for (int i=0;i<2;i++) {
    #pragma unroll
    for (int j=0;j<2;j++) {
      #pragma unroll
      for (int r=0;r<4;r++) {
        int row = bm + wr + i*16 + (lane>>4)*4 + r;
        int col = bn + wc + j*16 + fm;
        float v = acc[i][j][r];
        if (EPI == EPI_SILU)          v = v / (1.f + __expf(-v));
        else if (EPI == EPI_SUB)      v = v - E[(long)row*lde + col];
        else if (EPI == EPI_LINCOMB)  v = a0*E[(long)row*lde + col] + a1*v;
        else if (EPI == EPI_MUL)      v = v * E[(long)row*lde + col];
        else if (EPI == EPI_ADD)      v = v + E[(long)row*lde + col];
        else if (EPI == EPI_SILU_MUL) v = (v / (1.f + __expf(-v))) * E[(long)row*lde + col];
        stf(&C[(long)row*ldc + col], v);
      }
    }
  }
}

// xn = x * nw * rsqrt(mean(x^2)+eps); one block per row
__global__ __launch_bounds__(256) void rmsnorm_in_k(const float* __restrict__ x,
    const float* __restrict__ w, float* __restrict__ xn)
{
  __shared__ float sbuf[4];
  long row = blockIdx.x;
  const float* xr = x + row*SD;
  int c0 = threadIdx.x, c1 = threadIdx.x + 256;
  float v0 = xr[c0], v1 = xr[c1];
  float ss = block_sum256(v0*v0 + v1*v1, sbuf);
  float r = rsqrtf(ss*(1.f/SD) + 1e-6f);
  xn[row*SD + c0] = v0*r*w[c0];
  xn[row*SD + c1] = v1*r*w[c1];
}

// dst_row = rms(silu(dwconv3(raw_row))) * nw ;  one block per (t, b)
__global__ __launch_bounds__(256) void conv_silu_rms_k(const float* __restrict__ raw,
    const float* __restrict__ cw, const float* __restrict__ cb, const float* __restrict__ nw,
    float* __restrict__ dst, long dstBatchStride, int dstRowOff)
{
  __shared__ float sbuf[4];
  int t = blockIdx.x, b = blockIdx.y;
  const float* base = raw + ((long)b*SS + t)*SD;
  float vals[2];
  #pragma unroll
  for (int u = 0; u < 2; u++) {
    int c = threadIdx.x + u*256;
    float w0 = cw[c*3+0], w1 = cw[c*3+1], w2 = cw[c*3+2];
    float acc = cb[c];
    if (t > 0)     acc += base[c - SD]*w0;
    acc += base[c]*w1;
    if (t < SS-1)  acc += base[c + SD]*w2;
    vals[u] = acc / (1.f + __expf(-acc));
  }
  float ss = block_sum256(vals[0]*vals[0] + vals[1]*vals[1], sbuf);
  float r = rsqrtf(ss*(1.f/SD) + 1e-6f);
  float* out = dst + (long)b*dstBatchStride + (long)(dstRowOff + t)*SD;
  out[threadIdx.x]       = vals[0]*r*nw[threadIdx.x];
  out[threadIdx.x + 256] = vals[1]*r*nw[threadIdx.x + 256];
}

// per-(b,chunk) column means of a [B*S, 512] buffer -> [B*NCH, 512]
__global__ __launch_bounds__(256) void chunk_means1_k(const float* __restrict__ src,
    float* __restrict__ dst)
{
  int cb = blockIdx.x;
  long rowbase = (long)cb*SCH*SD;
  #pragma unroll
  for (int u = 0; u < 2; u++) {
    int col = threadIdx.x + u*256;
    float s = 0.f;
    for (int r = 0; r < SCH; r++) s += src[rowbase + (long)r*SD + col];
    dst[(long)cb*SD + col] = s * (1.f/SCH);
  }
}

// X0 *= 1/(||G||_F+1e-7) using 128 per-block slots; write split pair -> Xhl
__global__ __launch_bounds__(256) void ns_scale_split_k(const float* __restrict__ X,
    const float* __restrict__ part, unsigned short* __restrict__ Xhl)
{
  int b = blockIdx.y;
  float s = 0.f;
  for (int i = 0; i < 128; i++) s += part[b*128 + i];
  float scale = 1.f / (sqrtf(s) + 1e-7f);
  long base  = (long)b*DD + (long)blockIdx.x*4096;
  long obase = (long)b*2*DD + (long)blockIdx.x*4096;
  for (int i = threadIdx.x; i < 4096; i += 256) {
    float f = X[base + i] * scale;
    unsigned short h = f2bs(f);
    Xhl[obase + i]      = h;
    Xhl[obase + DD + i] = f2bs(f - bs2f(h));
  }
}

// atlas epilogue (in place): t = rms(a)*nw_out*gb; a = rms(t)*n1_w
__global__ __launch_bounds__(256) void atlas_final_norm_k(float* __restrict__ a,
    const float* __restrict__ gb, const float* __restrict__ nwout,
    const float* __restrict__ n1w)
{
  __shared__ float sbuf[4];
  long row = blockIdx.x;
  float* xr = a + row*SD;
  int c0 = threadIdx.x, c1 = threadIdx.x + 256;
  float v0 = xr[c0], v1 = xr[c1];
  float ss = block_sum256(v0*v0 + v1*v1, sbuf);
  float r = rsqrtf(ss*(1.f/SD) + 1e-6f);
  float t0 = v0*r*nwout[c0] * gb[row*SD+c0];
  float t1 = v1*r*nwout[c1] * gb[row*SD+c1];
  float ss2 = block_sum256(t0*t0 + t1*t1, sbuf);
  float r2 = rsqrtf(ss2*(1.f/SD) + 1e-6f);
  xr[c0] = t0*r2*n1w[c0];
  xr[c1] = t1*r2*n1w[c1];
}

// dst = rms(o)*w + dst  (in place on dst)
__global__ __launch_bounds__(256) void rms_add_k(const float* __restrict__ o,
    const float* __restrict__ w, float* __restrict__ dst)
{
  __shared__ float sbuf[4];
  long row = blockIdx.x;
  const float* xr = o + row*SD;
  int c0 = threadIdx.x, c1 = threadIdx.x + 256;
  float v0 = xr[c0], v1 = xr[c1];
  float ss = block_sum256(v0*v0 + v1*v1, sbuf);
  float r = rsqrtf(ss*(1.f/SD) + 1e-6f);
  dst[row*SD+c0] += v0*r*w[c0];
  dst[row*SD+c1] += v1*r*w[c1];
}

// sliding-window attention, one wave per (b, h, query); 4 waves/block
__global__ __launch_bounds__(256) void attn_swa_k(const float* __restrict__ Q,
    const float* __restrict__ K, const float* __restrict__ V, float* __restrict__ O)
{
  __shared__ float sc[4][SWIN];
  int wid = threadIdx.x >> 6, lane = threadIdx.x & 63;
  int w = blockIdx.x*4 + wid;
  int b = w >> 14;
  int rem = w & 16383;
  int h = rem >> 11;
  int i = rem & (SS-1);
  const float* qp = Q + ((long)b*SS + i)*SD + h*64;
  float qv = qp[lane];
  int j0 = i - (SWIN-1); if (j0 < 0) j0 = 0;
  int cnt = i - j0 + 1;
  const float* Kb = K + (long)b*SS*SD + h*64;
  const float* Vb = V + (long)b*SS*SD + h*64;
  float mx = -1e30f;
  for (int jj = 0; jj < cnt; jj++) {
    float p = qv * Kb[(long)(j0+jj)*SD + lane];
    #pragma unroll
    for (int o2 = 32; o2 > 0; o2 >>= 1) p += __shfl_xor(p, o2);
    p *= 0.125f;
    if (lane == 0) sc[wid][jj] = p;
    mx = fmaxf(mx, p);
  }
  __syncthreads();
  float sum = 0.f, oa = 0.f;
  for (int jj = 0; jj < cnt; jj++) {
    float p = __expf(sc[wid][jj] - mx);
    sum += p;
    oa += p * Vb[(long)(j0+jj)*SD + lane];
  }
  O[((long)b*SS + i)*SD + h*64 + lane] = oa / sum;
}

__global__ __launch_bounds__(256) void copy_f_k(float* __restrict__ dst, long dstride,
    const float* __restrict__ src, long sstride, long nper, int nb)
{
  long total = nper * nb;
  for (long i = (long)blockIdx.x*256 + threadIdx.x; i < total; i += (long)gridDim.x*256) {
    long b = i / nper, r = i - b*nper;
    dst[b*dstride + r] = src[b*sstride + r];
  }
}

// f32 -> hi/lo bf16 planes
__global__ __launch_bounds__(256) void split_k(unsigned short* __restrict__ dst,
    long dBatch, long dPlane, const float* __restrict__ src, long sBatch,
    long nper, int nb)
{
  long total = nper * nb;
  for (long i = (long)blockIdx.x*256 + threadIdx.x; i < total; i += (long)gridDim.x*256) {
    long b = i / nper, r = i - b*nper;
    float f = src[b*sBatch + r];
    unsigned short h = f2bs(f);
    dst[b*dBatch + r]          = h;
    dst[b*dBatch + dPlane + r] = f2bs(f - bs2f(h));
  }
}

// hi/lo planes -> f32
__global__ __launch_bounds__(256) void merge_k(float* __restrict__ dst, long dBatch,
    const unsigned short* __restrict__ src, long sBatch, long sPlane, long nper, int nb)
{
  long total = nper * nb;
  for (long i = (long)blockIdx.x*256 + threadIdx.x; i < total; i += (long)gridDim.x*256) {
    long b = i / nper, r = i - b*nper;
    dst[b*dBatch + r] = bs2f(src[b*sBatch + r]) + bs2f(src[b*sBatch + sPlane + r]);
  }
}

extern "C" void kernel_launch(void* const* d_in, const int* in_sizes, int n_in,
                              void* d_out, int out_size, void* d_ws, size_t ws_size,
                              hipStream_t stream)
{
  (void)in_sizes; (void)n_in; (void)out_size; (void)ws_size;
  const float* x      = (const float*)d_in[0];
  const float* mem0   = (const float*)d_in[1];
  const float* buf_k  = (const float*)d_in[2];
  const float* buf_v  = (const float*)d_in[3];
  const float* nw_in  = (const float*)d_in[4];
  const float* nw_kq  = (const float*)d_in[5];
  const float* nw_out = (const float*)d_in[6];
  const float* wk_a   = (const float*)d_in[7];
  const float* wq_a   = (const float*)d_in[8];
  const float* wv_a   = (const float*)d_in[9];
  const float* wg     = (const float*)d_in[10];
  const float* wb     = (const float*)d_in[11];
  const float* ck_w   = (const float*)d_in[12];
  const float* ck_b   = (const float*)d_in[13];
  const float* cq_w   = (const float*)d_in[14];
  const float* cq_b   = (const float*)d_in[15];
  const float* s1_wq  = (const float*)d_in[16];
  const float* s1_wk  = (const float*)d_in[17];
  const float* s1_wv  = (const float*)d_in[18];
  const float* s1_wo  = (const float*)d_in[19];
  const float* s2_wq  = (const float*)d_in[20];
  const float* s2_wk  = (const float*)d_in[21];
  const float* s2_wv  = (const float*)d_in[22];
  const float* s2_wo  = (const float*)d_in[23];
  const float* n1_w   = (const float*)d_in[24];
  const float* n2_w   = (const float*)d_in[25];
  const float* m_w1   = (const float*)d_in[26];
  const float* m_w2   = (const float*)d_in[27];
  const float* m_w3   = (const float*)d_in[28];
  float* ob = (float*)d_out;

  // ---- workspace carve: f32 section (~56MB) + u16 split arena (~29MB) ----
  float* p = (float*)d_ws;
  float* kp   = p; p += SB*KPBATCH;   // padded k f32; C: attn out; MLP: h1 head
  float* vp   = p; p += SB*KPBATCH;   // padded v f32; C: oproj1 out
  float* qbuf = p; p += SB*BSD;       // atlas q f32; C: v1/v2
  float* gb   = p; p += SB*BSD;       // gamma*bypass; C: k1/k2; MLP: h1 tail
  float* sc1  = p; p += SB*BSD;       // xn; C: q1/q2, y
  float* sc2  = p; p += SB*BSD;       // kraw/qraw; B: aout; C: memn->fused
  float* Mb   = p; p += SB*DD;        // mem0 f32 (split source)
  float* X0   = p; p += SB*DD;        // grad f32 (frob input)
  float* etaM = p; p += (long)SB*SNCH*SD;
  float* alphaM = p; p += (long)SB*SNCH*SD;
  float* partials = p; p += 512;
  unsigned short* us = (unsigned short*)p;
  unsigned short* khl = us; us += SB*2*KPBATCH;
  unsigned short* qhl = us; us += SB*2*BSD;
  unsigned short* Mhl = us; us += SB*2*DD;
  unsigned short* Xhl = us; us += SB*2*DD;
  unsigned short* Yhl = us; us += SB*2*DD;
  unsigned short* Ahl = us; us += SB*2*DD;
  unsigned short* Thl = us; us += SB*2*DD;
  unsigned short* errhl = us; us += SB*2*ERRN;
  float* nsbuf = (float*)khl;         // phase-A scratch (before splits)
  float* aout = sc2;
  float* hbuf = kp;                   // MLP h1/h2: kp..gb span

  dim3 blk(256);

  // ================= Phase A =================
  rmsnorm_in_k<<<SB*SS, blk, 0, stream>>>(x, nw_in, sc1);

  mgemm_k<false,true,EPI_SILU,float><<<dim3(32,8,2),blk,0,stream>>>(
      sc1, wv_a, vp + (long)SWIN*SD, nullptr, 0.f,0.f, SS, SD, SD,
      BSD, 0, KPBATCH, 0, SD, SD, SD, 0);

  mgemm_k<false,true,EPI_NONE,float><<<dim3(64,8,1),blk,0,stream>>>(
      sc1, wk_a, sc2, nullptr, 0.f,0.f, SB*SS, SD, SD, 0,0,0,0, SD,SD,SD,0);
  conv_silu_rms_k<<<dim3(SS,SB),blk,0,stream>>>(sc2, ck_w, ck_b, nw_kq, kp, KPBATCH, SWIN);

  mgemm_k<false,true,EPI_NONE,float><<<dim3(64,8,1),blk,0,stream>>>(
      sc1, wq_a, sc2, nullptr, 0.f,0.f, SB*SS, SD, SD, 0,0,0,0, SD,SD,SD,0);
  conv_silu_rms_k<<<dim3(SS,SB),blk,0,stream>>>(sc2, cq_w, cq_b, nw_kq, qbuf, BSD, 0);

  mgemm_k<false,true,EPI_SILU,float><<<dim3(64,8,1),blk,0,stream>>>(
      sc1, wg, gb, nullptr, 0.f,0.f, SB*SS, SD, SD, 0,0,0,0, SD,SD,SD,0);
  mgemm_k<false,true,EPI_SILU_MUL,float><<<dim3(64,8,1),blk,0,stream>>>(
      sc1, wb, gb, gb, 0.f,0.f, SB*SS, SD, SD, 0,0,0,0, SD,SD,SD,SD);

  mgemm_k<false,true,EPI_SILU,float><<<dim3(64,8,1),blk,0,stream>>>(
      sc1, wg + (long)SD*SD, nsbuf, nullptr, 0.f,0.f, SB*SS, SD, SD, 0,0,0,0, SD,SD,SD,0);
  chunk_means1_k<<<SB*SNCH, blk, 0, stream>>>(nsbuf, etaM);
  mgemm_k<false,true,EPI_SILU,float><<<dim3(64,8,1),blk,0,stream>>>(
      sc1, wg + 2L*SD*SD, nsbuf, nullptr, 0.f,0.f, SB*SS, SD, SD, 0,0,0,0, SD,SD,SD,0);
  chunk_means1_k<<<SB*SNCH, blk, 0, stream>>>(nsbuf, alphaM);

  copy_f_k<<<256,blk,0,stream>>>(kp, KPBATCH, buf_k, (long)SWIN*SD, (long)SWIN*SD, SB);
  copy_f_k<<<256,blk,0,stream>>>(vp, KPBATCH, buf_v, (long)SWIN*SD, (long)SWIN*SD, SB);
  copy_f_k<<<256,blk,0,stream>>>(Mb, DD, mem0, DD, DD, SB);

  // split once for the scan (AFTER nsbuf is dead)
  split_k<<<512,blk,0,stream>>>(khl, 2*KPBATCH, KPBATCH, kp, KPBATCH, KPBATCH, SB);
  split_k<<<512,blk,0,stream>>>(qhl, 2*BSD, BSD, qbuf, BSD, BSD, SB);
  split_k<<<256,blk,0,stream>>>(Mhl, 2*DD, DD, Mb, DD, DD, SB);

  // ================= Phase B: sequential chunk scan (multi-launch) =================
  // initial err for chunk 0 (no out yet)
  out_err_k<<<256,blk,0,stream>>>(khl, qhl, Mhl, errhl, vp, aout, -1, 0);

  for (int t = 0; t < SNCH; ++t) {
    const long off = (long)t*SCH*SD;
    // grad = ck^T @ err -> X0 (f32) + fused Frobenius partials
    sgemm_k<32,true,false,EPI_NONE,false,false,true,true,false><<<dim3(16,8,2),blk,0,stream>>>(
        khl + off, errhl, X0, nullptr, nullptr, nullptr, partials, 0.f,0.f,
        512, 512, 192,
        2*KPBATCH, KPBATCH, 2*ERRN, ERRN,
        DD, 0, 0, 0, 0,
        512,512,512,0, nullptr, nullptr, 0);
    ns_scale_split_k<<<dim3(64,2),blk,0,stream>>>(X0, partials, Xhl);
    // NS iterations 1..4 (full)
    unsigned short* Xc = Xhl; unsigned short* Xn = Yhl;
    for (int it = 0; it < 4; ++it) {
      sgemm_k<32,false,true,EPI_NONE,false,true,false,false,false><<<dim3(16,8,2),blk,0,stream>>>(
          Xc, Xc, nullptr, Ahl, nullptr, nullptr, nullptr, 0.f,0.f,
          512,512,512, 2*DD,DD, 2*DD,DD, 0, 2*DD,DD, 0,0, 512,512,512,0,
          nullptr, nullptr, 0);
      sgemm_k<32,false,true,EPI_LINCOMB,true,true,false,false,false><<<dim3(16,8,2),blk,0,stream>>>(
          Ahl, Ahl, nullptr, Thl, nullptr, Ahl, nullptr, -4.7750f, 2.0315f,
          512,512,512, 2*DD,DD, 2*DD,DD, 0, 2*DD,DD, 2*DD,DD, 512,512,512,512,
          nullptr, nullptr, 0);
      sgemm_k<32,false,false,EPI_LINCOMB,true,true,false,false,false><<<dim3(16,8,2),blk,0,stream>>>(
          Thl, Xc, nullptr, Xn, nullptr, Xc, nullptr, 3.4445f, 1.0f,
          512,512,512, 2*DD,DD, 2*DD,DD, 0, 2*DD,DD, 2*DD,DD, 512,512,512,512,
          nullptr, nullptr, 0);
      unsigned short* tmp = Xc; Xc = Xn; Xn = tmp;
    }
    // iter 5: A, T, then fused X5 + M-update (X5 never materialized)
    sgemm_k<32,false,true,EPI_NONE,false,true,false,false,false><<<dim3(16,8,2),blk,0,stream>>>(
        Xc, Xc, nullptr, Ahl, nullptr, nullptr, nullptr, 0.f,0.f,
        512,512,512, 2*DD,DD, 2*DD,DD, 0, 2*DD,DD, 0,0, 512,512,512,0,
        nullptr, nullptr, 0);
    sgemm_k<32,false,true,EPI_LINCOMB,true,true,false,false,false><<<dim3(16,8,2),blk,0,stream>>>(
        Ahl, Ahl, nullptr, Thl, nullptr, Ahl, nullptr, -4.7750f, 2.0315f,
        512,512,512, 2*DD,DD, 2*DD,DD, 0, 2*DD,DD, 2*DD,DD, 512,512,512,512,
        nullptr, nullptr, 0);
    // v = a*X4 + T@X4 ; M = M*alpha - v*eta  (split pair, in place on Mhl)
    sgemm_k<32,false,false,EPI_LINCOMB,true,false,false,false,true><<<dim3(16,8,2),blk,0,stream>>>(
        Thl, Xc, nullptr, Mhl, nullptr, Xc, nullptr, 3.4445f, 1.0f,
        512,512,512, 2*DD,DD, 2*DD,DD, 0, 2*DD, DD, 2*DD,DD, 512,512,512,512,
        alphaM, etaM, t);
    // out(t) = cq @ M  ||  err(t+1)
    out_err_k<<<256,blk,0,stream>>>(khl, qhl, Mhl, errhl, vp, aout, t, t+1);
  }

  // ================= Phase C =================
  atlas_final_norm_k<<<SB*SS,blk,0,stream>>>(sc2, gb, nw_out, n1_w);

  // side outputs (before kp/vp reuse)
  merge_k<<<256,blk,0,stream>>>(ob + (long)SB*SS*SD, DD, Mhl, 2*DD, DD, DD, SB);
  copy_f_k<<<256,blk,0,stream>>>(ob + (long)SB*SS*SD + SB*DD, (long)SWIN*SD,
      kp + (long)SS*SD, KPBATCH, (long)SWIN*SD, SB);
  copy_f_k<<<256,blk,0,stream>>>(ob + (long)SB*SS*SD + SB*DD + (long)SB*SWIN*SD, (long)SWIN*SD,
      vp + (long)SS*SD, KPBATCH, (long)SWIN*SD, SB);

  // SWA 1 on x
  mgemm_k<false,true,EPI_NONE,float><<<dim3(64,8,1),blk,0,stream>>>(
      x, s1_wq, sc1, nullptr,0.f,0.f, SB*SS, SD, SD, 0,0,0,0, SD,SD,SD,0);
  mgemm_k<false,true,EPI_NONE,float><<<dim3(64,8,1),blk,0,stream>>>(
      x, s1_wk, gb, nullptr,0.f,0.f, SB*SS, SD, SD, 0,0,0,0, SD,SD,SD,0);
  mgemm_k<false,true,EPI_NONE,float><<<dim3(64,8,1),blk,0,stream>>>(
      x, s1_wv, qbuf, nullptr,0.f,0.f, SB*SS, SD, SD, 0,0,0,0, SD,SD,SD,0);
  attn_swa_k<<<SB*SH*SS/4, blk, 0, stream>>>(sc1, gb, qbuf, kp);
  mgemm_k<false,true,EPI_NONE,float><<<dim3(64,8,1),blk,0,stream>>>(
      kp, s1_wo, vp, nullptr,0.f,0.f, SB*SS, SD, SD, 0,0,0,0, SD,SD,SD,0);
  rms_add_k<<<SB*SS,blk,0,stream>>>(vp, n2_w, sc2);   // sc2 = fused

  // SWA 2 on fused
  mgemm_k<false,true,EPI_NONE,float><<<dim3(64,8,1),blk,0,stream>>>(
      sc2, s2_wq, sc1, nullptr,0.f,0.f, SB*SS, SD, SD, 0,0,0,0, SD,SD,SD,0);
  mgemm_k<false,true,EPI_NONE,float><<<dim3(64,8,1),blk,0,stream>>>(
      sc2, s2_wk, gb, nullptr,0.f,0.f, SB*SS, SD, SD, 0,0,0,0, SD,SD,SD,0);
  mgemm_k<false,true,EPI_NONE,float><<<dim3(64,8,1),blk,0,stream>>>(
      sc2, s2_wv, qbuf, nullptr,0.f,0.f, SB*SS, SD, SD, 0,0,0,0, SD,SD,SD,0);
  attn_swa_k<<<SB*SH*SS/4, blk, 0, stream>>>(sc1, gb, qbuf, kp);
  mgemm_k<false,true,EPI_NONE,float><<<dim3(64,8,1),blk,0,stream>>>(
      kp, s2_wo, sc1, nullptr,0.f,0.f, SB*SS, SD, SD, 0,0,0,0, SD,SD,SD,0); // y=sc1

  // MLP
  mgemm_k<false,true,EPI_SILU,float><<<dim3(64,32,1),blk,0,stream>>>(
      sc1, m_w1, hbuf, nullptr,0.f,0.f, SB*SS, SFF, SD, 0,0,0,0, SD,SD,SFF,0);
  mgemm_k<false,true,EPI_MUL,float><<<dim3(64,32,1),blk,0,stream>>>(
      sc1, m_w2, hbuf, hbuf, 0.f,0.f, SB*SS, SFF, SD, 0,0,0,0, SD,SD,SFF,SFF);
  mgemm_k<false,true,EPI_ADD,float><<<dim3(64,8,1),blk,0,stream>>>(
      hbuf, m_w3, ob, sc2, 0.f,0.f, SB*SS, SD, SFF, 0,0,0,0, SFF,SFF,SD,SD);
}

// Round 13
// 6220.386 us; speedup vs baseline: 11.1944x; 1.1828x over previous
//
#include <hip/hip_runtime.h>
#include <hip/hip_bf16.h>

typedef __hip_bfloat16 bf16;
typedef __attribute__((ext_vector_type(8))) short bfrag;            // 8 bf16 = 4 VGPRs
typedef __attribute__((ext_vector_type(8))) unsigned short u16x8;   // 16B copy unit
typedef __attribute__((ext_vector_type(4))) float f32x4;

#define SB 2
#define SS 2048
#define SD 512
#define SH 8
#define SWIN 128
#define SCH 64
#define SNCH 32
#define SFF 2048
#define KPROWS 2176              // WIN + S
#define KPBATCH 1114112L         // KPROWS*SD
#define BSD 1048576L             // SS*SD
#define DD 262144L               // SD*SD
#define ERRN 98304L              // 192*SD

__device__ __forceinline__ void stf(float* p, float v){ *p = v; }
__device__ __forceinline__ void stf(bf16* p, float v){ *p = __float2bfloat16(v); }

// f32 -> bf16 bits, round-to-nearest-even (finite inputs)
__device__ __forceinline__ unsigned short f2bs(float f){
  union { float f; unsigned int u; } v; v.f = f;
  unsigned int r = v.u + 0x7FFFu + ((v.u >> 16) & 1u);
  return (unsigned short)(r >> 16);
}
__device__ __forceinline__ float bs2f(unsigned short h){
  union { unsigned int u; float f; } v; v.u = ((unsigned int)h) << 16;
  return v.f;
}

__device__ __forceinline__ float block_sum256(float v, float* sbuf){
  #pragma unroll
  for (int o = 32; o > 0; o >>= 1) v += __shfl_xor(v, o);
  int wid = threadIdx.x >> 6;
  if ((threadIdx.x & 63) == 0) sbuf[wid] = v;
  __syncthreads();
  float r = sbuf[0] + sbuf[1] + sbuf[2] + sbuf[3];
  __syncthreads();
  return r;
}

enum { EPI_NONE=0, EPI_SILU=1, EPI_SUB=2, EPI_LINCOMB=3, EPI_MUL=4, EPI_ADD=5, EPI_SILU_MUL=6 };

// ===================== 32x32-tile split-pair MFMA GEMM (scan) =====================
// Pre-split bf16 hi/lo planes; 3-term Dekker product, f32 accum.
// 4 waves, each one 16x16 quadrant. Double-buffered LDS, reg prefetch.
// TRA: A given [K,M]. TRB: B given [N,K]. M%32==N%32==K%32==0.
// SCL: 1 -> multiply result by 1/s^2, 2 -> by 1/s, where
//   s = sqrt(sum(partIn[bz*nPart .. +nPart])) + 1e-7  (nPart <= 256).
// MUPD: Chl treated as M in/out split pair: M = M*alpha[col] - v*eta[col].
template<bool TRA, bool TRB, int EPI, bool EPAIR, bool OSPLIT, bool OF32, bool FROB, bool MUPD, int SCL>
__global__ __launch_bounds__(256)
void sgemm32_k(const unsigned short* __restrict__ Ahl, const unsigned short* __restrict__ Bhl,
               float* __restrict__ Cf, unsigned short* __restrict__ Chl,
               const float* __restrict__ Ef, const unsigned short* __restrict__ Ehl,
               float* __restrict__ frobOut,
               const float* __restrict__ partIn, int nPart,
               float a0, float a1, int M, int N, int K,
               long sA, long pA, long sB, long pB,
               long sCf, long sChl, long pC, long sE, long pE,
               int lda, int ldb, int ldc, int lde,
               const float* __restrict__ alphaM, const float* __restrict__ etaM, int chunkIdx)
{
  __shared__ __align__(16) unsigned short As[2][2][32][40];
  __shared__ __align__(16) unsigned short Bs[2][2][32][40];
  __shared__ float fb[4];
  const int bz = blockIdx.z;
  const unsigned short* A = Ahl + (long)bz*sA;
  const unsigned short* B = Bhl + (long)bz*sB;
  const int bm = blockIdx.x*32, bn = blockIdx.y*32;
  const int tid = threadIdx.x;
  const int lane = tid & 63, wid = tid >> 6;
  const int wr = (wid >> 1)*16, wc = (wid & 1)*16;
  const int fm = lane & 15, fk = (lane >> 4)*8;

  int aR=0, aC=0, aPl=0, tK=0, tM0=0, tPl=0;
  if (!TRA) { aR = tid >> 3; int s = tid & 7; aPl = s >> 2; aC = (s & 3) << 3; }
  else      { tK = tid & 31; int q = tid >> 5; tPl = q >> 2; tM0 = (q & 3) << 3; }
  int bR=0, bC=0, bPl=0, uK=0, uN0=0, uPl=0;
  if (TRB)  { bR = tid >> 3; int s = tid & 7; bPl = s >> 2; bC = (s & 3) << 3; }
  else      { uK = tid & 31; int q = tid >> 5; uPl = q >> 2; uN0 = (q & 3) << 3; }

  u16x8 ra, rb;
  auto LA = [&](int k0){
    if (!TRA) ra = *reinterpret_cast<const u16x8*>(A + (long)(bm+aR)*lda + k0 + aC + (aPl ? pA : 0));
    else      ra = *reinterpret_cast<const u16x8*>(A + (long)(k0+tK)*lda + bm + tM0 + (tPl ? pA : 0));
  };
  auto SA = [&](int buf){
    if (!TRA) *reinterpret_cast<u16x8*>(&As[buf][aPl][aR][aC]) = ra;
    else {
      #pragma unroll
      for (int j=0;j<8;j++) As[buf][tPl][tM0+j][tK] = ra[j];
    }
  };
  auto LB = [&](int k0){
    if (TRB)  rb = *reinterpret_cast<const u16x8*>(B + (long)(bn+bR)*ldb + k0 + bC + (bPl ? pB : 0));
    else      rb = *reinterpret_cast<const u16x8*>(B + (long)(k0+uK)*ldb + bn + uN0 + (uPl ? pB : 0));
  };
  auto SBst = [&](int buf){
    if (TRB)  *reinterpret_cast<u16x8*>(&Bs[buf][bPl][bR][bC]) = rb;
    else {
      #pragma unroll
      for (int j=0;j<8;j++) Bs[buf][uPl][uN0+j][uK] = rb[j];
    }
  };

  f32x4 acc = {0.f,0.f,0.f,0.f};
  const int nk = K >> 5;
  LA(0); LB(0);
  int buf = 0;
  for (int i = 0; i < nk; i++) {
    SA(buf); SBst(buf);
    __syncthreads();
    if (i+1 < nk) { LA((i+1)<<5); LB((i+1)<<5); }
    bfrag ah = *reinterpret_cast<const bfrag*>(&As[buf][0][wr+fm][fk]);
    bfrag al = *reinterpret_cast<const bfrag*>(&As[buf][1][wr+fm][fk]);
    bfrag bh = *reinterpret_cast<const bfrag*>(&Bs[buf][0][wc+fm][fk]);
    bfrag bl = *reinterpret_cast<const bfrag*>(&Bs[buf][1][wc+fm][fk]);
    acc = __builtin_amdgcn_mfma_f32_16x16x32_bf16(ah, bh, acc, 0,0,0);
    acc = __builtin_amdgcn_mfma_f32_16x16x32_bf16(ah, bl, acc, 0,0,0);
    acc = __builtin_amdgcn_mfma_f32_16x16x32_bf16(al, bh, acc, 0,0,0);
    buf ^= 1;
  }

  float scl = 1.f;
  if (SCL) {
    float pv = (tid < nPart) ? partIn[(long)bz*nPart + tid] : 0.f;
    __syncthreads();                       // all LDS reads done before fb reuse
    float ssum = block_sum256(pv, fb);
    float s = sqrtf(ssum) + 1e-7f;
    scl = (SCL == 1) ? 1.f/(s*s) : 1.f/s;
  }

  const float* alR = MUPD ? (alphaM + ((long)(bz*32 + chunkIdx) << 9)) : nullptr;
  const float* etR = MUPD ? (etaM  + ((long)(bz*32 + chunkIdx) << 9)) : nullptr;

  float fs = 0.f;
  #pragma unroll
  for (int r=0;r<4;r++){
    int row = bm + wr + (lane>>4)*4 + r;
    int col = bn + wc + fm;
    float v = acc[r];
    if (EPI == EPI_SUB || EPI == EPI_LINCOMB) {
      long eidx = (long)bz*sE + (long)row*lde + col;
      float e = EPAIR ? (bs2f(Ehl[eidx]) + bs2f(Ehl[eidx + pE])) : Ef[eidx];
      if (EPI == EPI_SUB) v = v - e;
      else                v = a0*e + a1*v;
    }
    if (SCL) v *= scl;
    if (FROB) fs += v*v;
    if (OF32) Cf[(long)bz*sCf + (long)row*ldc + col] = v;
    if (OSPLIT) {
      long cidx = (long)bz*sChl + (long)row*ldc + col;
      unsigned short h = f2bs(v);
      Chl[cidx]      = h;
      Chl[cidx + pC] = f2bs(v - bs2f(h));
    }
    if (MUPD) {
      long mi = (long)bz*sChl + (long)row*ldc + col;
      float mo = bs2f(Chl[mi]) + bs2f(Chl[mi + pC]);
      float nv = mo*alR[col] - v*etR[col];
      unsigned short h = f2bs(nv);
      Chl[mi]      = h;
      Chl[mi + pC] = f2bs(nv - bs2f(h));
    }
  }
  if (FROB) {
    #pragma unroll
    for (int o = 32; o > 0; o >>= 1) fs += __shfl_xor(fs, o);
    if (lane == 0) fb[wid] = fs;
    __syncthreads();
    if (tid == 0)
      frobOut[(long)bz*(gridDim.x*gridDim.y) + blockIdx.x*gridDim.y + blockIdx.y] =
          fb[0]+fb[1]+fb[2]+fb[3];
  }
}

// ===== one 32x32 output tile of a split-pair 3-term Dekker GEMM (device fn) =====
template<bool TRA, bool TRB, int EPI, bool EPAIR, bool OSPLIT, bool OF32>
__device__ __forceinline__ void gtile(
    const unsigned short* __restrict__ A, long pA, int lda,
    const unsigned short* __restrict__ B, long pB, int ldb,
    float* __restrict__ Cf, unsigned short* __restrict__ Chl, long pC, int ldc,
    const float* __restrict__ Ef, const unsigned short* __restrict__ Ehl, long pE, int lde,
    float a0, float a1,
    int K, int bm, int bn,
    unsigned short (*As)[2][32][40], unsigned short (*Bs)[2][32][40])
{
  const int tid = threadIdx.x;
  const int lane = tid & 63, wid = tid >> 6;
  const int wr = (wid >> 1) * 16, wc = (wid & 1) * 16;
  const int fm = lane & 15, fk = (lane >> 4) * 8;

  int aR=0, aC=0, aPl=0, tK=0, tM0=0, tPl=0;
  if (!TRA) { aR = tid >> 3; int s = tid & 7; aPl = s >> 2; aC = (s & 3) << 3; }
  else      { tK = tid & 31; int q = tid >> 5; tPl = q >> 2; tM0 = (q & 3) << 3; }
  int bR=0, bC=0, bPl=0, uK=0, uN0=0, uPl=0;
  if (TRB)  { bR = tid >> 3; int s = tid & 7; bPl = s >> 2; bC = (s & 3) << 3; }
  else      { uK = tid & 31; int q = tid >> 5; uPl = q >> 2; uN0 = (q & 3) << 3; }

  u16x8 ra, rb;
  auto LA = [&](int k0){
    if (!TRA) ra = *reinterpret_cast<const u16x8*>(A + (long)(bm+aR)*lda + k0 + aC + (aPl ? pA : 0));
    else      ra = *reinterpret_cast<const u16x8*>(A + (long)(k0+tK)*lda + bm + tM0 + (tPl ? pA : 0));
  };
  auto SA = [&](int buf){
    if (!TRA) *reinterpret_cast<u16x8*>(&(*As)[0][0][0] + ((long)buf*2 + aPl)*32*40 + aR*40 + aC) = ra;
    else {
      #pragma unroll
      for (int j=0;j<8;j++) As[buf][tPl][tM0+j][tK] = ra[j];
    }
  };
  auto LB = [&](int k0){
    if (TRB)  rb = *reinterpret_cast<const u16x8*>(B + (long)(bn+bR)*ldb + k0 + bC + (bPl ? pB : 0));
    else      rb = *reinterpret_cast<const u16x8*>(B + (long)(k0+uK)*ldb + bn + uN0 + (uPl ? pB : 0));
  };
  auto SBst = [&](int buf){
    if (TRB)  *reinterpret_cast<u16x8*>(&(*Bs)[0][0][0] + ((long)buf*2 + bPl)*32*40 + bR*40 + bC) = rb;
    else {
      #pragma unroll
      for (int j=0;j<8;j++) Bs[buf][uPl][uN0+j][uK] = rb[j];
    }
  };

  f32x4 acc = {0.f,0.f,0.f,0.f};
  const int nk = K >> 5;
  LA(0); LB(0);
  int buf = 0;
  for (int i = 0; i < nk; i++) {
    SA(buf); SBst(buf);
    __syncthreads();
    if (i+1 < nk) { LA((i+1)<<5); LB((i+1)<<5); }
    bfrag ah = *reinterpret_cast<const bfrag*>(&As[buf][0][wr+fm][fk]);
    bfrag al = *reinterpret_cast<const bfrag*>(&As[buf][1][wr+fm][fk]);
    bfrag bh = *reinterpret_cast<const bfrag*>(&Bs[buf][0][wc+fm][fk]);
    bfrag bl = *reinterpret_cast<const bfrag*>(&Bs[buf][1][wc+fm][fk]);
    acc = __builtin_amdgcn_mfma_f32_16x16x32_bf16(ah, bh, acc, 0,0,0);
    acc = __builtin_amdgcn_mfma_f32_16x16x32_bf16(ah, bl, acc, 0,0,0);
    acc = __builtin_amdgcn_mfma_f32_16x16x32_bf16(al, bh, acc, 0,0,0);
    buf ^= 1;
  }

  #pragma unroll
  for (int r=0;r<4;r++){
    int row = bm + wr + (lane>>4)*4 + r;
    int col = bn + wc + fm;
    float v = acc[r];
    if (EPI == EPI_SUB || EPI == EPI_LINCOMB) {
      float e;
      if (EPAIR){ long ei = (long)row*lde + col; e = bs2f(Ehl[ei]) + bs2f(Ehl[ei + pE]); }
      else      { e = Ef[(long)row*lde + col]; }
      v = (EPI == EPI_SUB) ? (v - e) : (a0*e + a1*v);
    }
    if (OF32) Cf[(long)row*ldc + col] = v;
    if (OSPLIT){
      long ci = (long)row*ldc + col;
      unsigned short h = f2bs(v);
      Chl[ci] = h; Chl[ci + pC] = f2bs(v - bs2f(h));
    }
  }
}

// ===== combined out(tOut) + err(tErr) dispatch: 256 flat blocks =====
// blocks [0,64): out = cq@M ; blocks [64,256): err = ck@M - cv
__global__ __launch_bounds__(256)
void out_err_k(const unsigned short* __restrict__ khl,
               const unsigned short* __restrict__ qhl,
               unsigned short* __restrict__ Mhl,
               unsigned short* __restrict__ errhl,
               const float* __restrict__ vp, float* __restrict__ aout,
               int tOut, int tErr)
{
  __shared__ __align__(16) unsigned short As[2][2][32][40];
  __shared__ __align__(16) unsigned short Bs[2][2][32][40];
  int bid = blockIdx.x;
  if (bid < 64) {
    if (tOut < 0) return;
    int b = bid >> 5, r = bid & 31, mt = r >> 4, nt = r & 15;
    long off = (long)tOut*SCH*SD;
    gtile<false,false,EPI_NONE,false,false,true>(
      qhl + (long)b*2*BSD + off, BSD, SD,
      Mhl + (long)b*2*DD, DD, SD,
      aout + (long)b*BSD + off, nullptr, 0, SD,
      nullptr, nullptr, 0, 0,
      0.f,0.f, SD, mt*32, nt*32, As, Bs);
  } else {
    if (tErr >= SNCH) return;
    int ti = bid - 64;
    int b = ti / 96, r = ti % 96, mt = r >> 4, nt = r & 15;
    long off = (long)tErr*SCH*SD;
    gtile<false,false,EPI_SUB,false,true,false>(
      khl + (long)b*2*KPBATCH + off, KPBATCH, SD,
      Mhl + (long)b*2*DD, DD, SD,
      nullptr, errhl + (long)b*2*ERRN, ERRN, SD,
      vp + (long)b*KPBATCH + off, nullptr, 0, SD,
      0.f,0.f, SD, mt*32, nt*32, As, Bs);
  }
}

// ===================== f32-input MFMA GEMM (phase A/C) =====================
template<bool TRA, bool TRB, int EPI, typename TO>
__global__ __launch_bounds__(256)
void mgemm_k(const float* __restrict__ Ag, const float* __restrict__ Bg, TO* __restrict__ Cg,
             const float* __restrict__ Eg, float a0, float a1,
             int M, int N, int K,
             long sA, long sB, long sC, long sE,
             int lda, int ldb, int ldc, int lde)
{
  __shared__ __align__(16) unsigned short As[2][64][40];
  __shared__ __align__(16) unsigned short Bs[2][64][40];
  const int bz = blockIdx.z;
  const float* A = Ag + (long)bz*sA;
  const float* Bp = Bg + (long)bz*sB;
  TO* C = Cg + (long)bz*sC;
  const float* E = Eg ? (Eg + (long)bz*sE) : nullptr;
  const int bm = blockIdx.x*64, bn = blockIdx.y*64;
  const int tid = threadIdx.x;
  const int lane = tid & 63, wid = tid >> 6;
  const int wr = (wid >> 1)*32, wc = (wid & 1)*32;
  const int fm = lane & 15, fk = (lane >> 4)*8;

  f32x4 acc[2][2];
  #pragma unroll
  for (int i=0;i<2;i++)
    #pragma unroll
    for (int j=0;j<2;j++) acc[i][j] = (f32x4){0.f,0.f,0.f,0.f};

  for (int k0 = 0; k0 < K; k0 += 32) {
    if (!TRA) {
      int k = tid & 31, m0 = tid >> 5;
      #pragma unroll
      for (int u = 0; u < 8; u++) {
        int m = m0 + u*8;
        float f = A[(long)(bm+m)*lda + k0 + k];
        unsigned short h = f2bs(f);
        As[0][m][k] = h;
        As[1][m][k] = f2bs(f - bs2f(h));
      }
    } else {
      int m = tid & 63, kk0 = tid >> 6;
      #pragma unroll
      for (int u = 0; u < 8; u++) {
        int k = kk0 + u*4;
        float f = A[(long)(k0+k)*lda + bm + m];
        unsigned short h = f2bs(f);
        As[0][m][k] = h;
        As[1][m][k] = f2bs(f - bs2f(h));
      }
    }
    if (TRB) {
      int k = tid & 31, n0 = tid >> 5;
      #pragma unroll
      for (int u = 0; u < 8; u++) {
        int n = n0 + u*8;
        float f = Bp[(long)(bn+n)*ldb + k0 + k];
        unsigned short h = f2bs(f);
        Bs[0][n][k] = h;
        Bs[1][n][k] = f2bs(f - bs2f(h));
      }
    } else {
      int n = tid & 63, kk0 = tid >> 6;
      #pragma unroll
      for (int u = 0; u < 8; u++) {
        int k = kk0 + u*4;
        float f = Bp[(long)(k0+k)*ldb + bn + n];
        unsigned short h = f2bs(f);
        Bs[0][n][k] = h;
        Bs[1][n][k] = f2bs(f - bs2f(h));
      }
    }
    __syncthreads();
    bfrag ah0 = *reinterpret_cast<const bfrag*>(&As[0][wr + fm][fk]);
    bfrag ah1 = *reinterpret_cast<const bfrag*>(&As[0][wr + 16 + fm][fk]);
    bfrag bh0 = *reinterpret_cast<const bfrag*>(&Bs[0][wc + fm][fk]);
    bfrag bh1 = *reinterpret_cast<const bfrag*>(&Bs[0][wc + 16 + fm][fk]);
    bfrag al0 = *reinterpret_cast<const bfrag*>(&As[1][wr + fm][fk]);
    bfrag al1 = *reinterpret_cast<const bfrag*>(&As[1][wr + 16 + fm][fk]);
    bfrag bl0 = *reinterpret_cast<const bfrag*>(&Bs[1][wc + fm][fk]);
    bfrag bl1 = *reinterpret_cast<const bfrag*>(&Bs[1][wc + 16 + fm][fk]);
    acc[0][0] = __builtin_amdgcn_mfma_f32_16x16x32_bf16(ah0, bh0, acc[0][0], 0,0,0);
    acc[0][1] = __builtin_amdgcn_mfma_f32_16x16x32_bf16(ah0, bh1, acc[0][1], 0,0,0);
    acc[1][0] = __builtin_amdgcn_mfma_f32_16x16x32_bf16(ah1, bh0, acc[1][0], 0,0,0);
    acc[1][1] = __builtin_amdgcn_mfma_f32_16x16x32_bf16(ah1, bh1, acc[1][1], 0,0,0);
    acc[0][0] = __builtin_amdgcn_mfma_f32_16x16x32_bf16(ah0, bl0, acc[0][0], 0,0,0);
    acc[0][1] = __builtin_amdgcn_mfma_f32_16x16x32_bf16(ah0, bl1, acc[0][1], 0,0,0);
    acc[1][0] = __builtin_amdgcn_mfma_f32_16x16x32_bf16(ah1, bl0, acc[1][0], 0,0,0);
    acc[1][1] = __builtin_amdgcn_mfma_f32_16x16x32_bf16(ah1, bl1, acc[1][1], 0,0,0);
    acc[0][0] = __builtin_amdgcn_mfma_f32_16x16x32_bf16(al0, bh0, acc[0][0], 0,0,0);
    acc[0][1] = __builtin_amdgcn_mfma_f32_16x16x32_bf16(al0, bh1, acc[0][1], 0,0,0);
    acc[1][0] = __builtin_amdgcn_mfma_f32_16x16x32_bf16(al1, bh0, acc[1][0], 0,0,0);
    acc[1][1] = __builtin_amdgcn_mfma_f32_16x16x32_bf16(al1, bh1, acc[1][1], 0,0,0);
    __syncthreads();
  }

  #pragma unroll
  for (int i=0;i<2;i++) {
    #pragma unroll
    for (int j=0;j<2;j++) {
      #pragma unroll
      for (int r=0;r<4;r++) {
        int row = bm + wr + i*16 + (lane>>4)*4 + r;
        int col = bn + wc + j*16 + fm;
        float v = acc[i][j][r];
        if (EPI == EPI_SILU)          v = v / (1.f + __expf(-v));
        else if (EPI == EPI_SUB)      v = v - E[(long)row*lde + col];
        else if (EPI == EPI_LINCOMB)  v = a0*E[(long)row*lde + col] + a1*v;
        else if (EPI == EPI_MUL)      v = v * E[(long)row*lde + col];
        else if (EPI == EPI_ADD)      v = v + E[(long)row*lde + col];
        else if (EPI == EPI_SILU_MUL) v = (v / (1.f + __expf(-v))) * E[(long)row*lde + col];
        stf(&C[(long)row*ldc + col], v);
      }
    }
  }
}

// xn = x * nw * rsqrt(mean(x^2)+eps); one block per row
__global__ __launch_bounds__(256) void rmsnorm_in_k(const float* __restrict__ x,
    const float* __restrict__ w, float* __restrict__ xn)
{
  __shared__ float sbuf[4];
  long row = blockIdx.x;
  const float* xr = x + row*SD;
  int c0 = threadIdx.x, c1 = threadIdx.x + 256;
  float v0 = xr[c0], v1 = xr[c1];
  float ss = block_sum256(v0*v0 + v1*v1, sbuf);
  float r = rsqrtf(ss*(1.f/SD) + 1e-6f);
  xn[row*SD + c0] = v0*r*w[c0];
  xn[row*SD + c1] = v1*r*w[c1];
}

// dst_row = rms(silu(dwconv3(raw_row))) * nw ;  one block per (t, b)
__global__ __launch_bounds__(256) void conv_silu_rms_k(const float* __restrict__ raw,
    const float* __restrict__ cw, const float* __restrict__ cb, const float* __restrict__ nw,
    float* __restrict__ dst, long dstBatchStride, int dstRowOff)
{
  __shared__ float sbuf[4];
  int t = blockIdx.x, b = blockIdx.y;
  const float* base = raw + ((long)b*SS + t)*SD;
  float vals[2];
  #pragma unroll
  for (int u = 0; u < 2; u++) {
    int c = threadIdx.x + u*256;
    float w0 = cw[c*3+0], w1 = cw[c*3+1], w2 = cw[c*3+2];
    float acc = cb[c];
    if (t > 0)     acc += base[c - SD]*w0;
    acc += base[c]*w1;
    if (t < SS-1)  acc += base[c + SD]*w2;
    vals[u] = acc / (1.f + __expf(-acc));
  }
  float ss = block_sum256(vals[0]*vals[0] + vals[1]*vals[1], sbuf);
  float r = rsqrtf(ss*(1.f/SD) + 1e-6f);
  float* out = dst + (long)b*dstBatchStride + (long)(dstRowOff + t)*SD;
  out[threadIdx.x]       = vals[0]*r*nw[threadIdx.x];
  out[threadIdx.x + 256] = vals[1]*r*nw[threadIdx.x + 256];
}

// per-(b,chunk) column means of a [B*S, 512] buffer -> [B*NCH, 512]
__global__ __launch_bounds__(256) void chunk_means1_k(const float* __restrict__ src,
    float* __restrict__ dst)
{
  int cb = blockIdx.x;
  long rowbase = (long)cb*SCH*SD;
  #pragma unroll
  for (int u = 0; u < 2; u++) {
    int col = threadIdx.x + u*256;
    float s = 0.f;
    for (int r = 0; r < SCH; r++) s += src[rowbase + (long)r*SD + col];
    dst[(long)cb*SD + col] = s * (1.f/SCH);
  }
}

// atlas epilogue (in place): t = rms(a)*nw_out*gb; a = rms(t)*n1_w
__global__ __launch_bounds__(256) void atlas_final_norm_k(float* __restrict__ a,
    const float* __restrict__ gb, const float* __restrict__ nwout,
    const float* __restrict__ n1w)
{
  __shared__ float sbuf[4];
  long row = blockIdx.x;
  float* xr = a + row*SD;
  int c0 = threadIdx.x, c1 = threadIdx.x + 256;
  float v0 = xr[c0], v1 = xr[c1];
  float ss = block_sum256(v0*v0 + v1*v1, sbuf);
  float r = rsqrtf(ss*(1.f/SD) + 1e-6f);
  float t0 = v0*r*nwout[c0] * gb[row*SD+c0];
  float t1 = v1*r*nwout[c1] * gb[row*SD+c1];
  float ss2 = block_sum256(t0*t0 + t1*t1, sbuf);
  float r2 = rsqrtf(ss2*(1.f/SD) + 1e-6f);
  xr[c0] = t0*r2*n1w[c0];
  xr[c1] = t1*r2*n1w[c1];
}

// dst = rms(o)*w + dst  (in place on dst)
__global__ __launch_bounds__(256) void rms_add_k(const float* __restrict__ o,
    const float* __restrict__ w, float* __restrict__ dst)
{
  __shared__ float sbuf[4];
  long row = blockIdx.x;
  const float* xr = o + row*SD;
  int c0 = threadIdx.x, c1 = threadIdx.x + 256;
  float v0 = xr[c0], v1 = xr[c1];
  float ss = block_sum256(v0*v0 + v1*v1, sbuf);
  float r = rsqrtf(ss*(1.f/SD) + 1e-6f);
  dst[row*SD+c0] += v0*r*w[c0];
  dst[row*SD+c1] += v1*r*w[c1];
}

// sliding-window attention, one wave per (b, h, query); 4 waves/block
__global__ __launch_bounds__(256) void attn_swa_k(const float* __restrict__ Q,
    const float* __restrict__ K, const float* __restrict__ V, float* __restrict__ O)
{
  __shared__ float sc[4][SWIN];
  int wid = threadIdx.x >> 6, lane = threadIdx.x & 63;
  int w = blockIdx.x*4 + wid;
  int b = w >> 14;
  int rem = w & 16383;
  int h = rem >> 11;
  int i = rem & (SS-1);
  const float* qp = Q + ((long)b*SS + i)*SD + h*64;
  float qv = qp[lane];
  int j0 = i - (SWIN-1); if (j0 < 0) j0 = 0;
  int cnt = i - j0 + 1;
  const float* Kb = K + (long)b*SS*SD + h*64;
  const float* Vb = V + (long)b*SS*SD + h*64;
  float mx = -1e30f;
  for (int jj = 0; jj < cnt; jj++) {
    float p = qv * Kb[(long)(j0+jj)*SD + lane];
    #pragma unroll
    for (int o2 = 32; o2 > 0; o2 >>= 1) p += __shfl_xor(p, o2);
    p *= 0.125f;
    if (lane == 0) sc[wid][jj] = p;
    mx = fmaxf(mx, p);
  }
  __syncthreads();
  float sum = 0.f, oa = 0.f;
  for (int jj = 0; jj < cnt; jj++) {
    float p = __expf(sc[wid][jj] - mx);
    sum += p;
    oa += p * Vb[(long)(j0+jj)*SD + lane];
  }
  O[((long)b*SS + i)*SD + h*64 + lane] = oa / sum;
}

__global__ __launch_bounds__(256) void copy_f_k(float* __restrict__ dst, long dstride,
    const float* __restrict__ src, long sstride, long nper, int nb)
{
  long total = nper * nb;
  for (long i = (long)blockIdx.x*256 + threadIdx.x; i < total; i += (long)gridDim.x*256) {
    long b = i / nper, r = i - b*nper;
    dst[b*dstride + r] = src[b*sstride + r];
  }
}

// f32 -> hi/lo bf16 planes
__global__ __launch_bounds__(256) void split_k(unsigned short* __restrict__ dst,
    long dBatch, long dPlane, const float* __restrict__ src, long sBatch,
    long nper, int nb)
{
  long total = nper * nb;
  for (long i = (long)blockIdx.x*256 + threadIdx.x; i < total; i += (long)gridDim.x*256) {
    long b = i / nper, r = i - b*nper;
    float f = src[b*sBatch + r];
    unsigned short h = f2bs(f);
    dst[b*dBatch + r]          = h;
    dst[b*dBatch + dPlane + r] = f2bs(f - bs2f(h));
  }
}

// hi/lo planes -> f32
__global__ __launch_bounds__(256) void merge_k(float* __restrict__ dst, long dBatch,
    const unsigned short* __restrict__ src, long sBatch, long sPlane, long nper, int nb)
{
  long total = nper * nb;
  for (long i = (long)blockIdx.x*256 + threadIdx.x; i < total; i += (long)gridDim.x*256) {
    long b = i / nper, r = i - b*nper;
    dst[b*dBatch + r] = bs2f(src[b*sBatch + r]) + bs2f(src[b*sBatch + sPlane + r]);
  }
}

extern "C" void kernel_launch(void* const* d_in, const int* in_sizes, int n_in,
                              void* d_out, int out_size, void* d_ws, size_t ws_size,
                              hipStream_t stream)
{
  (void)in_sizes; (void)n_in; (void)out_size; (void)ws_size;
  const float* x      = (const float*)d_in[0];
  const float* mem0   = (const float*)d_in[1];
  const float* buf_k  = (const float*)d_in[2];
  const float* buf_v  = (const float*)d_in[3];
  const float* nw_in  = (const float*)d_in[4];
  const float* nw_kq  = (const float*)d_in[5];
  const float* nw_out = (const float*)d_in[6];
  const float* wk_a   = (const float*)d_in[7];
  const float* wq_a   = (const float*)d_in[8];
  const float* wv_a   = (const float*)d_in[9];
  const float* wg     = (const float*)d_in[10];
  const float* wb     = (const float*)d_in[11];
  const float* ck_w   = (const float*)d_in[12];
  const float* ck_b   = (const float*)d_in[13];
  const float* cq_w   = (const float*)d_in[14];
  const float* cq_b   = (const float*)d_in[15];
  const float* s1_wq  = (const float*)d_in[16];
  const float* s1_wk  = (const float*)d_in[17];
  const float* s1_wv  = (const float*)d_in[18];
  const float* s1_wo  = (const float*)d_in[19];
  const float* s2_wq  = (const float*)d_in[20];
  const float* s2_wk  = (const float*)d_in[21];
  const float* s2_wv  = (const float*)d_in[22];
  const float* s2_wo  = (const float*)d_in[23];
  const float* n1_w   = (const float*)d_in[24];
  const float* n2_w   = (const float*)d_in[25];
  const float* m_w1   = (const float*)d_in[26];
  const float* m_w2   = (const float*)d_in[27];
  const float* m_w3   = (const float*)d_in[28];
  float* ob = (float*)d_out;

  // ---- workspace carve: f32 section (~52MB) + u16 split arena (~29MB) ----
  float* p = (float*)d_ws;
  float* kp   = p; p += SB*KPBATCH;   // padded k f32; C: attn out; MLP: h1 head
  float* vp   = p; p += SB*KPBATCH;   // padded v f32; C: oproj1 out
  float* qbuf = p; p += SB*BSD;       // atlas q f32; C: v1/v2
  float* gb   = p; p += SB*BSD;       // gamma*bypass; C: k1/k2; MLP: h1 tail
  float* sc1  = p; p += SB*BSD;       // xn; C: q1/q2, y
  float* sc2  = p; p += SB*BSD;       // kraw/qraw; B: aout; C: memn->fused
  float* Mb   = p; p += SB*DD;        // mem0 f32 (split source)
  float* etaM = p; p += (long)SB*SNCH*SD;
  float* alphaM = p; p += (long)SB*SNCH*SD;
  float* partials = p; p += 512;
  unsigned short* us = (unsigned short*)p;
  unsigned short* khl = us; us += SB*2*KPBATCH;
  unsigned short* qhl = us; us += SB*2*BSD;
  unsigned short* Mhl = us; us += SB*2*DD;
  unsigned short* Xhl = us; us += SB*2*DD;
  unsigned short* Yhl = us; us += SB*2*DD;
  unsigned short* Ahl = us; us += SB*2*DD;
  unsigned short* Thl = us; us += SB*2*DD;
  unsigned short* errhl = us; us += SB*2*ERRN;
  float* nsbuf = (float*)khl;         // phase-A scratch (before splits)
  float* aout = sc2;
  float* hbuf = kp;                   // MLP h1/h2: kp..gb span

  dim3 blk(256);

  // ================= Phase A =================
  rmsnorm_in_k<<<SB*SS, blk, 0, stream>>>(x, nw_in, sc1);

  mgemm_k<false,true,EPI_SILU,float><<<dim3(32,8,2),blk,0,stream>>>(
      sc1, wv_a, vp + (long)SWIN*SD, nullptr, 0.f,0.f, SS, SD, SD,
      BSD, 0, KPBATCH, 0, SD, SD, SD, 0);

  mgemm_k<false,true,EPI_NONE,float><<<dim3(64,8,1),blk,0,stream>>>(
      sc1, wk_a, sc2, nullptr, 0.f,0.f, SB*SS, SD, SD, 0,0,0,0, SD,SD,SD,0);
  conv_silu_rms_k<<<dim3(SS,SB),blk,0,stream>>>(sc2, ck_w, ck_b, nw_kq, kp, KPBATCH, SWIN);

  mgemm_k<false,true,EPI_NONE,float><<<dim3(64,8,1),blk,0,stream>>>(
      sc1, wq_a, sc2, nullptr, 0.f,0.f, SB*SS, SD, SD, 0,0,0,0, SD,SD,SD,0);
  conv_silu_rms_k<<<dim3(SS,SB),blk,0,stream>>>(sc2, cq_w, cq_b, nw_kq, qbuf, BSD, 0);

  mgemm_k<false,true,EPI_SILU,float><<<dim3(64,8,1),blk,0,stream>>>(
      sc1, wg, gb, nullptr, 0.f,0.f, SB*SS, SD, SD, 0,0,0,0, SD,SD,SD,0);
  mgemm_k<false,true,EPI_SILU_MUL,float><<<dim3(64,8,1),blk,0,stream>>>(
      sc1, wb, gb, gb, 0.f,0.f, SB*SS, SD, SD, 0,0,0,0, SD,SD,SD,SD);

  mgemm_k<false,true,EPI_SILU,float><<<dim3(64,8,1),blk,0,stream>>>(
      sc1, wg + (long)SD*SD, nsbuf, nullptr, 0.f,0.f, SB*SS, SD, SD, 0,0,0,0, SD,SD,SD,0);
  chunk_means1_k<<<SB*SNCH, blk, 0, stream>>>(nsbuf, etaM);
  mgemm_k<false,true,EPI_SILU,float><<<dim3(64,8,1),blk,0,stream>>>(
      sc1, wg + 2L*SD*SD, nsbuf, nullptr, 0.f,0.f, SB*SS, SD, SD, 0,0,0,0, SD,SD,SD,0);
  chunk_means1_k<<<SB*SNCH, blk, 0, stream>>>(nsbuf, alphaM);

  copy_f_k<<<256,blk,0,stream>>>(kp, KPBATCH, buf_k, (long)SWIN*SD, (long)SWIN*SD, SB);
  copy_f_k<<<256,blk,0,stream>>>(vp, KPBATCH, buf_v, (long)SWIN*SD, (long)SWIN*SD, SB);
  copy_f_k<<<256,blk,0,stream>>>(Mb, DD, mem0, DD, DD, SB);

  // split once for the scan (AFTER nsbuf is dead)
  split_k<<<512,blk,0,stream>>>(khl, 2*KPBATCH, KPBATCH, kp, KPBATCH, KPBATCH, SB);
  split_k<<<512,blk,0,stream>>>(qhl, 2*BSD, BSD, qbuf, BSD, BSD, SB);
  split_k<<<256,blk,0,stream>>>(Mhl, 2*DD, DD, Mb, DD, DD, SB);

  // ================= Phase B: sequential chunk scan (multi-launch) =================
  // initial err for chunk 0 (no out yet)
  out_err_k<<<256,blk,0,stream>>>(khl, qhl, Mhl, errhl, vp, aout, -1, 0);

  for (int t = 0; t < SNCH; ++t) {
    const long off = (long)t*SCH*SD;
    // grad (UNNORMALIZED) = ck^T @ err -> Xhl split + frob partials (256/batch)
    sgemm32_k<true,false,EPI_NONE,false,true,false,true,false,0><<<dim3(16,16,2),blk,0,stream>>>(
        khl + off, errhl, nullptr, Xhl, nullptr, nullptr, partials, nullptr, 0,
        0.f,0.f, 512, 512, 192,
        2*KPBATCH, KPBATCH, 2*ERRN, ERRN,
        0, 2*DD, DD, 0, 0,
        512,512,512,0, nullptr, nullptr, 0);
    // NS iter 1 (scale folded): A1 = (X0@X0^T)/s^2
    sgemm32_k<false,true,EPI_NONE,false,true,false,false,false,1><<<dim3(16,16,2),blk,0,stream>>>(
        Xhl, Xhl, nullptr, Ahl, nullptr, nullptr, nullptr, partials, 256,
        0.f,0.f, 512,512,512, 2*DD,DD, 2*DD,DD, 0, 2*DD,DD, 0,0, 512,512,512,0,
        nullptr, nullptr, 0);
    // T1 = b*A1 + c*A1@A1
    sgemm32_k<false,true,EPI_LINCOMB,true,true,false,false,false,0><<<dim3(16,16,2),blk,0,stream>>>(
        Ahl, Ahl, nullptr, Thl, nullptr, Ahl, nullptr, nullptr, 0,
        -4.7750f, 2.0315f, 512,512,512, 2*DD,DD, 2*DD,DD, 0, 2*DD,DD, 2*DD,DD,
        512,512,512,512, nullptr, nullptr, 0);
    // X1 = (a*X0 + T1@X0)/s -> Yhl
    sgemm32_k<false,false,EPI_LINCOMB,true,true,false,false,false,2><<<dim3(16,16,2),blk,0,stream>>>(
        Thl, Xhl, nullptr, Yhl, nullptr, Xhl, nullptr, partials, 256,
        3.4445f, 1.0f, 512,512,512, 2*DD,DD, 2*DD,DD, 0, 2*DD,DD, 2*DD,DD,
        512,512,512,512, nullptr, nullptr, 0);
    // NS iterations 2..4 (full)
    unsigned short* Xc = Yhl; unsigned short* Xn = Xhl;
    for (int it = 0; it < 3; ++it) {
      sgemm32_k<false,true,EPI_NONE,false,true,false,false,false,0><<<dim3(16,16,2),blk,0,stream>>>(
          Xc, Xc, nullptr, Ahl, nullptr, nullptr, nullptr, nullptr, 0,
          0.f,0.f, 512,512,512, 2*DD,DD, 2*DD,DD, 0, 2*DD,DD, 0,0, 512,512,512,0,
          nullptr, nullptr, 0);
      sgemm32_k<false,true,EPI_LINCOMB,true,true,false,false,false,0><<<dim3(16,16,2),blk,0,stream>>>(
          Ahl, Ahl, nullptr, Thl, nullptr, Ahl, nullptr, nullptr, 0,
          -4.7750f, 2.0315f, 512,512,512, 2*DD,DD, 2*DD,DD, 0, 2*DD,DD, 2*DD,DD,
          512,512,512,512, nullptr, nullptr, 0);
      sgemm32_k<false,false,EPI_LINCOMB,true,true,false,false,false,0><<<dim3(16,16,2),blk,0,stream>>>(
          Thl, Xc, nullptr, Xn, nullptr, Xc, nullptr, nullptr, 0,
          3.4445f, 1.0f, 512,512,512, 2*DD,DD, 2*DD,DD, 0, 2*DD,DD, 2*DD,DD,
          512,512,512,512, nullptr, nullptr, 0);
      unsigned short* tmp = Xc; Xc = Xn; Xn = tmp;
    }
    // iter 5: A, T, then fused X5 + M-update (X5 never materialized)
    sgemm32_k<false,true,EPI_NONE,false,true,false,false,false,0><<<dim3(16,16,2),blk,0,stream>>>(
        Xc, Xc, nullptr, Ahl, nullptr, nullptr, nullptr, nullptr, 0,
        0.f,0.f, 512,512,512, 2*DD,DD, 2*DD,DD, 0, 2*DD,DD, 0,0, 512,512,512,0,
        nullptr, nullptr, 0);
    sgemm32_k<false,true,EPI_LINCOMB,true,true,false,false,false,0><<<dim3(16,16,2),blk,0,stream>>>(
        Ahl, Ahl, nullptr, Thl, nullptr, Ahl, nullptr, nullptr, 0,
        -4.7750f, 2.0315f, 512,512,512, 2*DD,DD, 2*DD,DD, 0, 2*DD,DD, 2*DD,DD,
        512,512,512,512, nullptr, nullptr, 0);
    // v = a*X4 + T@X4 ; M = M*alpha - v*eta  (split pair, in place on Mhl)
    sgemm32_k<false,false,EPI_LINCOMB,true,false,false,false,true,0><<<dim3(16,16,2),blk,0,stream>>>(
        Thl, Xc, nullptr, Mhl, nullptr, Xc, nullptr, nullptr, 0,
        3.4445f, 1.0f, 512,512,512, 2*DD,DD, 2*DD,DD, 0, 2*DD, DD, 2*DD,DD,
        512,512,512,512, alphaM, etaM, t);
    // out(t) = cq @ M  ||  err(t+1)
    out_err_k<<<256,blk,0,stream>>>(khl, qhl, Mhl, errhl, vp, aout, t, t+1);
  }

  // ================= Phase C =================
  atlas_final_norm_k<<<SB*SS,blk,0,stream>>>(sc2, gb, nw_out, n1_w);

  // side outputs (before kp/vp reuse)
  merge_k<<<256,blk,0,stream>>>(ob + (long)SB*SS*SD, DD, Mhl, 2*DD, DD, DD, SB);
  copy_f_k<<<256,blk,0,stream>>>(ob + (long)SB*SS*SD + SB*DD, (long)SWIN*SD,
      kp + (long)SS*SD, KPBATCH, (long)SWIN*SD, SB);
  copy_f_k<<<256,blk,0,stream>>>(ob + (long)SB*SS*SD + SB*DD + (long)SB*SWIN*SD, (long)SWIN*SD,
      vp + (long)SS*SD, KPBATCH, (long)SWIN*SD, SB);

  // SWA 1 on x
  mgemm_k<false,true,EPI_NONE,float><<<dim3(64,8,1),blk,0,stream>>>(
      x, s1_wq, sc1, nullptr,0.f,0.f, SB*SS, SD, SD, 0,0,0,0, SD,SD,SD,0);
  mgemm_k<false,true,EPI_NONE,float><<<dim3(64,8,1),blk,0,stream>>>(
      x, s1_wk, gb, nullptr,0.f,0.f, SB*SS, SD, SD, 0,0,0,0, SD,SD,SD,0);
  mgemm_k<false,true,EPI_NONE,float><<<dim3(64,8,1),blk,0,stream>>>(
      x, s1_wv, qbuf, nullptr,0.f,0.f, SB*SS, SD, SD, 0,0,0,0, SD,SD,SD,0);
  attn_swa_k<<<SB*SH*SS/4, blk, 0, stream>>>(sc1, gb, qbuf, kp);
  mgemm_k<false,true,EPI_NONE,float><<<dim3(64,8,1),blk,0,stream>>>(
      kp, s1_wo, vp, nullptr,0.f,0.f, SB*SS, SD, SD, 0,0,0,0, SD,SD,SD,0);
  rms_add_k<<<SB*SS,blk,0,stream>>>(vp, n2_w, sc2);   // sc2 = fused

  // SWA 2 on fused
  mgemm_k<false,true,EPI_NONE,float><<<dim3(64,8,1),blk,0,stream>>>(
      sc2, s2_wq, sc1, nullptr,0.f,0.f, SB*SS, SD, SD, 0,0,0,0, SD,SD,SD,0);
  mgemm_k<false,true,EPI_NONE,float><<<dim3(64,8,1),blk,0,stream>>>(
      sc2, s2_wk, gb, nullptr,0.f,0.f, SB*SS, SD, SD, 0,0,0,0, SD,SD,SD,0);
  mgemm_k<false,true,EPI_NONE,float><<<dim3(64,8,1),blk,0,stream>>>(
      sc2, s2_wv, qbuf, nullptr,0.f,0.f, SB*SS, SD, SD, 0,0,0,0, SD,SD,SD,0);
  attn_swa_k<<<SB*SH*SS/4, blk, 0, stream>>>(sc1, gb, qbuf, kp);
  mgemm_k<false,true,EPI_NONE,float><<<dim3(64,8,1),blk,0,stream>>>(
      kp, s2_wo, sc1, nullptr,0.f,0.f, SB*SS, SD, SD, 0,0,0,0, SD,SD,SD,0); // y=sc1

  // MLP
  mgemm_k<false,true,EPI_SILU,float><<<dim3(64,32,1),blk,0,stream>>>(
      sc1, m_w1, hbuf, nullptr,0.f,0.f, SB*SS, SFF, SD, 0,0,0,0, SD,SD,SFF,0);
  mgemm_k<false,true,EPI_MUL,float><<<dim3(64,32,1),blk,0,stream>>>(
      sc1, m_w2, hbuf, hbuf, 0.f,0.f, SB*SS, SFF, SD, 0,0,0,0, SD,SD,SFF,SFF);
  mgemm_k<false,true,EPI_ADD,float><<<dim3(64,8,1),blk,0,stream>>>(
      hbuf, m_w3, ob, sc2, 0.f,0.f, SB*SS, SD, SFF, 0,0,0,0, SFF,SFF,SD,SD);
}

// Round 14
// 5737.084 us; speedup vs baseline: 12.1374x; 1.0842x over previous
//
#include <hip/hip_runtime.h>
#include <hip/hip_bf16.h>

typedef __hip_bfloat16 bf16;
typedef __attribute__((ext_vector_type(8))) short bfrag;            // 8 bf16 = 4 VGPRs
typedef __attribute__((ext_vector_type(8))) unsigned short u16x8;   // 16B copy unit
typedef __attribute__((ext_vector_type(4))) float f32x4;

#define SB 2
#define SS 2048
#define SD 512
#define SH 8
#define SWIN 128
#define SCH 64
#define SNCH 32
#define SFF 2048
#define KPROWS 2176              // WIN + S
#define KPBATCH 1114112L         // KPROWS*SD
#define BSD 1048576L             // SS*SD
#define DD 262144L               // SD*SD
#define ERRN 98304L              // 192*SD

__device__ __forceinline__ void stf(float* p, float v){ *p = v; }
__device__ __forceinline__ void stf(bf16* p, float v){ *p = __float2bfloat16(v); }

// f32 -> bf16 bits, round-to-nearest-even (finite inputs)
__device__ __forceinline__ unsigned short f2bs(float f){
  union { float f; unsigned int u; } v; v.f = f;
  unsigned int r = v.u + 0x7FFFu + ((v.u >> 16) & 1u);
  return (unsigned short)(r >> 16);
}
__device__ __forceinline__ float bs2f(unsigned short h){
  union { unsigned int u; float f; } v; v.u = ((unsigned int)h) << 16;
  return v.f;
}

__device__ __forceinline__ float block_sum256(float v, float* sbuf){
  #pragma unroll
  for (int o = 32; o > 0; o >>= 1) v += __shfl_xor(v, o);
  int wid = threadIdx.x >> 6;
  if ((threadIdx.x & 63) == 0) sbuf[wid] = v;
  __syncthreads();
  float r = sbuf[0] + sbuf[1] + sbuf[2] + sbuf[3];
  __syncthreads();
  return r;
}

enum { EPI_NONE=0, EPI_SILU=1, EPI_SUB=2, EPI_LINCOMB=3, EPI_MUL=4, EPI_ADD=5, EPI_SILU_MUL=6 };

// ============ 32x32-tile split-pair MFMA GEMM with intra-block split-K(2) ============
// 512 threads = 8 waves: quadrant q = wave&3, K-half kh = wave>>2.
// Each K-half runs its own double-buffered LDS pipeline over K/2 (serial chain halved).
// Halves combined deterministically (acc = half0 + half1) via LDS exchange.
// TRA: A given [K,M]. TRB: B given [N,K]. M%32==N%32==0, K%64==0.
// SCL: 1 -> multiply by 1/s^2, 2 -> by 1/s; s = sqrt(sum(partIn[bz*nPart..])) + 1e-7.
// MUPD: Chl is M in/out split pair: M = M*alpha[col] - v*eta[col].
template<bool TRA, bool TRB, int EPI, bool EPAIR, bool OSPLIT, bool OF32, bool FROB, bool MUPD, int SCL>
__global__ __launch_bounds__(512)
void sgemm32s_k(const unsigned short* __restrict__ Ahl, const unsigned short* __restrict__ Bhl,
                float* __restrict__ Cf, unsigned short* __restrict__ Chl,
                const float* __restrict__ Ef, const unsigned short* __restrict__ Ehl,
                float* __restrict__ frobOut,
                const float* __restrict__ partIn, int nPart,
                float a0, float a1, int M, int N, int K,
                long sA, long pA, long sB, long pB,
                long sCf, long sChl, long pC, long sE, long pE,
                int lda, int ldb, int ldc, int lde,
                const float* __restrict__ alphaM, const float* __restrict__ etaM, int chunkIdx)
{
  __shared__ __align__(16) unsigned short As[2][2][2][32][40];  // [kh][dbuf][pl][row][col]
  __shared__ __align__(16) unsigned short Bs[2][2][2][32][40];
  __shared__ float accx[4][64][4];
  __shared__ float sb8[8];
  const int bz = blockIdx.z;
  const unsigned short* A = Ahl + (long)bz*sA;
  const unsigned short* B = Bhl + (long)bz*sB;
  const int bm = blockIdx.x*32, bn = blockIdx.y*32;
  const int tid = threadIdx.x;
  const int lane = tid & 63, w = tid >> 6;
  const int q = w & 3, kh = w >> 2;
  const int wr = (q >> 1)*16, wc = (q & 1)*16;
  const int fm = lane & 15, fk = (lane >> 4)*8;
  const int htid = tid & 255;
  const int kbase = kh * (K >> 1);
  const int nk2 = K >> 6;                       // k-steps per half

  int aR=0, aC=0, aPl=0, tK=0, tM0=0, tPl=0;
  if (!TRA) { aR = htid >> 3; int s = htid & 7; aPl = s >> 2; aC = (s & 3) << 3; }
  else      { tK = htid & 31; int qq = htid >> 5; tPl = qq >> 2; tM0 = (qq & 3) << 3; }
  int bR=0, bC=0, bPl=0, uK=0, uN0=0, uPl=0;
  if (TRB)  { bR = htid >> 3; int s = htid & 7; bPl = s >> 2; bC = (s & 3) << 3; }
  else      { uK = htid & 31; int qq = htid >> 5; uPl = qq >> 2; uN0 = (qq & 3) << 3; }

  u16x8 ra, rb;
  auto LA = [&](int k0){
    int kk = kbase + k0;
    if (!TRA) ra = *reinterpret_cast<const u16x8*>(A + (long)(bm+aR)*lda + kk + aC + (aPl ? pA : 0));
    else      ra = *reinterpret_cast<const u16x8*>(A + (long)(kk+tK)*lda + bm + tM0 + (tPl ? pA : 0));
  };
  auto SA = [&](int buf){
    if (!TRA) *reinterpret_cast<u16x8*>(&As[kh][buf][aPl][aR][aC]) = ra;
    else {
      #pragma unroll
      for (int j=0;j<8;j++) As[kh][buf][tPl][tM0+j][tK] = ra[j];
    }
  };
  auto LB = [&](int k0){
    int kk = kbase + k0;
    if (TRB)  rb = *reinterpret_cast<const u16x8*>(B + (long)(bn+bR)*ldb + kk + bC + (bPl ? pB : 0));
    else      rb = *reinterpret_cast<const u16x8*>(B + (long)(kk+uK)*ldb + bn + uN0 + (uPl ? pB : 0));
  };
  auto SBst = [&](int buf){
    if (TRB)  *reinterpret_cast<u16x8*>(&Bs[kh][buf][bPl][bR][bC]) = rb;
    else {
      #pragma unroll
      for (int j=0;j<8;j++) Bs[kh][buf][uPl][uN0+j][uK] = rb[j];
    }
  };

  f32x4 acc = {0.f,0.f,0.f,0.f};
  LA(0); LB(0);
  int buf = 0;
  for (int i = 0; i < nk2; i++) {
    SA(buf); SBst(buf);
    __syncthreads();
    if (i+1 < nk2) { LA((i+1)<<5); LB((i+1)<<5); }
    bfrag ah = *reinterpret_cast<const bfrag*>(&As[kh][buf][0][wr+fm][fk]);
    bfrag al = *reinterpret_cast<const bfrag*>(&As[kh][buf][1][wr+fm][fk]);
    bfrag bh = *reinterpret_cast<const bfrag*>(&Bs[kh][buf][0][wc+fm][fk]);
    bfrag bl = *reinterpret_cast<const bfrag*>(&Bs[kh][buf][1][wc+fm][fk]);
    acc = __builtin_amdgcn_mfma_f32_16x16x32_bf16(ah, bh, acc, 0,0,0);
    acc = __builtin_amdgcn_mfma_f32_16x16x32_bf16(ah, bl, acc, 0,0,0);
    acc = __builtin_amdgcn_mfma_f32_16x16x32_bf16(al, bh, acc, 0,0,0);
    buf ^= 1;
    __syncthreads();
  }

  // combine halves: acc_total = half0 + half1 (deterministic order)
  if (kh == 1) {
    #pragma unroll
    for (int r=0;r<4;r++) accx[q][lane][r] = acc[r];
  }
  __syncthreads();
  float accv[4];
  if (kh == 0) {
    #pragma unroll
    for (int r=0;r<4;r++) accv[r] = acc[r] + accx[q][lane][r];
  }

  float scl = 1.f;
  if (SCL) {
    float pv = (tid < nPart) ? partIn[(long)bz*nPart + tid] : 0.f;
    #pragma unroll
    for (int o = 32; o > 0; o >>= 1) pv += __shfl_xor(pv, o);
    if (lane == 0) sb8[w] = pv;
    __syncthreads();
    float ssum = sb8[0]+sb8[1]+sb8[2]+sb8[3]+sb8[4]+sb8[5]+sb8[6]+sb8[7];
    float s = sqrtf(ssum) + 1e-7f;
    scl = (SCL == 1) ? 1.f/(s*s) : 1.f/s;
    __syncthreads();
  }

  const float* alR = MUPD ? (alphaM + ((long)(bz*32 + chunkIdx) << 9)) : nullptr;
  const float* etR = MUPD ? (etaM  + ((long)(bz*32 + chunkIdx) << 9)) : nullptr;

  float fs = 0.f;
  if (kh == 0) {
    #pragma unroll
    for (int r=0;r<4;r++){
      int row = bm + wr + (lane>>4)*4 + r;
      int col = bn + wc + fm;
      float v = accv[r];
      if (EPI == EPI_SUB || EPI == EPI_LINCOMB) {
        long eidx = (long)bz*sE + (long)row*lde + col;
        float e = EPAIR ? (bs2f(Ehl[eidx]) + bs2f(Ehl[eidx + pE])) : Ef[eidx];
        if (EPI == EPI_SUB) v = v - e;
        else                v = a0*e + a1*v;
      }
      if (SCL) v *= scl;
      if (FROB) fs += v*v;
      if (OF32) Cf[(long)bz*sCf + (long)row*ldc + col] = v;
      if (OSPLIT) {
        long cidx = (long)bz*sChl + (long)row*ldc + col;
        unsigned short h = f2bs(v);
        Chl[cidx]      = h;
        Chl[cidx + pC] = f2bs(v - bs2f(h));
      }
      if (MUPD) {
        long mi = (long)bz*sChl + (long)row*ldc + col;
        float mo = bs2f(Chl[mi]) + bs2f(Chl[mi + pC]);
        float nv = mo*alR[col] - v*etR[col];
        unsigned short h = f2bs(nv);
        Chl[mi]      = h;
        Chl[mi + pC] = f2bs(nv - bs2f(h));
      }
    }
  }
  if (FROB) {
    #pragma unroll
    for (int o = 32; o > 0; o >>= 1) fs += __shfl_xor(fs, o);
    if (lane == 0) sb8[w] = fs;
    __syncthreads();
    if (tid == 0)
      frobOut[(long)bz*(gridDim.x*gridDim.y) + blockIdx.x*gridDim.y + blockIdx.y] =
          sb8[0]+sb8[1]+sb8[2]+sb8[3]+sb8[4]+sb8[5]+sb8[6]+sb8[7];
  }
}

// ===== one 32x32 output tile of a split-pair 3-term Dekker GEMM (device fn) =====
template<bool TRA, bool TRB, int EPI, bool EPAIR, bool OSPLIT, bool OF32>
__device__ __forceinline__ void gtile(
    const unsigned short* __restrict__ A, long pA, int lda,
    const unsigned short* __restrict__ B, long pB, int ldb,
    float* __restrict__ Cf, unsigned short* __restrict__ Chl, long pC, int ldc,
    const float* __restrict__ Ef, const unsigned short* __restrict__ Ehl, long pE, int lde,
    float a0, float a1,
    int K, int bm, int bn,
    unsigned short (*As)[2][32][40], unsigned short (*Bs)[2][32][40])
{
  const int tid = threadIdx.x;
  const int lane = tid & 63, wid = tid >> 6;
  const int wr = (wid >> 1) * 16, wc = (wid & 1) * 16;
  const int fm = lane & 15, fk = (lane >> 4) * 8;

  int aR=0, aC=0, aPl=0, tK=0, tM0=0, tPl=0;
  if (!TRA) { aR = tid >> 3; int s = tid & 7; aPl = s >> 2; aC = (s & 3) << 3; }
  else      { tK = tid & 31; int q = tid >> 5; tPl = q >> 2; tM0 = (q & 3) << 3; }
  int bR=0, bC=0, bPl=0, uK=0, uN0=0, uPl=0;
  if (TRB)  { bR = tid >> 3; int s = tid & 7; bPl = s >> 2; bC = (s & 3) << 3; }
  else      { uK = tid & 31; int q = tid >> 5; uPl = q >> 2; uN0 = (q & 3) << 3; }

  u16x8 ra, rb;
  auto LA = [&](int k0){
    if (!TRA) ra = *reinterpret_cast<const u16x8*>(A + (long)(bm+aR)*lda + k0 + aC + (aPl ? pA : 0));
    else      ra = *reinterpret_cast<const u16x8*>(A + (long)(k0+tK)*lda + bm + tM0 + (tPl ? pA : 0));
  };
  auto SA = [&](int buf){
    if (!TRA) *reinterpret_cast<u16x8*>(&(*As)[0][0][0] + ((long)buf*2 + aPl)*32*40 + aR*40 + aC) = ra;
    else {
      #pragma unroll
      for (int j=0;j<8;j++) As[buf][tPl][tM0+j][tK] = ra[j];
    }
  };
  auto LB = [&](int k0){
    if (TRB)  rb = *reinterpret_cast<const u16x8*>(B + (long)(bn+bR)*ldb + k0 + bC + (bPl ? pB : 0));
    else      rb = *reinterpret_cast<const u16x8*>(B + (long)(k0+uK)*ldb + bn + uN0 + (uPl ? pB : 0));
  };
  auto SBst = [&](int buf){
    if (TRB)  *reinterpret_cast<u16x8*>(&(*Bs)[0][0][0] + ((long)buf*2 + bPl)*32*40 + bR*40 + bC) = rb;
    else {
      #pragma unroll
      for (int j=0;j<8;j++) Bs[buf][uPl][uN0+j][uK] = rb[j];
    }
  };

  f32x4 acc = {0.f,0.f,0.f,0.f};
  const int nk = K >> 5;
  LA(0); LB(0);
  int buf = 0;
  for (int i = 0; i < nk; i++) {
    SA(buf); SBst(buf);
    __syncthreads();
    if (i+1 < nk) { LA((i+1)<<5); LB((i+1)<<5); }
    bfrag ah = *reinterpret_cast<const bfrag*>(&As[buf][0][wr+fm][fk]);
    bfrag al = *reinterpret_cast<const bfrag*>(&As[buf][1][wr+fm][fk]);
    bfrag bh = *reinterpret_cast<const bfrag*>(&Bs[buf][0][wc+fm][fk]);
    bfrag bl = *reinterpret_cast<const bfrag*>(&Bs[buf][1][wc+fm][fk]);
    acc = __builtin_amdgcn_mfma_f32_16x16x32_bf16(ah, bh, acc, 0,0,0);
    acc = __builtin_amdgcn_mfma_f32_16x16x32_bf16(ah, bl, acc, 0,0,0);
    acc = __builtin_amdgcn_mfma_f32_16x16x32_bf16(al, bh, acc, 0,0,0);
    buf ^= 1;
    __syncthreads();
  }

  #pragma unroll
  for (int r=0;r<4;r++){
    int row = bm + wr + (lane>>4)*4 + r;
    int col = bn + wc + fm;
    float v = acc[r];
    if (EPI == EPI_SUB || EPI == EPI_LINCOMB) {
      float e;
      if (EPAIR){ long ei = (long)row*lde + col; e = bs2f(Ehl[ei]) + bs2f(Ehl[ei + pE]); }
      else      { e = Ef[(long)row*lde + col]; }
      v = (EPI == EPI_SUB) ? (v - e) : (a0*e + a1*v);
    }
    if (OF32) Cf[(long)row*ldc + col] = v;
    if (OSPLIT){
      long ci = (long)row*ldc + col;
      unsigned short h = f2bs(v);
      Chl[ci] = h; Chl[ci + pC] = f2bs(v - bs2f(h));
    }
  }
}

// ===== combined out(tOut) + err(tErr) dispatch: 256 flat blocks =====
__global__ __launch_bounds__(256)
void out_err_k(const unsigned short* __restrict__ khl,
               const unsigned short* __restrict__ qhl,
               unsigned short* __restrict__ Mhl,
               unsigned short* __restrict__ errhl,
               const float* __restrict__ vp, float* __restrict__ aout,
               int tOut, int tErr)
{
  __shared__ __align__(16) unsigned short As[2][2][32][40];
  __shared__ __align__(16) unsigned short Bs[2][2][32][40];
  int bid = blockIdx.x;
  if (bid < 64) {
    if (tOut < 0) return;
    int b = bid >> 5, r = bid & 31, mt = r >> 4, nt = r & 15;
    long off = (long)tOut*SCH*SD;
    gtile<false,false,EPI_NONE,false,false,true>(
      qhl + (long)b*2*BSD + off, BSD, SD,
      Mhl + (long)b*2*DD, DD, SD,
      aout + (long)b*BSD + off, nullptr, 0, SD,
      nullptr, nullptr, 0, 0,
      0.f,0.f, SD, mt*32, nt*32, As, Bs);
  } else {
    if (tErr >= SNCH) return;
    int ti = bid - 64;
    int b = ti / 96, r = ti % 96, mt = r >> 4, nt = r & 15;
    long off = (long)tErr*SCH*SD;
    gtile<false,false,EPI_SUB,false,true,false>(
      khl + (long)b*2*KPBATCH + off, KPBATCH, SD,
      Mhl + (long)b*2*DD, DD, SD,
      nullptr, errhl + (long)b*2*ERRN, ERRN, SD,
      vp + (long)b*KPBATCH + off, nullptr, 0, SD,
      0.f,0.f, SD, mt*32, nt*32, As, Bs);
  }
}

// ===================== f32-input MFMA GEMM (phase A/C) =====================
template<bool TRA, bool TRB, int EPI, typename TO>
__global__ __launch_bounds__(256)
void mgemm_k(const float* __restrict__ Ag, const float* __restrict__ Bg, TO* __restrict__ Cg,
             const float* __restrict__ Eg, float a0, float a1,
             int M, int N, int K,
             long sA, long sB, long sC, long sE,
             int lda, int ldb, int ldc, int lde)
{
  __shared__ __align__(16) unsigned short As[2][64][40];
  __shared__ __align__(16) unsigned short Bs[2][64][40];
  const int bz = blockIdx.z;
  const float* A = Ag + (long)bz*sA;
  const float* Bp = Bg + (long)bz*sB;
  TO* C = Cg + (long)bz*sC;
  const float* E = Eg ? (Eg + (long)bz*sE) : nullptr;
  const int bm = blockIdx.x*64, bn = blockIdx.y*64;
  const int tid = threadIdx.x;
  const int lane = tid & 63, wid = tid >> 6;
  const int wr = (wid >> 1)*32, wc = (wid & 1)*32;
  const int fm = lane & 15, fk = (lane >> 4)*8;

  f32x4 acc[2][2];
  #pragma unroll
  for (int i=0;i<2;i++)
    #pragma unroll
    for (int j=0;j<2;j++) acc[i][j] = (f32x4){0.f,0.f,0.f,0.f};

  for (int k0 = 0; k0 < K; k0 += 32) {
    if (!TRA) {
      int k = tid & 31, m0 = tid >> 5;
      #pragma unroll
      for (int u = 0; u < 8; u++) {
        int m = m0 + u*8;
        float f = A[(long)(bm+m)*lda + k0 + k];
        unsigned short h = f2bs(f);
        As[0][m][k] = h;
        As[1][m][k] = f2bs(f - bs2f(h));
      }
    } else {
      int m = tid & 63, kk0 = tid >> 6;
      #pragma unroll
      for (int u = 0; u < 8; u++) {
        int k = kk0 + u*4;
        float f = A[(long)(k0+k)*lda + bm + m];
        unsigned short h = f2bs(f);
        As[0][m][k] = h;
        As[1][m][k] = f2bs(f - bs2f(h));
      }
    }
    if (TRB) {
      int k = tid & 31, n0 = tid >> 5;
      #pragma unroll
      for (int u = 0; u < 8; u++) {
        int n = n0 + u*8;
        float f = Bp[(long)(bn+n)*ldb + k0 + k];
        unsigned short h = f2bs(f);
        Bs[0][n][k] = h;
        Bs[1][n][k] = f2bs(f - bs2f(h));
      }
    } else {
      int n = tid & 63, kk0 = tid >> 6;
      #pragma unroll
      for (int u = 0; u < 8; u++) {
        int k = kk0 + u*4;
        float f = Bp[(long)(k0+k)*ldb + bn + n];
        unsigned short h = f2bs(f);
        Bs[0][n][k] = h;
        Bs[1][n][k] = f2bs(f - bs2f(h));
      }
    }
    __syncthreads();
    bfrag ah0 = *reinterpret_cast<const bfrag*>(&As[0][wr + fm][fk]);
    bfrag ah1 = *reinterpret_cast<const bfrag*>(&As[0][wr + 16 + fm][fk]);
    bfrag bh0 = *reinterpret_cast<const bfrag*>(&Bs[0][wc + fm][fk]);
    bfrag bh1 = *reinterpret_cast<const bfrag*>(&Bs[0][wc + 16 + fm][fk]);
    bfrag al0 = *reinterpret_cast<const bfrag*>(&As[1][wr + fm][fk]);
    bfrag al1 = *reinterpret_cast<const bfrag*>(&As[1][wr + 16 + fm][fk]);
    bfrag bl0 = *reinterpret_cast<const bfrag*>(&Bs[1][wc + fm][fk]);
    bfrag bl1 = *reinterpret_cast<const bfrag*>(&Bs[1][wc + 16 + fm][fk]);
    acc[0][0] = __builtin_amdgcn_mfma_f32_16x16x32_bf16(ah0, bh0, acc[0][0], 0,0,0);
    acc[0][1] = __builtin_amdgcn_mfma_f32_16x16x32_bf16(ah0, bh1, acc[0][1], 0,0,0);
    acc[1][0] = __builtin_amdgcn_mfma_f32_16x16x32_bf16(ah1, bh0, acc[1][0], 0,0,0);
    acc[1][1] = __builtin_amdgcn_mfma_f32_16x16x32_bf16(ah1, bh1, acc[1][1], 0,0,0);
    acc[0][0] = __builtin_amdgcn_mfma_f32_16x16x32_bf16(ah0, bl0, acc[0][0], 0,0,0);
    acc[0][1] = __builtin_amdgcn_mfma_f32_16x16x32_bf16(ah0, bl1, acc[0][1], 0,0,0);
    acc[1][0] = __builtin_amdgcn_mfma_f32_16x16x32_bf16(ah1, bl0, acc[1][0], 0,0,0);
    acc[1][1] = __builtin_amdgcn_mfma_f32_16x16x32_bf16(ah1, bl1, acc[1][1], 0,0,0);
    acc[0][0] = __builtin_amdgcn_mfma_f32_16x16x32_bf16(al0, bh0, acc[0][0], 0,0,0);
    acc[0][1] = __builtin_amdgcn_mfma_f32_16x16x32_bf16(al0, bh1, acc[0][1], 0,0,0);
    acc[1][0] = __builtin_amdgcn_mfma_f32_16x16x32_bf16(al1, bh0, acc[1][0], 0,0,0);
    acc[1][1] = __builtin_amdgcn_mfma_f32_16x16x32_bf16(al1, bh1, acc[1][1], 0,0,0);
    __syncthreads();
  }

  #pragma unroll
  for (int i=0;i<2;i++) {
    #pragma unroll
    for (int j=0;j<2;j++) {
      #pragma unroll
      for (int r=0;r<4;r++) {
        int row = bm + wr + i*16 + (lane>>4)*4 + r;
        int col = bn + wc + j*16 + fm;
        float v = acc[i][j][r];
        if (EPI == EPI_SILU)          v = v / (1.f + __expf(-v));
        else if (EPI == EPI_SUB)      v = v - E[(long)row*lde + col];
        else if (EPI == EPI_LINCOMB)  v = a0*E[(long)row*lde + col] + a1*v;
        else if (EPI == EPI_MUL)      v = v * E[(long)row*lde + col];
        else if (EPI == EPI_ADD)      v = v + E[(long)row*lde + col];
        else if (EPI == EPI_SILU_MUL) v = (v / (1.f + __expf(-v))) * E[(long)row*lde + col];
        stf(&C[(long)row*ldc + col], v);
      }
    }
  }
}

// xn = x * nw * rsqrt(mean(x^2)+eps); one block per row
__global__ __launch_bounds__(256) void rmsnorm_in_k(const float* __restrict__ x,
    const float* __restrict__ w, float* __restrict__ xn)
{
  __shared__ float sbuf[4];
  long row = blockIdx.x;
  const float* xr = x + row*SD;
  int c0 = threadIdx.x, c1 = threadIdx.x + 256;
  float v0 = xr[c0], v1 = xr[c1];
  float ss = block_sum256(v0*v0 + v1*v1, sbuf);
  float r = rsqrtf(ss*(1.f/SD) + 1e-6f);
  xn[row*SD + c0] = v0*r*w[c0];
  xn[row*SD + c1] = v1*r*w[c1];
}

// dst_row = rms(silu(dwconv3(raw_row))) * nw ;  one block per (t, b)
__global__ __launch_bounds__(256) void conv_silu_rms_k(const float* __restrict__ raw,
    const float* __restrict__ cw, const float* __restrict__ cb, const float* __restrict__ nw,
    float* __restrict__ dst, long dstBatchStride, int dstRowOff)
{
  __shared__ float sbuf[4];
  int t = blockIdx.x, b = blockIdx.y;
  const float* base = raw + ((long)b*SS + t)*SD;
  float vals[2];
  #pragma unroll
  for (int u = 0; u < 2; u++) {
    int c = threadIdx.x + u*256;
    float w0 = cw[c*3+0], w1 = cw[c*3+1], w2 = cw[c*3+2];
    float acc = cb[c];
    if (t > 0)     acc += base[c - SD]*w0;
    acc += base[c]*w1;
    if (t < SS-1)  acc += base[c + SD]*w2;
    vals[u] = acc / (1.f + __expf(-acc));
  }
  float ss = block_sum256(vals[0]*vals[0] + vals[1]*vals[1], sbuf);
  float r = rsqrtf(ss*(1.f/SD) + 1e-6f);
  float* out = dst + (long)b*dstBatchStride + (long)(dstRowOff + t)*SD;
  out[threadIdx.x]       = vals[0]*r*nw[threadIdx.x];
  out[threadIdx.x + 256] = vals[1]*r*nw[threadIdx.x + 256];
}

// per-(b,chunk) column means of a [B*S, 512] buffer -> [B*NCH, 512]
__global__ __launch_bounds__(256) void chunk_means1_k(const float* __restrict__ src,
    float* __restrict__ dst)
{
  int cb = blockIdx.x;
  long rowbase = (long)cb*SCH*SD;
  #pragma unroll
  for (int u = 0; u < 2; u++) {
    int col = threadIdx.x + u*256;
    float s = 0.f;
    for (int r = 0; r < SCH; r++) s += src[rowbase + (long)r*SD + col];
    dst[(long)cb*SD + col] = s * (1.f/SCH);
  }
}

// atlas epilogue (in place): t = rms(a)*nw_out*gb; a = rms(t)*n1_w
__global__ __launch_bounds__(256) void atlas_final_norm_k(float* __restrict__ a,
    const float* __restrict__ gb, const float* __restrict__ nwout,
    const float* __restrict__ n1w)
{
  __shared__ float sbuf[4];
  long row = blockIdx.x;
  float* xr = a + row*SD;
  int c0 = threadIdx.x, c1 = threadIdx.x + 256;
  float v0 = xr[c0], v1 = xr[c1];
  float ss = block_sum256(v0*v0 + v1*v1, sbuf);
  float r = rsqrtf(ss*(1.f/SD) + 1e-6f);
  float t0 = v0*r*nwout[c0] * gb[row*SD+c0];
  float t1 = v1*r*nwout[c1] * gb[row*SD+c1];
  float ss2 = block_sum256(t0*t0 + t1*t1, sbuf);
  float r2 = rsqrtf(ss2*(1.f/SD) + 1e-6f);
  xr[c0] = t0*r2*n1w[c0];
  xr[c1] = t1*r2*n1w[c1];
}

// dst = rms(o)*w + dst  (in place on dst)
__global__ __launch_bounds__(256) void rms_add_k(const float* __restrict__ o,
    const float* __restrict__ w, float* __restrict__ dst)
{
  __shared__ float sbuf[4];
  long row = blockIdx.x;
  const float* xr = o + row*SD;
  int c0 = threadIdx.x, c1 = threadIdx.x + 256;
  float v0 = xr[c0], v1 = xr[c1];
  float ss = block_sum256(v0*v0 + v1*v1, sbuf);
  float r = rsqrtf(ss*(1.f/SD) + 1e-6f);
  dst[row*SD+c0] += v0*r*w[c0];
  dst[row*SD+c1] += v1*r*w[c1];
}

// sliding-window attention, one wave per (b, h, query); 4 waves/block
__global__ __launch_bounds__(256) void attn_swa_k(const float* __restrict__ Q,
    const float* __restrict__ K, const float* __restrict__ V, float* __restrict__ O)
{
  __shared__ float sc[4][SWIN];
  int wid = threadIdx.x >> 6, lane = threadIdx.x & 63;
  int w = blockIdx.x*4 + wid;
  int b = w >> 14;
  int rem = w & 16383;
  int h = rem >> 11;
  int i = rem & (SS-1);
  const float* qp = Q + ((long)b*SS + i)*SD + h*64;
  float qv = qp[lane];
  int j0 = i - (SWIN-1); if (j0 < 0) j0 = 0;
  int cnt = i - j0 + 1;
  const float* Kb = K + (long)b*SS*SD + h*64;
  const float* Vb = V + (long)b*SS*SD + h*64;
  float mx = -1e30f;
  for (int jj = 0; jj < cnt; jj++) {
    float p = qv * Kb[(long)(j0+jj)*SD + lane];
    #pragma unroll
    for (int o2 = 32; o2 > 0; o2 >>= 1) p += __shfl_xor(p, o2);
    p *= 0.125f;
    if (lane == 0) sc[wid][jj] = p;
    mx = fmaxf(mx, p);
  }
  __syncthreads();
  float sum = 0.f, oa = 0.f;
  for (int jj = 0; jj < cnt; jj++) {
    float p = __expf(sc[wid][jj] - mx);
    sum += p;
    oa += p * Vb[(long)(j0+jj)*SD + lane];
  }
  O[((long)b*SS + i)*SD + h*64 + lane] = oa / sum;
}

__global__ __launch_bounds__(256) void copy_f_k(float* __restrict__ dst, long dstride,
    const float* __restrict__ src, long sstride, long nper, int nb)
{
  long total = nper * nb;
  for (long i = (long)blockIdx.x*256 + threadIdx.x; i < total; i += (long)gridDim.x*256) {
    long b = i / nper, r = i - b*nper;
    dst[b*dstride + r] = src[b*sstride + r];
  }
}

// f32 -> hi/lo bf16 planes
__global__ __launch_bounds__(256) void split_k(unsigned short* __restrict__ dst,
    long dBatch, long dPlane, const float* __restrict__ src, long sBatch,
    long nper, int nb)
{
  long total = nper * nb;
  for (long i = (long)blockIdx.x*256 + threadIdx.x; i < total; i += (long)gridDim.x*256) {
    long b = i / nper, r = i - b*nper;
    float f = src[b*sBatch + r];
    unsigned short h = f2bs(f);
    dst[b*dBatch + r]          = h;
    dst[b*dBatch + dPlane + r] = f2bs(f - bs2f(h));
  }
}

// hi/lo planes -> f32
__global__ __launch_bounds__(256) void merge_k(float* __restrict__ dst, long dBatch,
    const unsigned short* __restrict__ src, long sBatch, long sPlane, long nper, int nb)
{
  long total = nper * nb;
  for (long i = (long)blockIdx.x*256 + threadIdx.x; i < total; i += (long)gridDim.x*256) {
    long b = i / nper, r = i - b*nper;
    dst[b*dBatch + r] = bs2f(src[b*sBatch + r]) + bs2f(src[b*sBatch + sPlane + r]);
  }
}

extern "C" void kernel_launch(void* const* d_in, const int* in_sizes, int n_in,
                              void* d_out, int out_size, void* d_ws, size_t ws_size,
                              hipStream_t stream)
{
  (void)in_sizes; (void)n_in; (void)out_size; (void)ws_size;
  const float* x      = (const float*)d_in[0];
  const float* mem0   = (const float*)d_in[1];
  const float* buf_k  = (const float*)d_in[2];
  const float* buf_v  = (const float*)d_in[3];
  const float* nw_in  = (const float*)d_in[4];
  const float* nw_kq  = (const float*)d_in[5];
  const float* nw_out = (const float*)d_in[6];
  const float* wk_a   = (const float*)d_in[7];
  const float* wq_a   = (const float*)d_in[8];
  const float* wv_a   = (const float*)d_in[9];
  const float* wg     = (const float*)d_in[10];
  const float* wb     = (const float*)d_in[11];
  const float* ck_w   = (const float*)d_in[12];
  const float* ck_b   = (const float*)d_in[13];
  const float* cq_w   = (const float*)d_in[14];
  const float* cq_b   = (const float*)d_in[15];
  const float* s1_wq  = (const float*)d_in[16];
  const float* s1_wk  = (const float*)d_in[17];
  const float* s1_wv  = (const float*)d_in[18];
  const float* s1_wo  = (const float*)d_in[19];
  const float* s2_wq  = (const float*)d_in[20];
  const float* s2_wk  = (const float*)d_in[21];
  const float* s2_wv  = (const float*)d_in[22];
  const float* s2_wo  = (const float*)d_in[23];
  const float* n1_w   = (const float*)d_in[24];
  const float* n2_w   = (const float*)d_in[25];
  const float* m_w1   = (const float*)d_in[26];
  const float* m_w2   = (const float*)d_in[27];
  const float* m_w3   = (const float*)d_in[28];
  float* ob = (float*)d_out;

  // ---- workspace carve: f32 section (~52MB) + u16 split arena (~29MB) ----
  float* p = (float*)d_ws;
  float* kp   = p; p += SB*KPBATCH;   // padded k f32; C: attn out; MLP: h1 head
  float* vp   = p; p += SB*KPBATCH;   // padded v f32; C: oproj1 out
  float* qbuf = p; p += SB*BSD;       // atlas q f32; C: v1/v2
  float* gb   = p; p += SB*BSD;       // gamma*bypass; C: k1/k2; MLP: h1 tail
  float* sc1  = p; p += SB*BSD;       // xn; C: q1/q2, y
  float* sc2  = p; p += SB*BSD;       // kraw/qraw; B: aout; C: memn->fused
  float* Mb   = p; p += SB*DD;        // mem0 f32 (split source)
  float* etaM = p; p += (long)SB*SNCH*SD;
  float* alphaM = p; p += (long)SB*SNCH*SD;
  float* partials = p; p += 512;
  unsigned short* us = (unsigned short*)p;
  unsigned short* khl = us; us += SB*2*KPBATCH;
  unsigned short* qhl = us; us += SB*2*BSD;
  unsigned short* Mhl = us; us += SB*2*DD;
  unsigned short* Xhl = us; us += SB*2*DD;
  unsigned short* Yhl = us; us += SB*2*DD;
  unsigned short* Ahl = us; us += SB*2*DD;
  unsigned short* Thl = us; us += SB*2*DD;
  unsigned short* errhl = us; us += SB*2*ERRN;
  float* nsbuf = (float*)khl;         // phase-A scratch (before splits)
  float* aout = sc2;
  float* hbuf = kp;                   // MLP h1/h2: kp..gb span

  dim3 blk(256);
  dim3 blk512(512);

  // ================= Phase A =================
  rmsnorm_in_k<<<SB*SS, blk, 0, stream>>>(x, nw_in, sc1);

  mgemm_k<false,true,EPI_SILU,float><<<dim3(32,8,2),blk,0,stream>>>(
      sc1, wv_a, vp + (long)SWIN*SD, nullptr, 0.f,0.f, SS, SD, SD,
      BSD, 0, KPBATCH, 0, SD, SD, SD, 0);

  mgemm_k<false,true,EPI_NONE,float><<<dim3(64,8,1),blk,0,stream>>>(
      sc1, wk_a, sc2, nullptr, 0.f,0.f, SB*SS, SD, SD, 0,0,0,0, SD,SD,SD,0);
  conv_silu_rms_k<<<dim3(SS,SB),blk,0,stream>>>(sc2, ck_w, ck_b, nw_kq, kp, KPBATCH, SWIN);

  mgemm_k<false,true,EPI_NONE,float><<<dim3(64,8,1),blk,0,stream>>>(
      sc1, wq_a, sc2, nullptr, 0.f,0.f, SB*SS, SD, SD, 0,0,0,0, SD,SD,SD,0);
  conv_silu_rms_k<<<dim3(SS,SB),blk,0,stream>>>(sc2, cq_w, cq_b, nw_kq, qbuf, BSD, 0);

  mgemm_k<false,true,EPI_SILU,float><<<dim3(64,8,1),blk,0,stream>>>(
      sc1, wg, gb, nullptr, 0.f,0.f, SB*SS, SD, SD, 0,0,0,0, SD,SD,SD,0);
  mgemm_k<false,true,EPI_SILU_MUL,float><<<dim3(64,8,1),blk,0,stream>>>(
      sc1, wb, gb, gb, 0.f,0.f, SB*SS, SD, SD, 0,0,0,0, SD,SD,SD,SD);

  mgemm_k<false,true,EPI_SILU,float><<<dim3(64,8,1),blk,0,stream>>>(
      sc1, wg + (long)SD*SD, nsbuf, nullptr, 0.f,0.f, SB*SS, SD, SD, 0,0,0,0, SD,SD,SD,0);
  chunk_means1_k<<<SB*SNCH, blk, 0, stream>>>(nsbuf, etaM);
  mgemm_k<false,true,EPI_SILU,float><<<dim3(64,8,1),blk,0,stream>>>(
      sc1, wg + 2L*SD*SD, nsbuf, nullptr, 0.f,0.f, SB*SS, SD, SD, 0,0,0,0, SD,SD,SD,0);
  chunk_means1_k<<<SB*SNCH, blk, 0, stream>>>(nsbuf, alphaM);

  copy_f_k<<<256,blk,0,stream>>>(kp, KPBATCH, buf_k, (long)SWIN*SD, (long)SWIN*SD, SB);
  copy_f_k<<<256,blk,0,stream>>>(vp, KPBATCH, buf_v, (long)SWIN*SD, (long)SWIN*SD, SB);
  copy_f_k<<<256,blk,0,stream>>>(Mb, DD, mem0, DD, DD, SB);

  // split once for the scan (AFTER nsbuf is dead)
  split_k<<<512,blk,0,stream>>>(khl, 2*KPBATCH, KPBATCH, kp, KPBATCH, KPBATCH, SB);
  split_k<<<512,blk,0,stream>>>(qhl, 2*BSD, BSD, qbuf, BSD, BSD, SB);
  split_k<<<256,blk,0,stream>>>(Mhl, 2*DD, DD, Mb, DD, DD, SB);

  // ================= Phase B: sequential chunk scan (multi-launch) =================
  out_err_k<<<256,blk,0,stream>>>(khl, qhl, Mhl, errhl, vp, aout, -1, 0);

  for (int t = 0; t < SNCH; ++t) {
    const long off = (long)t*SCH*SD;
    // grad (UNNORMALIZED) = ck^T @ err -> Xhl split + frob partials (256/batch)
    sgemm32s_k<true,false,EPI_NONE,false,true,false,true,false,0><<<dim3(16,16,2),blk512,0,stream>>>(
        khl + off, errhl, nullptr, Xhl, nullptr, nullptr, partials, nullptr, 0,
        0.f,0.f, 512, 512, 192,
        2*KPBATCH, KPBATCH, 2*ERRN, ERRN,
        0, 2*DD, DD, 0, 0,
        512,512,512,0, nullptr, nullptr, 0);
    // NS iter 1 (scale folded): A1 = (X0@X0^T)/s^2
    sgemm32s_k<false,true,EPI_NONE,false,true,false,false,false,1><<<dim3(16,16,2),blk512,0,stream>>>(
        Xhl, Xhl, nullptr, Ahl, nullptr, nullptr, nullptr, partials, 256,
        0.f,0.f, 512,512,512, 2*DD,DD, 2*DD,DD, 0, 2*DD,DD, 0,0, 512,512,512,0,
        nullptr, nullptr, 0);
    // T1 = b*A1 + c*A1@A1
    sgemm32s_k<false,true,EPI_LINCOMB,true,true,false,false,false,0><<<dim3(16,16,2),blk512,0,stream>>>(
        Ahl, Ahl, nullptr, Thl, nullptr, Ahl, nullptr, nullptr, 0,
        -4.7750f, 2.0315f, 512,512,512, 2*DD,DD, 2*DD,DD, 0, 2*DD,DD, 2*DD,DD,
        512,512,512,512, nullptr, nullptr, 0);
    // X1 = (a*X0 + T1@X0)/s -> Yhl
    sgemm32s_k<false,false,EPI_LINCOMB,true,true,false,false,false,2><<<dim3(16,16,2),blk512,0,stream>>>(
        Thl, Xhl, nullptr, Yhl, nullptr, Xhl, nullptr, partials, 256,
        3.4445f, 1.0f, 512,512,512, 2*DD,DD, 2*DD,DD, 0, 2*DD,DD, 2*DD,DD,
        512,512,512,512, nullptr, nullptr, 0);
    // NS iterations 2..4 (full)
    unsigned short* Xc = Yhl; unsigned short* Xn = Xhl;
    for (int it = 0; it < 3; ++it) {
      sgemm32s_k<false,true,EPI_NONE,false,true,false,false,false,0><<<dim3(16,16,2),blk512,0,stream>>>(
          Xc, Xc, nullptr, Ahl, nullptr, nullptr, nullptr, nullptr, 0,
          0.f,0.f, 512,512,512, 2*DD,DD, 2*DD,DD, 0, 2*DD,DD, 0,0, 512,512,512,0,
          nullptr, nullptr, 0);
      sgemm32s_k<false,true,EPI_LINCOMB,true,true,false,false,false,0><<<dim3(16,16,2),blk512,0,stream>>>(
          Ahl, Ahl, nullptr, Thl, nullptr, Ahl, nullptr, nullptr, 0,
          -4.7750f, 2.0315f, 512,512,512, 2*DD,DD, 2*DD,DD, 0, 2*DD,DD, 2*DD,DD,
          512,512,512,512, nullptr, nullptr, 0);
      sgemm32s_k<false,false,EPI_LINCOMB,true,true,false,false,false,0><<<dim3(16,16,2),blk512,0,stream>>>(
          Thl, Xc, nullptr, Xn, nullptr, Xc, nullptr, nullptr, 0,
          3.4445f, 1.0f, 512,512,512, 2*DD,DD, 2*DD,DD, 0, 2*DD,DD, 2*DD,DD,
          512,512,512,512, nullptr, nullptr, 0);
      unsigned short* tmp = Xc; Xc = Xn; Xn = tmp;
    }
    // iter 5: A, T, then fused X5 + M-update (X5 never materialized)
    sgemm32s_k<false,true,EPI_NONE,false,true,false,false,false,0><<<dim3(16,16,2),blk512,0,stream>>>(
        Xc, Xc, nullptr, Ahl, nullptr, nullptr, nullptr, nullptr, 0,
        0.f,0.f, 512,512,512, 2*DD,DD, 2*DD,DD, 0, 2*DD,DD, 0,0, 512,512,512,0,
        nullptr, nullptr, 0);
    sgemm32s_k<false,true,EPI_LINCOMB,true,true,false,false,false,0><<<dim3(16,16,2),blk512,0,stream>>>(
        Ahl, Ahl, nullptr, Thl, nullptr, Ahl, nullptr, nullptr, 0,
        -4.7750f, 2.0315f, 512,512,512, 2*DD,DD, 2*DD,DD, 0, 2*DD,DD, 2*DD,DD,
        512,512,512,512, nullptr, nullptr, 0);
    // v = a*X4 + T@X4 ; M = M*alpha - v*eta  (split pair, in place on Mhl)
    sgemm32s_k<false,false,EPI_LINCOMB,true,false,false,false,true,0><<<dim3(16,16,2),blk512,0,stream>>>(
        Thl, Xc, nullptr, Mhl, nullptr, Xc, nullptr, nullptr, 0,
        3.4445f, 1.0f, 512,512,512, 2*DD,DD, 2*DD,DD, 0, 2*DD, DD, 2*DD,DD,
        512,512,512,512, alphaM, etaM, t);
    // out(t) = cq @ M  ||  err(t+1)
    out_err_k<<<256,blk,0,stream>>>(khl, qhl, Mhl, errhl, vp, aout, t, t+1);
  }

  // ================= Phase C =================
  atlas_final_norm_k<<<SB*SS,blk,0,stream>>>(sc2, gb, nw_out, n1_w);

  // side outputs (before kp/vp reuse)
  merge_k<<<256,blk,0,stream>>>(ob + (long)SB*SS*SD, DD, Mhl, 2*DD, DD, DD, SB);
  copy_f_k<<<256,blk,0,stream>>>(ob + (long)SB*SS*SD + SB*DD, (long)SWIN*SD,
      kp + (long)SS*SD, KPBATCH, (long)SWIN*SD, SB);
  copy_f_k<<<256,blk,0,stream>>>(ob + (long)SB*SS*SD + SB*DD + (long)SB*SWIN*SD, (long)SWIN*SD,
      vp + (long)SS*SD, KPBATCH, (long)SWIN*SD, SB);

  // SWA 1 on x
  mgemm_k<false,true,EPI_NONE,float><<<dim3(64,8,1),blk,0,stream>>>(
      x, s1_wq, sc1, nullptr,0.f,0.f, SB*SS, SD, SD, 0,0,0,0, SD,SD,SD,0);
  mgemm_k<false,true,EPI_NONE,float><<<dim3(64,8,1),blk,0,stream>>>(
      x, s1_wk, gb, nullptr,0.f,0.f, SB*SS, SD, SD, 0,0,0,0, SD,SD,SD,0);
  mgemm_k<false,true,EPI_NONE,float><<<dim3(64,8,1),blk,0,stream>>>(
      x, s1_wv, qbuf, nullptr,0.f,0.f, SB*SS, SD, SD, 0,0,0,0, SD,SD,SD,0);
  attn_swa_k<<<SB*SH*SS/4, blk, 0, stream>>>(sc1, gb, qbuf, kp);
  mgemm_k<false,true,EPI_NONE,float><<<dim3(64,8,1),blk,0,stream>>>(
      kp, s1_wo, vp, nullptr,0.f,0.f, SB*SS, SD, SD, 0,0,0,0, SD,SD,SD,0);
  rms_add_k<<<SB*SS,blk,0,stream>>>(vp, n2_w, sc2);   // sc2 = fused

  // SWA 2 on fused
  mgemm_k<false,true,EPI_NONE,float><<<dim3(64,8,1),blk,0,stream>>>(
      sc2, s2_wq, sc1, nullptr,0.f,0.f, SB*SS, SD, SD, 0,0,0,0, SD,SD,SD,0);
  mgemm_k<false,true,EPI_NONE,float><<<dim3(64,8,1),blk,0,stream>>>(
      sc2, s2_wk, gb, nullptr,0.f,0.f, SB*SS, SD, SD, 0,0,0,0, SD,SD,SD,0);
  mgemm_k<false,true,EPI_NONE,float><<<dim3(64,8,1),blk,0,stream>>>(
      sc2, s2_wv, qbuf, nullptr,0.f,0.f, SB*SS, SD, SD, 0,0,0,0, SD,SD,SD,0);
  attn_swa_k<<<SB*SH*SS/4, blk, 0, stream>>>(sc1, gb, qbuf, kp);
  mgemm_k<false,true,EPI_NONE,float><<<dim3(64,8,1),blk,0,stream>>>(
      kp, s2_wo, sc1, nullptr,0.f,0.f, SB*SS, SD, SD, 0,0,0,0, SD,SD,SD,0); // y=sc1

  // MLP
  mgemm_k<false,true,EPI_SILU,float><<<dim3(64,32,1),blk,0,stream>>>(
      sc1, m_w1, hbuf, nullptr,0.f,0.f, SB*SS, SFF, SD, 0,0,0,0, SD,SD,SFF,0);
  mgemm_k<false,true,EPI_MUL,float><<<dim3(64,32,1),blk,0,stream>>>(
      sc1, m_w2, hbuf, hbuf, 0.f,0.f, SB*SS, SFF, SD, 0,0,0,0, SD,SD,SFF,SFF);
  mgemm_k<false,true,EPI_ADD,float><<<dim3(64,8,1),blk,0,stream>>>(
      hbuf, m_w3, ob, sc2, 0.f,0.f, SB*SS, SD, SFF, 0,0,0,0, SFF,SFF,SD,SD);
}

// Round 15
// 5636.040 us; speedup vs baseline: 12.3550x; 1.0179x over previous
//
#include <hip/hip_runtime.h>
#include <hip/hip_bf16.h>

typedef __hip_bfloat16 bf16;
typedef __attribute__((ext_vector_type(8))) short bfrag;            // 8 bf16 = 4 VGPRs
typedef __attribute__((ext_vector_type(8))) unsigned short u16x8;   // 16B copy unit
typedef __attribute__((ext_vector_type(4))) float f32x4;

#define SB 2
#define SS 2048
#define SD 512
#define SH 8
#define SWIN 128
#define SCH 64
#define SNCH 32
#define SFF 2048
#define KPROWS 2176              // WIN + S
#define KPBATCH 1114112L         // KPROWS*SD
#define BSD 1048576L             // SS*SD
#define DD 262144L               // SD*SD
#define ERRN 98304L              // 192*SD

__device__ __forceinline__ void stf(float* p, float v){ *p = v; }
__device__ __forceinline__ void stf(bf16* p, float v){ *p = __float2bfloat16(v); }

// f32 -> bf16 bits, round-to-nearest-even (finite inputs)
__device__ __forceinline__ unsigned short f2bs(float f){
  union { float f; unsigned int u; } v; v.f = f;
  unsigned int r = v.u + 0x7FFFu + ((v.u >> 16) & 1u);
  return (unsigned short)(r >> 16);
}
__device__ __forceinline__ float bs2f(unsigned short h){
  union { unsigned int u; float f; } v; v.u = ((unsigned int)h) << 16;
  return v.f;
}

__device__ __forceinline__ float block_sum256(float v, float* sbuf){
  #pragma unroll
  for (int o = 32; o > 0; o >>= 1) v += __shfl_xor(v, o);
  int wid = threadIdx.x >> 6;
  if ((threadIdx.x & 63) == 0) sbuf[wid] = v;
  __syncthreads();
  float r = sbuf[0] + sbuf[1] + sbuf[2] + sbuf[3];
  __syncthreads();
  return r;
}

enum { EPI_NONE=0, EPI_SILU=1, EPI_SUB=2, EPI_LINCOMB=3, EPI_MUL=4, EPI_ADD=5, EPI_SILU_MUL=6 };

// ============ 32x32-tile split-pair MFMA GEMM with intra-block split-K(2) ============
// 512 threads = 8 waves: quadrant q = wave&3, K-half kh = wave>>2.
// Single barrier per k-step (reads of buf complete before SYNC_{i+1}; next write to
// buf is after SYNC_{i+1}).
template<bool TRA, bool TRB, int EPI, bool EPAIR, bool OSPLIT, bool OF32, bool FROB, bool MUPD, int SCL>
__global__ __launch_bounds__(512)
void sgemm32s_k(const unsigned short* __restrict__ Ahl, const unsigned short* __restrict__ Bhl,
                float* __restrict__ Cf, unsigned short* __restrict__ Chl,
                const float* __restrict__ Ef, const unsigned short* __restrict__ Ehl,
                float* __restrict__ frobOut,
                const float* __restrict__ partIn, int nPart,
                float a0, float a1, int M, int N, int K,
                long sA, long pA, long sB, long pB,
                long sCf, long sChl, long pC, long sE, long pE,
                int lda, int ldb, int ldc, int lde,
                const float* __restrict__ alphaM, const float* __restrict__ etaM, int chunkIdx)
{
  __shared__ __align__(16) unsigned short As[2][2][2][32][40];  // [kh][dbuf][pl][row][col]
  __shared__ __align__(16) unsigned short Bs[2][2][2][32][40];
  __shared__ float accx[4][64][4];
  __shared__ float sb8[8];
  const int bz = blockIdx.z;
  const unsigned short* A = Ahl + (long)bz*sA;
  const unsigned short* B = Bhl + (long)bz*sB;
  const int bm = blockIdx.x*32, bn = blockIdx.y*32;
  const int tid = threadIdx.x;
  const int lane = tid & 63, w = tid >> 6;
  const int q = w & 3, kh = w >> 2;
  const int wr = (q >> 1)*16, wc = (q & 1)*16;
  const int fm = lane & 15, fk = (lane >> 4)*8;
  const int htid = tid & 255;
  const int kbase = kh * (K >> 1);
  const int nk2 = K >> 6;                       // k-steps per half

  int aR=0, aC=0, aPl=0, tK=0, tM0=0, tPl=0;
  if (!TRA) { aR = htid >> 3; int s = htid & 7; aPl = s >> 2; aC = (s & 3) << 3; }
  else      { tK = htid & 31; int qq = htid >> 5; tPl = qq >> 2; tM0 = (qq & 3) << 3; }
  int bR=0, bC=0, bPl=0, uK=0, uN0=0, uPl=0;
  if (TRB)  { bR = htid >> 3; int s = htid & 7; bPl = s >> 2; bC = (s & 3) << 3; }
  else      { uK = htid & 31; int qq = htid >> 5; uPl = qq >> 2; uN0 = (qq & 3) << 3; }

  u16x8 ra, rb;
  auto LA = [&](int k0){
    int kk = kbase + k0;
    if (!TRA) ra = *reinterpret_cast<const u16x8*>(A + (long)(bm+aR)*lda + kk + aC + (aPl ? pA : 0));
    else      ra = *reinterpret_cast<const u16x8*>(A + (long)(kk+tK)*lda + bm + tM0 + (tPl ? pA : 0));
  };
  auto SA = [&](int buf){
    if (!TRA) *reinterpret_cast<u16x8*>(&As[kh][buf][aPl][aR][aC]) = ra;
    else {
      #pragma unroll
      for (int j=0;j<8;j++) As[kh][buf][tPl][tM0+j][tK] = ra[j];
    }
  };
  auto LB = [&](int k0){
    int kk = kbase + k0;
    if (TRB)  rb = *reinterpret_cast<const u16x8*>(B + (long)(bn+bR)*ldb + kk + bC + (bPl ? pB : 0));
    else      rb = *reinterpret_cast<const u16x8*>(B + (long)(kk+uK)*ldb + bn + uN0 + (uPl ? pB : 0));
  };
  auto SBst = [&](int buf){
    if (TRB)  *reinterpret_cast<u16x8*>(&Bs[kh][buf][bPl][bR][bC]) = rb;
    else {
      #pragma unroll
      for (int j=0;j<8;j++) Bs[kh][buf][uPl][uN0+j][uK] = rb[j];
    }
  };

  f32x4 acc = {0.f,0.f,0.f,0.f};
  LA(0); LB(0);
  int buf = 0;
  for (int i = 0; i < nk2; i++) {
    SA(buf); SBst(buf);
    __syncthreads();
    if (i+1 < nk2) { LA((i+1)<<5); LB((i+1)<<5); }
    bfrag ah = *reinterpret_cast<const bfrag*>(&As[kh][buf][0][wr+fm][fk]);
    bfrag al = *reinterpret_cast<const bfrag*>(&As[kh][buf][1][wr+fm][fk]);
    bfrag bh = *reinterpret_cast<const bfrag*>(&Bs[kh][buf][0][wc+fm][fk]);
    bfrag bl = *reinterpret_cast<const bfrag*>(&Bs[kh][buf][1][wc+fm][fk]);
    acc = __builtin_amdgcn_mfma_f32_16x16x32_bf16(ah, bh, acc, 0,0,0);
    acc = __builtin_amdgcn_mfma_f32_16x16x32_bf16(ah, bl, acc, 0,0,0);
    acc = __builtin_amdgcn_mfma_f32_16x16x32_bf16(al, bh, acc, 0,0,0);
    buf ^= 1;
  }
  __syncthreads();

  // combine halves: acc_total = half0 + half1 (deterministic order)
  if (kh == 1) {
    #pragma unroll
    for (int r=0;r<4;r++) accx[q][lane][r] = acc[r];
  }
  __syncthreads();
  float accv[4];
  if (kh == 0) {
    #pragma unroll
    for (int r=0;r<4;r++) accv[r] = acc[r] + accx[q][lane][r];
  }

  float scl = 1.f;
  if (SCL) {
    float pv = (tid < nPart) ? partIn[(long)bz*nPart + tid] : 0.f;
    #pragma unroll
    for (int o = 32; o > 0; o >>= 1) pv += __shfl_xor(pv, o);
    if (lane == 0) sb8[w] = pv;
    __syncthreads();
    float ssum = sb8[0]+sb8[1]+sb8[2]+sb8[3]+sb8[4]+sb8[5]+sb8[6]+sb8[7];
    float s = sqrtf(ssum) + 1e-7f;
    scl = (SCL == 1) ? 1.f/(s*s) : 1.f/s;
    __syncthreads();
  }

  const float* alR = MUPD ? (alphaM + ((long)(bz*32 + chunkIdx) << 9)) : nullptr;
  const float* etR = MUPD ? (etaM  + ((long)(bz*32 + chunkIdx) << 9)) : nullptr;

  float fs = 0.f;
  if (kh == 0) {
    #pragma unroll
    for (int r=0;r<4;r++){
      int row = bm + wr + (lane>>4)*4 + r;
      int col = bn + wc + fm;
      float v = accv[r];
      if (EPI == EPI_SUB || EPI == EPI_LINCOMB) {
        long eidx = (long)bz*sE + (long)row*lde + col;
        float e = EPAIR ? (bs2f(Ehl[eidx]) + bs2f(Ehl[eidx + pE])) : Ef[eidx];
        if (EPI == EPI_SUB) v = v - e;
        else                v = a0*e + a1*v;
      }
      if (SCL) v *= scl;
      if (FROB) fs += v*v;
      if (OF32) Cf[(long)bz*sCf + (long)row*ldc + col] = v;
      if (OSPLIT) {
        long cidx = (long)bz*sChl + (long)row*ldc + col;
        unsigned short h = f2bs(v);
        Chl[cidx]      = h;
        Chl[cidx + pC] = f2bs(v - bs2f(h));
      }
      if (MUPD) {
        long mi = (long)bz*sChl + (long)row*ldc + col;
        float mo = bs2f(Chl[mi]) + bs2f(Chl[mi + pC]);
        float nv = mo*alR[col] - v*etR[col];
        unsigned short h = f2bs(nv);
        Chl[mi]      = h;
        Chl[mi + pC] = f2bs(nv - bs2f(h));
      }
    }
  }
  if (FROB) {
    #pragma unroll
    for (int o = 32; o > 0; o >>= 1) fs += __shfl_xor(fs, o);
    if (lane == 0) sb8[w] = fs;
    __syncthreads();
    if (tid == 0)
      frobOut[(long)bz*(gridDim.x*gridDim.y) + blockIdx.x*gridDim.y + blockIdx.y] =
          sb8[0]+sb8[1]+sb8[2]+sb8[3]+sb8[4]+sb8[5]+sb8[6]+sb8[7];
  }
}

// ===== one 32x32 output tile of a split-pair 3-term Dekker GEMM (device fn) =====
template<bool TRA, bool TRB, int EPI, bool EPAIR, bool OSPLIT, bool OF32>
__device__ __forceinline__ void gtile(
    const unsigned short* __restrict__ A, long pA, int lda,
    const unsigned short* __restrict__ B, long pB, int ldb,
    float* __restrict__ Cf, unsigned short* __restrict__ Chl, long pC, int ldc,
    const float* __restrict__ Ef, const unsigned short* __restrict__ Ehl, long pE, int lde,
    float a0, float a1,
    int K, int bm, int bn,
    unsigned short (*As)[2][32][40], unsigned short (*Bs)[2][32][40])
{
  const int tid = threadIdx.x;
  const int lane = tid & 63, wid = tid >> 6;
  const int wr = (wid >> 1) * 16, wc = (wid & 1) * 16;
  const int fm = lane & 15, fk = (lane >> 4) * 8;

  int aR=0, aC=0, aPl=0, tK=0, tM0=0, tPl=0;
  if (!TRA) { aR = tid >> 3; int s = tid & 7; aPl = s >> 2; aC = (s & 3) << 3; }
  else      { tK = tid & 31; int q = tid >> 5; tPl = q >> 2; tM0 = (q & 3) << 3; }
  int bR=0, bC=0, bPl=0, uK=0, uN0=0, uPl=0;
  if (TRB)  { bR = tid >> 3; int s = tid & 7; bPl = s >> 2; bC = (s & 3) << 3; }
  else      { uK = tid & 31; int q = tid >> 5; uPl = q >> 2; uN0 = (q & 3) << 3; }

  u16x8 ra, rb;
  auto LA = [&](int k0){
    if (!TRA) ra = *reinterpret_cast<const u16x8*>(A + (long)(bm+aR)*lda + k0 + aC + (aPl ? pA : 0));
    else      ra = *reinterpret_cast<const u16x8*>(A + (long)(k0+tK)*lda + bm + tM0 + (tPl ? pA : 0));
  };
  auto SA = [&](int buf){
    if (!TRA) *reinterpret_cast<u16x8*>(&(*As)[0][0][0] + ((long)buf*2 + aPl)*32*40 + aR*40 + aC) = ra;
    else {
      #pragma unroll
      for (int j=0;j<8;j++) As[buf][tPl][tM0+j][tK] = ra[j];
    }
  };
  auto LB = [&](int k0){
    if (TRB)  rb = *reinterpret_cast<const u16x8*>(B + (long)(bn+bR)*ldb + k0 + bC + (bPl ? pB : 0));
    else      rb = *reinterpret_cast<const u16x8*>(B + (long)(k0+uK)*ldb + bn + uN0 + (uPl ? pB : 0));
  };
  auto SBst = [&](int buf){
    if (TRB)  *reinterpret_cast<u16x8*>(&(*Bs)[0][0][0] + ((long)buf*2 + bPl)*32*40 + bR*40 + bC) = rb;
    else {
      #pragma unroll
      for (int j=0;j<8;j++) Bs[buf][uPl][uN0+j][uK] = rb[j];
    }
  };

  f32x4 acc = {0.f,0.f,0.f,0.f};
  const int nk = K >> 5;
  LA(0); LB(0);
  int buf = 0;
  for (int i = 0; i < nk; i++) {
    SA(buf); SBst(buf);
    __syncthreads();
    if (i+1 < nk) { LA((i+1)<<5); LB((i+1)<<5); }
    bfrag ah = *reinterpret_cast<const bfrag*>(&As[buf][0][wr+fm][fk]);
    bfrag al = *reinterpret_cast<const bfrag*>(&As[buf][1][wr+fm][fk]);
    bfrag bh = *reinterpret_cast<const bfrag*>(&Bs[buf][0][wc+fm][fk]);
    bfrag bl = *reinterpret_cast<const bfrag*>(&Bs[buf][1][wc+fm][fk]);
    acc = __builtin_amdgcn_mfma_f32_16x16x32_bf16(ah, bh, acc, 0,0,0);
    acc = __builtin_amdgcn_mfma_f32_16x16x32_bf16(ah, bl, acc, 0,0,0);
    acc = __builtin_amdgcn_mfma_f32_16x16x32_bf16(al, bh, acc, 0,0,0);
    buf ^= 1;
  }

  #pragma unroll
  for (int r=0;r<4;r++){
    int row = bm + wr + (lane>>4)*4 + r;
    int col = bn + wc + fm;
    float v = acc[r];
    if (EPI == EPI_SUB || EPI == EPI_LINCOMB) {
      float e;
      if (EPAIR){ long ei = (long)row*lde + col; e = bs2f(Ehl[ei]) + bs2f(Ehl[ei + pE]); }
      else      { e = Ef[(long)row*lde + col]; }
      v = (EPI == EPI_SUB) ? (v - e) : (a0*e + a1*v);
    }
    if (OF32) Cf[(long)row*ldc + col] = v;
    if (OSPLIT){
      long ci = (long)row*ldc + col;
      unsigned short h = f2bs(v);
      Chl[ci] = h; Chl[ci + pC] = f2bs(v - bs2f(h));
    }
  }
}

// ===== combined out(tOut) + err(tErr) dispatch: 256 flat blocks =====
__global__ __launch_bounds__(256)
void out_err_k(const unsigned short* __restrict__ khl,
               const unsigned short* __restrict__ qhl,
               unsigned short* __restrict__ Mhl,
               unsigned short* __restrict__ errhl,
               const float* __restrict__ vp, float* __restrict__ aout,
               int tOut, int tErr)
{
  __shared__ __align__(16) unsigned short As[2][2][32][40];
  __shared__ __align__(16) unsigned short Bs[2][2][32][40];
  int bid = blockIdx.x;
  if (bid < 64) {
    if (tOut < 0) return;
    int b = bid >> 5, r = bid & 31, mt = r >> 4, nt = r & 15;
    long off = (long)tOut*SCH*SD;
    gtile<false,false,EPI_NONE,false,false,true>(
      qhl + (long)b*2*BSD + off, BSD, SD,
      Mhl + (long)b*2*DD, DD, SD,
      aout + (long)b*BSD + off, nullptr, 0, SD,
      nullptr, nullptr, 0, 0,
      0.f,0.f, SD, mt*32, nt*32, As, Bs);
  } else {
    if (tErr >= SNCH) return;
    int ti = bid - 64;
    int b = ti / 96, r = ti % 96, mt = r >> 4, nt = r & 15;
    long off = (long)tErr*SCH*SD;
    gtile<false,false,EPI_SUB,false,true,false>(
      khl + (long)b*2*KPBATCH + off, KPBATCH, SD,
      Mhl + (long)b*2*DD, DD, SD,
      nullptr, errhl + (long)b*2*ERRN, ERRN, SD,
      vp + (long)b*KPBATCH + off, nullptr, 0, SD,
      0.f,0.f, SD, mt*32, nt*32, As, Bs);
  }
}

// ===================== f32-input MFMA GEMM (phase A/C) =====================
template<bool TRA, bool TRB, int EPI, typename TO>
__global__ __launch_bounds__(256)
void mgemm_k(const float* __restrict__ Ag, const float* __restrict__ Bg, TO* __restrict__ Cg,
             const float* __restrict__ Eg, float a0, float a1,
             int M, int N, int K,
             long sA, long sB, long sC, long sE,
             int lda, int ldb, int ldc, int lde)
{
  __shared__ __align__(16) unsigned short As[2][64][40];
  __shared__ __align__(16) unsigned short Bs[2][64][40];
  const int bz = blockIdx.z;
  const float* A = Ag + (long)bz*sA;
  const float* Bp = Bg + (long)bz*sB;
  TO* C = Cg + (long)bz*sC;
  const float* E = Eg ? (Eg + (long)bz*sE) : nullptr;
  const int bm = blockIdx.x*64, bn = blockIdx.y*64;
  const int tid = threadIdx.x;
  const int lane = tid & 63, wid = tid >> 6;
  const int wr = (wid >> 1)*32, wc = (wid & 1)*32;
  const int fm = lane & 15, fk = (lane >> 4)*8;

  f32x4 acc[2][2];
  #pragma unroll
  for (int i=0;i<2;i++)
    #pragma unroll
    for (int j=0;j<2;j++) acc[i][j] = (f32x4){0.f,0.f,0.f,0.f};

  for (int k0 = 0; k0 < K; k0 += 32) {
    if (!TRA) {
      int k = tid & 31, m0 = tid >> 5;
      #pragma unroll
      for (int u = 0; u < 8; u++) {
        int m = m0 + u*8;
        float f = A[(long)(bm+m)*lda + k0 + k];
        unsigned short h = f2bs(f);
        As[0][m][k] = h;
        As[1][m][k] = f2bs(f - bs2f(h));
      }
    } else {
      int m = tid & 63, kk0 = tid >> 6;
      #pragma unroll
      for (int u = 0; u < 8; u++) {
        int k = kk0 + u*4;
        float f = A[(long)(k0+k)*lda + bm + m];
        unsigned short h = f2bs(f);
        As[0][m][k] = h;
        As[1][m][k] = f2bs(f - bs2f(h));
      }
    }
    if (TRB) {
      int k = tid & 31, n0 = tid >> 5;
      #pragma unroll
      for (int u = 0; u < 8; u++) {
        int n = n0 + u*8;
        float f = Bp[(long)(bn+n)*ldb + k0 + k];
        unsigned short h = f2bs(f);
        Bs[0][n][k] = h;
        Bs[1][n][k] = f2bs(f - bs2f(h));
      }
    } else {
      int n = tid & 63, kk0 = tid >> 6;
      #pragma unroll
      for (int u = 0; u < 8; u++) {
        int k = kk0 + u*4;
        float f = Bp[(long)(k0+k)*ldb + bn + n];
        unsigned short h = f2bs(f);
        Bs[0][n][k] = h;
        Bs[1][n][k] = f2bs(f - bs2f(h));
      }
    }
    __syncthreads();
    bfrag ah0 = *reinterpret_cast<const bfrag*>(&As[0][wr + fm][fk]);
    bfrag ah1 = *reinterpret_cast<const bfrag*>(&As[0][wr + 16 + fm][fk]);
    bfrag bh0 = *reinterpret_cast<const bfrag*>(&Bs[0][wc + fm][fk]);
    bfrag bh1 = *reinterpret_cast<const bfrag*>(&Bs[0][wc + 16 + fm][fk]);
    bfrag al0 = *reinterpret_cast<const bfrag*>(&As[1][wr + fm][fk]);
    bfrag al1 = *reinterpret_cast<const bfrag*>(&As[1][wr + 16 + fm][fk]);
    bfrag bl0 = *reinterpret_cast<const bfrag*>(&Bs[1][wc + fm][fk]);
    bfrag bl1 = *reinterpret_cast<const bfrag*>(&Bs[1][wc + 16 + fm][fk]);
    acc[0][0] = __builtin_amdgcn_mfma_f32_16x16x32_bf16(ah0, bh0, acc[0][0], 0,0,0);
    acc[0][1] = __builtin_amdgcn_mfma_f32_16x16x32_bf16(ah0, bh1, acc[0][1], 0,0,0);
    acc[1][0] = __builtin_amdgcn_mfma_f32_16x16x32_bf16(ah1, bh0, acc[1][0], 0,0,0);
    acc[1][1] = __builtin_amdgcn_mfma_f32_16x16x32_bf16(ah1, bh1, acc[1][1], 0,0,0);
    acc[0][0] = __builtin_amdgcn_mfma_f32_16x16x32_bf16(ah0, bl0, acc[0][0], 0,0,0);
    acc[0][1] = __builtin_amdgcn_mfma_f32_16x16x32_bf16(ah0, bl1, acc[0][1], 0,0,0);
    acc[1][0] = __builtin_amdgcn_mfma_f32_16x16x32_bf16(ah1, bl0, acc[1][0], 0,0,0);
    acc[1][1] = __builtin_amdgcn_mfma_f32_16x16x32_bf16(ah1, bl1, acc[1][1], 0,0,0);
    acc[0][0] = __builtin_amdgcn_mfma_f32_16x16x32_bf16(al0, bh0, acc[0][0], 0,0,0);
    acc[0][1] = __builtin_amdgcn_mfma_f32_16x16x32_bf16(al0, bh1, acc[0][1], 0,0,0);
    acc[1][0] = __builtin_amdgcn_mfma_f32_16x16x32_bf16(al1, bh0, acc[1][0], 0,0,0);
    acc[1][1] = __builtin_amdgcn_mfma_f32_16x16x32_bf16(al1, bh1, acc[1][1], 0,0,0);
    __syncthreads();
  }

  #pragma unroll
  for (int i=0;i<2;i++) {
    #pragma unroll
    for (int j=0;j<2;j++) {
      #pragma unroll
      for (int r=0;r<4;r++) {
        int row = bm + wr + i*16 + (lane>>4)*4 + r;
        int col = bn + wc + j*16 + fm;
        float v = acc[i][j][r];
        if (EPI == EPI_SILU)          v = v / (1.f + __expf(-v));
        else if (EPI == EPI_SUB)      v = v - E[(long)row*lde + col];
        else if (EPI == EPI_LINCOMB)  v = a0*E[(long)row*lde + col] + a1*v;
        else if (EPI == EPI_MUL)      v = v * E[(long)row*lde + col];
        else if (EPI == EPI_ADD)      v = v + E[(long)row*lde + col];
        else if (EPI == EPI_SILU_MUL) v = (v / (1.f + __expf(-v))) * E[(long)row*lde + col];
        stf(&C[(long)row*ldc + col], v);
      }
    }
  }
}

// xn = x * nw * rsqrt(mean(x^2)+eps); one block per row
__global__ __launch_bounds__(256) void rmsnorm_in_k(const float* __restrict__ x,
    const float* __restrict__ w, float* __restrict__ xn)
{
  __shared__ float sbuf[4];
  long row = blockIdx.x;
  const float* xr = x + row*SD;
  int c0 = threadIdx.x, c1 = threadIdx.x + 256;
  float v0 = xr[c0], v1 = xr[c1];
  float ss = block_sum256(v0*v0 + v1*v1, sbuf);
  float r = rsqrtf(ss*(1.f/SD) + 1e-6f);
  xn[row*SD + c0] = v0*r*w[c0];
  xn[row*SD + c1] = v1*r*w[c1];
}

// dst_row = rms(silu(dwconv3(raw_row))) * nw ;  one block per (t, b)
__global__ __launch_bounds__(256) void conv_silu_rms_k(const float* __restrict__ raw,
    const float* __restrict__ cw, const float* __restrict__ cb, const float* __restrict__ nw,
    float* __restrict__ dst, long dstBatchStride, int dstRowOff)
{
  __shared__ float sbuf[4];
  int t = blockIdx.x, b = blockIdx.y;
  const float* base = raw + ((long)b*SS + t)*SD;
  float vals[2];
  #pragma unroll
  for (int u = 0; u < 2; u++) {
    int c = threadIdx.x + u*256;
    float w0 = cw[c*3+0], w1 = cw[c*3+1], w2 = cw[c*3+2];
    float acc = cb[c];
    if (t > 0)     acc += base[c - SD]*w0;
    acc += base[c]*w1;
    if (t < SS-1)  acc += base[c + SD]*w2;
    vals[u] = acc / (1.f + __expf(-acc));
  }
  float ss = block_sum256(vals[0]*vals[0] + vals[1]*vals[1], sbuf);
  float r = rsqrtf(ss*(1.f/SD) + 1e-6f);
  float* out = dst + (long)b*dstBatchStride + (long)(dstRowOff + t)*SD;
  out[threadIdx.x]       = vals[0]*r*nw[threadIdx.x];
  out[threadIdx.x + 256] = vals[1]*r*nw[threadIdx.x + 256];
}

// per-(b,chunk) column means of a [B*S, 512] buffer -> [B*NCH, 512]
__global__ __launch_bounds__(256) void chunk_means1_k(const float* __restrict__ src,
    float* __restrict__ dst)
{
  int cb = blockIdx.x;
  long rowbase = (long)cb*SCH*SD;
  #pragma unroll
  for (int u = 0; u < 2; u++) {
    int col = threadIdx.x + u*256;
    float s = 0.f;
    for (int r = 0; r < SCH; r++) s += src[rowbase + (long)r*SD + col];
    dst[(long)cb*SD + col] = s * (1.f/SCH);
  }
}

// atlas epilogue (in place): t = rms(a)*nw_out*gb; a = rms(t)*n1_w
__global__ __launch_bounds__(256) void atlas_final_norm_k(float* __restrict__ a,
    const float* __restrict__ gb, const float* __restrict__ nwout,
    const float* __restrict__ n1w)
{
  __shared__ float sbuf[4];
  long row = blockIdx.x;
  float* xr = a + row*SD;
  int c0 = threadIdx.x, c1 = threadIdx.x + 256;
  float v0 = xr[c0], v1 = xr[c1];
  float ss = block_sum256(v0*v0 + v1*v1, sbuf);
  float r = rsqrtf(ss*(1.f/SD) + 1e-6f);
  float t0 = v0*r*nwout[c0] * gb[row*SD+c0];
  float t1 = v1*r*nwout[c1] * gb[row*SD+c1];
  float ss2 = block_sum256(t0*t0 + t1*t1, sbuf);
  float r2 = rsqrtf(ss2*(1.f/SD) + 1e-6f);
  xr[c0] = t0*r2*n1w[c0];
  xr[c1] = t1*r2*n1w[c1];
}

// dst = rms(o)*w + dst  (in place on dst)
__global__ __launch_bounds__(256) void rms_add_k(const float* __restrict__ o,
    const float* __restrict__ w, float* __restrict__ dst)
{
  __shared__ float sbuf[4];
  long row = blockIdx.x;
  const float* xr = o + row*SD;
  int c0 = threadIdx.x, c1 = threadIdx.x + 256;
  float v0 = xr[c0], v1 = xr[c1];
  float ss = block_sum256(v0*v0 + v1*v1, sbuf);
  float r = rsqrtf(ss*(1.f/SD) + 1e-6f);
  dst[row*SD+c0] += v0*r*w[c0];
  dst[row*SD+c1] += v1*r*w[c1];
}

// sliding-window attention over packed QKV [B*S, ld] (q|k|v at col 0|512|1024)
__global__ __launch_bounds__(256) void attn_swa_k(const float* __restrict__ QKV,
    float* __restrict__ O, int ld)
{
  __shared__ float sc[4][SWIN];
  int wid = threadIdx.x >> 6, lane = threadIdx.x & 63;
  int w = blockIdx.x*4 + wid;
  int b = w >> 14;
  int rem = w & 16383;
  int h = rem >> 11;
  int i = rem & (SS-1);
  const float* base = QKV + (long)b*SS*ld;
  float qv = base[(long)i*ld + h*64 + lane];
  int j0 = i - (SWIN-1); if (j0 < 0) j0 = 0;
  int cnt = i - j0 + 1;
  const float* Kb = base + 512 + h*64;
  const float* Vb = base + 1024 + h*64;
  float mx = -1e30f;
  for (int jj = 0; jj < cnt; jj++) {
    float p = qv * Kb[(long)(j0+jj)*ld + lane];
    #pragma unroll
    for (int o2 = 32; o2 > 0; o2 >>= 1) p += __shfl_xor(p, o2);
    p *= 0.125f;
    if (lane == 0) sc[wid][jj] = p;
    mx = fmaxf(mx, p);
  }
  __syncthreads();
  float sum = 0.f, oa = 0.f;
  for (int jj = 0; jj < cnt; jj++) {
    float p = __expf(sc[wid][jj] - mx);
    sum += p;
    oa += p * Vb[(long)(j0+jj)*ld + lane];
  }
  O[((long)b*SS + i)*SD + h*64 + lane] = oa / sum;
}

__global__ __launch_bounds__(256) void copy_f_k(float* __restrict__ dst, long dstride,
    const float* __restrict__ src, long sstride, long nper, int nb)
{
  long total = nper * nb;
  for (long i = (long)blockIdx.x*256 + threadIdx.x; i < total; i += (long)gridDim.x*256) {
    long b = i / nper, r = i - b*nper;
    dst[b*dstride + r] = src[b*sstride + r];
  }
}

// concat SWA weights: wcat[0..DD)=q, [DD..2DD)=k, [2DD..3DD)=v for both SWAs
__global__ __launch_bounds__(256) void wcat_k(float* __restrict__ w1,
    const float* __restrict__ a0, const float* __restrict__ a1, const float* __restrict__ a2,
    float* __restrict__ w2,
    const float* __restrict__ b0, const float* __restrict__ b1, const float* __restrict__ b2)
{
  for (long i = (long)blockIdx.x*256 + threadIdx.x; i < DD; i += (long)gridDim.x*256) {
    w1[i] = a0[i]; w1[DD + i] = a1[i]; w1[2*DD + i] = a2[i];
    w2[i] = b0[i]; w2[DD + i] = b1[i]; w2[2*DD + i] = b2[i];
  }
}

// f32 -> hi/lo bf16 planes
__global__ __launch_bounds__(256) void split_k(unsigned short* __restrict__ dst,
    long dBatch, long dPlane, const float* __restrict__ src, long sBatch,
    long nper, int nb)
{
  long total = nper * nb;
  for (long i = (long)blockIdx.x*256 + threadIdx.x; i < total; i += (long)gridDim.x*256) {
    long b = i / nper, r = i - b*nper;
    float f = src[b*sBatch + r];
    unsigned short h = f2bs(f);
    dst[b*dBatch + r]          = h;
    dst[b*dBatch + dPlane + r] = f2bs(f - bs2f(h));
  }
}

// hi/lo planes -> f32
__global__ __launch_bounds__(256) void merge_k(float* __restrict__ dst, long dBatch,
    const unsigned short* __restrict__ src, long sBatch, long sPlane, long nper, int nb)
{
  long total = nper * nb;
  for (long i = (long)blockIdx.x*256 + threadIdx.x; i < total; i += (long)gridDim.x*256) {
    long b = i / nper, r = i - b*nper;
    dst[b*dBatch + r] = bs2f(src[b*sBatch + r]) + bs2f(src[b*sBatch + sPlane + r]);
  }
}

extern "C" void kernel_launch(void* const* d_in, const int* in_sizes, int n_in,
                              void* d_out, int out_size, void* d_ws, size_t ws_size,
                              hipStream_t stream)
{
  (void)in_sizes; (void)n_in; (void)out_size; (void)ws_size;
  const float* x      = (const float*)d_in[0];
  const float* mem0   = (const float*)d_in[1];
  const float* buf_k  = (const float*)d_in[2];
  const float* buf_v  = (const float*)d_in[3];
  const float* nw_in  = (const float*)d_in[4];
  const float* nw_kq  = (const float*)d_in[5];
  const float* nw_out = (const float*)d_in[6];
  const float* wk_a   = (const float*)d_in[7];
  const float* wq_a   = (const float*)d_in[8];
  const float* wv_a   = (const float*)d_in[9];
  const float* wg     = (const float*)d_in[10];
  const float* wb     = (const float*)d_in[11];
  const float* ck_w   = (const float*)d_in[12];
  const float* ck_b   = (const float*)d_in[13];
  const float* cq_w   = (const float*)d_in[14];
  const float* cq_b   = (const float*)d_in[15];
  const float* s1_wq  = (const float*)d_in[16];
  const float* s1_wk  = (const float*)d_in[17];
  const float* s1_wv  = (const float*)d_in[18];
  const float* s1_wo  = (const float*)d_in[19];
  const float* s2_wq  = (const float*)d_in[20];
  const float* s2_wk  = (const float*)d_in[21];
  const float* s2_wv  = (const float*)d_in[22];
  const float* s2_wo  = (const float*)d_in[23];
  const float* n1_w   = (const float*)d_in[24];
  const float* n2_w   = (const float*)d_in[25];
  const float* m_w1   = (const float*)d_in[26];
  const float* m_w2   = (const float*)d_in[27];
  const float* m_w3   = (const float*)d_in[28];
  float* ob = (float*)d_out;

  // ---- workspace carve: f32 section (~58MB) + u16 split arena (~29MB) ----
  float* p = (float*)d_ws;
  float* kp   = p; p += SB*KPBATCH;   // padded k f32; C: attn out; MLP: h1 head
  float* vp   = p; p += SB*KPBATCH;   // padded v f32; C: oproj1 out
  float* qbuf = p; p += SB*BSD;       // atlas q f32; C: qkv[0:512)
  float* gb   = p; p += SB*BSD;       // gamma*bypass; C: qkv[512:1024)
  float* sc1  = p; p += SB*BSD;       // xn; C: qkv[1024:1536), then y
  float* sc2  = p; p += SB*BSD;       // kraw/qraw; B: aout; C: memn->fused
  float* Mb   = p; p += SB*DD;        // mem0 f32 (split source)
  float* etaM = p; p += (long)SB*SNCH*SD;
  float* alphaM = p; p += (long)SB*SNCH*SD;
  float* partials = p; p += 512;
  float* wcat1 = p; p += 3*DD;        // [s1_wq; s1_wk; s1_wv]
  float* wcat2 = p; p += 3*DD;        // [s2_wq; s2_wk; s2_wv]
  unsigned short* us = (unsigned short*)p;
  unsigned short* khl = us; us += SB*2*KPBATCH;
  unsigned short* qhl = us; us += SB*2*BSD;
  unsigned short* Mhl = us; us += SB*2*DD;
  unsigned short* Xhl = us; us += SB*2*DD;
  unsigned short* Yhl = us; us += SB*2*DD;
  unsigned short* Ahl = us; us += SB*2*DD;
  unsigned short* Thl = us; us += SB*2*DD;
  unsigned short* errhl = us; us += SB*2*ERRN;
  float* nsbuf = (float*)khl;         // phase-A scratch (before splits)
  float* aout = sc2;
  float* qkv = qbuf;                  // [B*S][1536] spans qbuf+gb+sc1 (contiguous)
  float* hbuf = kp;                   // MLP h1/h2: kp..gb span

  dim3 blk(256);
  dim3 blk512(512);

  // ================= Phase A =================
  rmsnorm_in_k<<<SB*SS, blk, 0, stream>>>(x, nw_in, sc1);

  mgemm_k<false,true,EPI_SILU,float><<<dim3(32,8,2),blk,0,stream>>>(
      sc1, wv_a, vp + (long)SWIN*SD, nullptr, 0.f,0.f, SS, SD, SD,
      BSD, 0, KPBATCH, 0, SD, SD, SD, 0);

  mgemm_k<false,true,EPI_NONE,float><<<dim3(64,8,1),blk,0,stream>>>(
      sc1, wk_a, sc2, nullptr, 0.f,0.f, SB*SS, SD, SD, 0,0,0,0, SD,SD,SD,0);
  conv_silu_rms_k<<<dim3(SS,SB),blk,0,stream>>>(sc2, ck_w, ck_b, nw_kq, kp, KPBATCH, SWIN);

  mgemm_k<false,true,EPI_NONE,float><<<dim3(64,8,1),blk,0,stream>>>(
      sc1, wq_a, sc2, nullptr, 0.f,0.f, SB*SS, SD, SD, 0,0,0,0, SD,SD,SD,0);
  conv_silu_rms_k<<<dim3(SS,SB),blk,0,stream>>>(sc2, cq_w, cq_b, nw_kq, qbuf, BSD, 0);

  mgemm_k<false,true,EPI_SILU,float><<<dim3(64,8,1),blk,0,stream>>>(
      sc1, wg, gb, nullptr, 0.f,0.f, SB*SS, SD, SD, 0,0,0,0, SD,SD,SD,0);
  mgemm_k<false,true,EPI_SILU_MUL,float><<<dim3(64,8,1),blk,0,stream>>>(
      sc1, wb, gb, gb, 0.f,0.f, SB*SS, SD, SD, 0,0,0,0, SD,SD,SD,SD);

  mgemm_k<false,true,EPI_SILU,float><<<dim3(64,8,1),blk,0,stream>>>(
      sc1, wg + (long)SD*SD, nsbuf, nullptr, 0.f,0.f, SB*SS, SD, SD, 0,0,0,0, SD,SD,SD,0);
  chunk_means1_k<<<SB*SNCH, blk, 0, stream>>>(nsbuf, etaM);
  mgemm_k<false,true,EPI_SILU,float><<<dim3(64,8,1),blk,0,stream>>>(
      sc1, wg + 2L*SD*SD, nsbuf, nullptr, 0.f,0.f, SB*SS, SD, SD, 0,0,0,0, SD,SD,SD,0);
  chunk_means1_k<<<SB*SNCH, blk, 0, stream>>>(nsbuf, alphaM);

  copy_f_k<<<256,blk,0,stream>>>(kp, KPBATCH, buf_k, (long)SWIN*SD, (long)SWIN*SD, SB);
  copy_f_k<<<256,blk,0,stream>>>(vp, KPBATCH, buf_v, (long)SWIN*SD, (long)SWIN*SD, SB);
  copy_f_k<<<256,blk,0,stream>>>(Mb, DD, mem0, DD, DD, SB);
  wcat_k<<<512,blk,0,stream>>>(wcat1, s1_wq, s1_wk, s1_wv, wcat2, s2_wq, s2_wk, s2_wv);

  // split once for the scan (AFTER nsbuf is dead)
  split_k<<<512,blk,0,stream>>>(khl, 2*KPBATCH, KPBATCH, kp, KPBATCH, KPBATCH, SB);
  split_k<<<512,blk,0,stream>>>(qhl, 2*BSD, BSD, qbuf, BSD, BSD, SB);
  split_k<<<256,blk,0,stream>>>(Mhl, 2*DD, DD, Mb, DD, DD, SB);

  // ================= Phase B: sequential chunk scan (multi-launch) =================
  out_err_k<<<256,blk,0,stream>>>(khl, qhl, Mhl, errhl, vp, aout, -1, 0);

  for (int t = 0; t < SNCH; ++t) {
    const long off = (long)t*SCH*SD;
    // grad (UNNORMALIZED) = ck^T @ err -> Xhl split + frob partials (256/batch)
    sgemm32s_k<true,false,EPI_NONE,false,true,false,true,false,0><<<dim3(16,16,2),blk512,0,stream>>>(
        khl + off, errhl, nullptr, Xhl, nullptr, nullptr, partials, nullptr, 0,
        0.f,0.f, 512, 512, 192,
        2*KPBATCH, KPBATCH, 2*ERRN, ERRN,
        0, 2*DD, DD, 0, 0,
        512,512,512,0, nullptr, nullptr, 0);
    // NS iter 1 (scale folded): A1 = (X0@X0^T)/s^2
    sgemm32s_k<false,true,EPI_NONE,false,true,false,false,false,1><<<dim3(16,16,2),blk512,0,stream>>>(
        Xhl, Xhl, nullptr, Ahl, nullptr, nullptr, nullptr, partials, 256,
        0.f,0.f, 512,512,512, 2*DD,DD, 2*DD,DD, 0, 2*DD,DD, 0,0, 512,512,512,0,
        nullptr, nullptr, 0);
    // T1 = b*A1 + c*A1@A1
    sgemm32s_k<false,true,EPI_LINCOMB,true,true,false,false,false,0><<<dim3(16,16,2),blk512,0,stream>>>(
        Ahl, Ahl, nullptr, Thl, nullptr, Ahl, nullptr, nullptr, 0,
        -4.7750f, 2.0315f, 512,512,512, 2*DD,DD, 2*DD,DD, 0, 2*DD,DD, 2*DD,DD,
        512,512,512,512, nullptr, nullptr, 0);
    // X1 = (a*X0 + T1@X0)/s -> Yhl
    sgemm32s_k<false,false,EPI_LINCOMB,true,true,false,false,false,2><<<dim3(16,16,2),blk512,0,stream>>>(
        Thl, Xhl, nullptr, Yhl, nullptr, Xhl, nullptr, partials, 256,
        3.4445f, 1.0f, 512,512,512, 2*DD,DD, 2*DD,DD, 0, 2*DD,DD, 2*DD,DD,
        512,512,512,512, nullptr, nullptr, 0);
    // NS iterations 2..4 (full)
    unsigned short* Xc = Yhl; unsigned short* Xn = Xhl;
    for (int it = 0; it < 3; ++it) {
      sgemm32s_k<false,true,EPI_NONE,false,true,false,false,false,0><<<dim3(16,16,2),blk512,0,stream>>>(
          Xc, Xc, nullptr, Ahl, nullptr, nullptr, nullptr, nullptr, 0,
          0.f,0.f, 512,512,512, 2*DD,DD, 2*DD,DD, 0, 2*DD,DD, 0,0, 512,512,512,0,
          nullptr, nullptr, 0);
      sgemm32s_k<false,true,EPI_LINCOMB,true,true,false,false,false,0><<<dim3(16,16,2),blk512,0,stream>>>(
          Ahl, Ahl, nullptr, Thl, nullptr, Ahl, nullptr, nullptr, 0,
          -4.7750f, 2.0315f, 512,512,512, 2*DD,DD, 2*DD,DD, 0, 2*DD,DD, 2*DD,DD,
          512,512,512,512, nullptr, nullptr, 0);
      sgemm32s_k<false,false,EPI_LINCOMB,true,true,false,false,false,0><<<dim3(16,16,2),blk512,0,stream>>>(
          Thl, Xc, nullptr, Xn, nullptr, Xc, nullptr, nullptr, 0,
          3.4445f, 1.0f, 512,512,512, 2*DD,DD, 2*DD,DD, 0, 2*DD,DD, 2*DD,DD,
          512,512,512,512, nullptr, nullptr, 0);
      unsigned short* tmp = Xc; Xc = Xn; Xn = tmp;
    }
    // iter 5: A, T, then fused X5 + M-update (X5 never materialized)
    sgemm32s_k<false,true,EPI_NONE,false,true,false,false,false,0><<<dim3(16,16,2),blk512,0,stream>>>(
        Xc, Xc, nullptr, Ahl, nullptr, nullptr, nullptr, nullptr, 0,
        0.f,0.f, 512,512,512, 2*DD,DD, 2*DD,DD, 0, 2*DD,DD, 0,0, 512,512,512,0,
        nullptr, nullptr, 0);
    sgemm32s_k<false,true,EPI_LINCOMB,true,true,false,false,false,0><<<dim3(16,16,2),blk512,0,stream>>>(
        Ahl, Ahl, nullptr, Thl, nullptr, Ahl, nullptr, nullptr, 0,
        -4.7750f, 2.0315f, 512,512,512, 2*DD,DD, 2*DD,DD, 0, 2*DD,DD, 2*DD,DD,
        512,512,512,512, nullptr, nullptr, 0);
    // v = a*X4 + T@X4 ; M = M*alpha - v*eta  (split pair, in place on Mhl)
    sgemm32s_k<false,false,EPI_LINCOMB,true,false,false,false,true,0><<<dim3(16,16,2),blk512,0,stream>>>(
        Thl, Xc, nullptr, Mhl, nullptr, Xc, nullptr, nullptr, 0,
        3.4445f, 1.0f, 512,512,512, 2*DD,DD, 2*DD,DD, 0, 2*DD, DD, 2*DD,DD,
        512,512,512,512, alphaM, etaM, t);
    // out(t) = cq @ M  ||  err(t+1)
    out_err_k<<<256,blk,0,stream>>>(khl, qhl, Mhl, errhl, vp, aout, t, t+1);
  }

  // ================= Phase C =================
  atlas_final_norm_k<<<SB*SS,blk,0,stream>>>(sc2, gb, nw_out, n1_w);

  // side outputs (before kp/vp reuse)
  merge_k<<<256,blk,0,stream>>>(ob + (long)SB*SS*SD, DD, Mhl, 2*DD, DD, DD, SB);
  copy_f_k<<<256,blk,0,stream>>>(ob + (long)SB*SS*SD + SB*DD, (long)SWIN*SD,
      kp + (long)SS*SD, KPBATCH, (long)SWIN*SD, SB);
  copy_f_k<<<256,blk,0,stream>>>(ob + (long)SB*SS*SD + SB*DD + (long)SB*SWIN*SD, (long)SWIN*SD,
      vp + (long)SS*SD, KPBATCH, (long)SWIN*SD, SB);

  // SWA 1 on x: fused QKV gemm -> qkv[4096][1536]; attn -> kp; oproj -> vp
  mgemm_k<false,true,EPI_NONE,float><<<dim3(64,24,1),blk,0,stream>>>(
      x, wcat1, qkv, nullptr,0.f,0.f, SB*SS, 3*SD, SD, 0,0,0,0, SD,SD,3*SD,0);
  attn_swa_k<<<SB*SH*SS/4, blk, 0, stream>>>(qkv, kp, 3*SD);
  mgemm_k<false,true,EPI_NONE,float><<<dim3(64,8,1),blk,0,stream>>>(
      kp, s1_wo, vp, nullptr,0.f,0.f, SB*SS, SD, SD, 0,0,0,0, SD,SD,SD,0);
  rms_add_k<<<SB*SS,blk,0,stream>>>(vp, n2_w, sc2);   // sc2 = fused

  // SWA 2 on fused: QKV -> qkv; attn -> kp; oproj -> sc1 (y)
  mgemm_k<false,true,EPI_NONE,float><<<dim3(64,24,1),blk,0,stream>>>(
      sc2, wcat2, qkv, nullptr,0.f,0.f, SB*SS, 3*SD, SD, 0,0,0,0, SD,SD,3*SD,0);
  attn_swa_k<<<SB*SH*SS/4, blk, 0, stream>>>(qkv, kp, 3*SD);
  mgemm_k<false,true,EPI_NONE,float><<<dim3(64,8,1),blk,0,stream>>>(
      kp, s2_wo, sc1, nullptr,0.f,0.f, SB*SS, SD, SD, 0,0,0,0, SD,SD,SD,0); // y=sc1

  // MLP
  mgemm_k<false,true,EPI_SILU,float><<<dim3(64,32,1),blk,0,stream>>>(
      sc1, m_w1, hbuf, nullptr,0.f,0.f, SB*SS, SFF, SD, 0,0,0,0, SD,SD,SFF,0);
  mgemm_k<false,true,EPI_MUL,float><<<dim3(64,32,1),blk,0,stream>>>(
      sc1, m_w2, hbuf, hbuf, 0.f,0.f, SB*SS, SFF, SD, 0,0,0,0, SD,SD,SFF,SFF);
  mgemm_k<false,true,EPI_ADD,float><<<dim3(64,8,1),blk,0,stream>>>(
      hbuf, m_w3, ob, sc2, 0.f,0.f, SB*SS, SD, SFF, 0,0,0,0, SFF,SFF,SD,SD);
}